// Round 4
// baseline (8482.220 us; speedup 1.0000x reference)
//
#include <hip/hip_runtime.h>
#include <hip/hip_bf16.h>
#include <math.h>

// ---------------------------------------------------------------------------
// HybridGemmaDiT forward.  B=64, S=256 (16x16), D=768, L=8, NH=4, HD=192.
// R4: BK=64 GEMM + XCD swizzle; head/lpred rewrite (coalesced, rowlam fused);
//     wave-per-row rmsnorm.
// ---------------------------------------------------------------------------

#define DEV static __device__ __forceinline__

typedef float    f32x4 __attribute__((ext_vector_type(4)));
typedef short    s16x8 __attribute__((ext_vector_type(8)));
typedef unsigned short u16x8 __attribute__((ext_vector_type(8)));
typedef unsigned short u16x4 __attribute__((ext_vector_type(4)));

constexpr int Bb = 64, Ss = 256, Dd = 768, Ll = 8, NHh = 4, HDd = 192;
constexpr int M_TOK = Bb * Ss;                 // 16384
constexpr float EPS_RMS = 1.1920929e-07f;
constexpr float ATT_SCALE = 0.07216878364870322f;  // 1/sqrt(192)
constexpr size_t ARENA_K = (size_t)Bb * NHh * Ss * HDd;   // 12,582,912 elems

// ---- workspace layout (BYTES) ---------------------------------------------
constexpr size_t B_SPINS  = 0;
constexpr size_t B_SCALEF = 2048;
constexpr size_t B_QT     = 5120;                        // 8*192*192 f32
constexpr size_t B_COS    = B_QT + 1179648;
constexpr size_t B_SIN    = B_COS + 196608;
constexpr size_t B_G      = B_SIN + 196608;              // 8*96*96 f32
constexpr size_t B_T      = B_G + 294912;
constexpr size_t B_AWY    = B_T + 294912;                // 8*96*192 f32
constexpr size_t B_ROWLAM = B_AWY + 589824;              // 16384 f32
constexpr size_t B_X      = B_ROWLAM + 65536;            // 16384*768 f32
constexpr size_t B_H      = B_X + 50331648;              // bf16
constexpr size_t B_PROJ   = B_H + 25165824;              // bf16
constexpr size_t B_WEFFT  = B_PROJ + 25165824;           // 8*2304*768 bf16
constexpr size_t B_OUTWT  = B_WEFFT + 28311552;
constexpr size_t B_GATEWT = B_OUTWT + 9437184;
constexpr size_t B_MLPGT  = B_GATEWT + 9437184;          // 8*6144*768 bf16
constexpr size_t B_MLPOT  = B_MLPGT + 75497472;          // 8*768*3072 bf16
constexpr size_t B_ARENA  = B_MLPOT + 37748736;          // q,k,v^T,attn bf16 | hidden | weff_f32

DEV float sigmoidf_(float x) { return 1.0f / (1.0f + expf(-x)); }
DEV float geluf_(float g)    { return 0.5f * g * (1.0f + erff(g * 0.7071067811865476f)); }
DEV unsigned short f2bf(float f) {
    union { float f; unsigned u; } a; a.f = f;
    unsigned u = a.u + 0x7fffu + ((a.u >> 16) & 1u);
    return (unsigned short)(u >> 16);
}
DEV float b2f(unsigned short u) {
    union { unsigned u; float f; } a; a.u = ((unsigned)u) << 16; return a.f;
}
DEV void gload16(const void* g, void* l) {
    __builtin_amdgcn_global_load_lds((const __attribute__((address_space(1))) void*)g,
                                     (__attribute__((address_space(3))) void*)l, 16, 0, 0);
}

// ---------------------------------------------------------------------------
__global__ void spins_kernel(const float* __restrict__ logsnr, float* __restrict__ spins) {
    int b = threadIdx.x;
    if (b < 64) {
        float v = logsnr[b];
#pragma unroll
        for (int j = 0; j < 4; ++j) {
            float ang = v * (float)(1 << j);
            spins[b * 8 + j]     = sinf(ang);
            spins[b * 8 + 4 + j] = cosf(ang);
        }
    }
}

__global__ void rope_table_kernel(float* __restrict__ cosb, float* __restrict__ sinb) {
    int s = blockIdx.x, j = threadIdx.x;
    int y = s >> 4, x = s & 15;
    int base = j % 96;
    float coord, invf;
    if (base < 48) { invf = expf(-(float)base * (2.0f / 96.0f) * 9.210340371976184f); coord = (float)y; }
    else { int i = base - 48; invf = expf(-(float)i * (2.0f / 96.0f) * 9.210340371976184f); coord = (float)x; }
    float f = coord * invf, sv, cv;
    sincosf(f, &sv, &cv);
    cosb[s * 192 + j] = cv;
    sinb[s * 192 + j] = sv;
}

// ---- WY householder: qt = P = I - Y T Y^T ---------------------------------
__global__ __launch_bounds__(256) void hh_gram_kernel(const float* __restrict__ hh_vs,
                                                      float* __restrict__ Gm) {
    __shared__ float Y[96][192];
    int l = blockIdx.x, t = threadIdx.x;
    const float4* src = (const float4*)(hh_vs + (size_t)l * 96 * 192);
    for (int i = t; i < 4608; i += 256) ((float4*)&Y[0][0])[i] = src[i];
    __syncthreads();
    for (int e = t; e < 9216; e += 256) {
        int i = e / 96, j = e - (e / 96) * 96;
        float acc = 0.f;
        for (int d = 0; d < 48; ++d) {
            float4 a = *(const float4*)&Y[i][d * 4];
            float4 b = *(const float4*)&Y[j][d * 4];
            acc += a.x * b.x + a.y * b.y + a.z * b.z + a.w * b.w;
        }
        Gm[(size_t)l * 9216 + e] = acc;
    }
}

__global__ __launch_bounds__(128) void hh_t_kernel(const float* __restrict__ Gm,
                                                   float* __restrict__ Tm) {
    __shared__ float G[96][96];
    __shared__ float T[96][100];
    int l = blockIdx.x, t = threadIdx.x;
    const float* Gl = Gm + (size_t)l * 9216;
    for (int i = t; i < 9216; i += 128) { G[i / 96][i % 96] = Gl[i]; }
    for (int i = t; i < 9600; i += 128) { T[i / 100][i % 100] = 0.f; }
    __syncthreads();
    if (t < 96) T[t][t] = 2.0f / (G[t][t] + 1e-8f);
    __syncthreads();
    for (int j = 1; j < 96; ++j) {
        if (t < j) {
            float cj = 2.0f / (G[j][j] + 1e-8f);
            float dot = 0.f;
            for (int p = t; p < j; ++p) dot += T[t][p] * G[p][j];
            T[t][j] = -cj * dot;
        }
        __syncthreads();
    }
    for (int i = t; i < 9216; i += 128) Tm[(size_t)l * 9216 + i] = T[i / 96][i % 96];
}

__global__ __launch_bounds__(256) void hh_a_kernel(const float* __restrict__ Tm,
                                                   const float* __restrict__ hh_vs,
                                                   float* __restrict__ Am) {
    __shared__ float T[96][100];
    __shared__ float Y[96][192];
    int l = blockIdx.x, t = threadIdx.x;
    const float* Tl = Tm + (size_t)l * 9216;
    const float4* src = (const float4*)(hh_vs + (size_t)l * 96 * 192);
    for (int i = t; i < 9216; i += 256) T[i / 96][i % 96] = Tl[i];
    for (int i = t; i < 4608; i += 256) ((float4*)&Y[0][0])[i] = src[i];
    __syncthreads();
    for (int idx = t; idx < 4608; idx += 256) {
        int i = idx / 48, e0 = (idx % 48) * 4;
        float4 acc = {0.f, 0.f, 0.f, 0.f};
        for (int j = i; j < 96; ++j) {
            float tv = T[i][j];
            float4 y = *(const float4*)&Y[j][e0];
            acc.x += tv * y.x; acc.y += tv * y.y; acc.z += tv * y.z; acc.w += tv * y.w;
        }
        *(float4*)(Am + (size_t)l * 96 * 192 + (size_t)i * 192 + e0) = acc;
    }
}

__global__ __launch_bounds__(256) void hh_p_kernel(const float* __restrict__ hh_vs,
                                                   const float* __restrict__ Am,
                                                   float* __restrict__ qt) {
    __shared__ float Y[96][192];
    __shared__ float A[96][192];
    int l = blockIdx.x, t = threadIdx.x;
    const float4* ys = (const float4*)(hh_vs + (size_t)l * 96 * 192);
    const float4* as = (const float4*)(Am + (size_t)l * 96 * 192);
    for (int i = t; i < 4608; i += 256) { ((float4*)&Y[0][0])[i] = ys[i]; ((float4*)&A[0][0])[i] = as[i]; }
    __syncthreads();
    for (int idx = t; idx < 9216; idx += 256) {
        int d = idx / 48, e0 = (idx % 48) * 4;
        float4 acc = {0.f, 0.f, 0.f, 0.f};
        for (int i = 0; i < 96; ++i) {
            float yv = Y[i][d];
            float4 a = *(const float4*)&A[i][e0];
            acc.x += yv * a.x; acc.y += yv * a.y; acc.z += yv * a.z; acc.w += yv * a.w;
        }
        acc.x = (d == e0 + 0 ? 1.f : 0.f) - acc.x;
        acc.y = (d == e0 + 1 ? 1.f : 0.f) - acc.y;
        acc.z = (d == e0 + 2 ? 1.f : 0.f) - acc.z;
        acc.w = (d == e0 + 3 ? 1.f : 0.f) - acc.w;
        *(float4*)(qt + (size_t)l * 192 * 192 + (size_t)d * 192 + e0) = acc;
    }
}

// W_eff q/k head-blocks <- qkv_w block @ Q^T (fp32).  grid (3, 12, 64).
__global__ __launch_bounds__(256) void fold_kernel(const float* __restrict__ qkv_w,
                                                   const float* __restrict__ qt,
                                                   float* __restrict__ weff) {
    int z = blockIdx.z;
    int l = z >> 3, which = (z >> 2) & 1, head = z & 3;
    const float* A  = qkv_w + (size_t)l * 768 * 2304 + (size_t)which * 768 + head * 192;
    const float* Bq = qt + (size_t)l * 192 * 192;
    float* C        = weff + (size_t)l * 768 * 2304 + (size_t)which * 768 + head * 192;
    int row0 = blockIdx.y * 64, col0 = blockIdx.x * 64;
    __shared__ float As[64][65];
    __shared__ float Bs[64][65];
    int tid = threadIdx.x, tx = tid & 15, ty = tid >> 4;
    float acc[4][4] = {};
    for (int k0 = 0; k0 < 192; k0 += 64) {
        for (int i = tid; i < 1024; i += 256) {
            int r = i >> 4, kq = i & 15;
            float4 va = *(const float4*)(A + (size_t)(row0 + r) * 2304 + k0 + kq * 4);
            As[kq * 4 + 0][r] = va.x; As[kq * 4 + 1][r] = va.y; As[kq * 4 + 2][r] = va.z; As[kq * 4 + 3][r] = va.w;
        }
        for (int i = tid; i < 1024; i += 256) {
            int r = i >> 4, nq = i & 15;
            float4 vb = *(const float4*)(Bq + (size_t)(k0 + r) * 192 + col0 + nq * 4);
            Bs[r][nq * 4 + 0] = vb.x; Bs[r][nq * 4 + 1] = vb.y; Bs[r][nq * 4 + 2] = vb.z; Bs[r][nq * 4 + 3] = vb.w;
        }
        __syncthreads();
        for (int k = 0; k < 64; ++k) {
            float a[4], bb[4];
#pragma unroll
            for (int m = 0; m < 4; ++m) a[m] = As[k][ty * 4 + m];
#pragma unroll
            for (int n = 0; n < 4; ++n) bb[n] = Bs[k][tx * 4 + n];
#pragma unroll
            for (int m = 0; m < 4; ++m)
#pragma unroll
                for (int n = 0; n < 4; ++n) acc[m][n] = fmaf(a[m], bb[n], acc[m][n]);
        }
        __syncthreads();
    }
#pragma unroll
    for (int m = 0; m < 4; ++m)
#pragma unroll
        for (int n = 0; n < 4; ++n)
            C[(size_t)(row0 + ty * 4 + m) * 2304 + col0 + tx * 4 + n] = acc[m][n];
}

// fp32 [K][N] -> bf16 [N][K]
__global__ __launch_bounds__(256) void transpose_bf16_kernel(const float* __restrict__ W,
                                                             unsigned short* __restrict__ Wt,
                                                             int K, int N) {
    __shared__ float t[32][33];
    size_t zoff = (size_t)blockIdx.z * K * N;
    const float* Wz = W + zoff;
    unsigned short* Wtz = Wt + zoff;
    int k0 = blockIdx.y * 32, n0 = blockIdx.x * 32;
    int tid = threadIdx.x;
    int tr = tid >> 3, tc = tid & 7;
    float4 v = *(const float4*)(Wz + (size_t)(k0 + tr) * N + n0 + tc * 4);
    t[tr][tc * 4 + 0] = v.x; t[tr][tc * 4 + 1] = v.y; t[tr][tc * 4 + 2] = v.z; t[tr][tc * 4 + 3] = v.w;
    __syncthreads();
    u16x4 o;
    o[0] = f2bf(t[tc * 4 + 0][tr]); o[1] = f2bf(t[tc * 4 + 1][tr]);
    o[2] = f2bf(t[tc * 4 + 2][tr]); o[3] = f2bf(t[tc * 4 + 3][tr]);
    *(u16x4*)(Wtz + (size_t)(n0 + tr) * K + k0 + tc * 4) = o;
}

__global__ __launch_bounds__(256) void patch_embed_kernel(const float* __restrict__ z_t,
                                                          const float* __restrict__ spins,
                                                          const float* __restrict__ patch_w,
                                                          const float* __restrict__ patch_b,
                                                          float* __restrict__ x) {
    int bs = blockIdx.x;
    int b = bs >> 8, s = bs & 255;
    int gy = s >> 4, gx = s & 15;
    __shared__ float in20[20];
    int t = threadIdx.x;
    if (t < 12) {
        int c = t >> 2, py = (t >> 1) & 1, px = t & 1;
        in20[t] = z_t[(((size_t)b * 3 + c) * 32 + (2 * gy + py)) * 32 + (2 * gx + px)];
    } else if (t < 20) {
        in20[t] = spins[b * 8 + (t - 12)];
    }
    __syncthreads();
    for (int d = t; d < 768; d += 256) {
        float acc = patch_b[d];
#pragma unroll
        for (int i = 0; i < 20; ++i) acc += in20[i] * patch_w[i * 768 + d];
        x[(size_t)bs * 768 + d] = acc;
    }
}

// wave-per-row rmsnorm: 4 rows/block, lane owns 12 contiguous d
__global__ __launch_bounds__(256) void rmsnorm_kernel(const float* __restrict__ x,
                                                      unsigned short* __restrict__ h) {
    int wave = threadIdx.x >> 6, lane = threadIdx.x & 63;
    int row = blockIdx.x * 4 + wave;
    const float* xr = x + (size_t)row * 768 + lane * 12;
    float4 a = *(const float4*)(xr);
    float4 b = *(const float4*)(xr + 4);
    float4 c = *(const float4*)(xr + 8);
    float ss = a.x*a.x + a.y*a.y + a.z*a.z + a.w*a.w
             + b.x*b.x + b.y*b.y + b.z*b.z + b.w*b.w
             + c.x*c.x + c.y*c.y + c.z*c.z + c.w*c.w;
#pragma unroll
    for (int msk = 1; msk < 64; msk <<= 1) ss += __shfl_xor(ss, msk);
    float sc = 1.0f / sqrtf(ss / 768.0f + EPS_RMS);
    unsigned short* hr = h + (size_t)row * 768 + lane * 12;
    u16x4 o0, o1, o2;
    o0[0]=f2bf(a.x*sc); o0[1]=f2bf(a.y*sc); o0[2]=f2bf(a.z*sc); o0[3]=f2bf(a.w*sc);
    o1[0]=f2bf(b.x*sc); o1[1]=f2bf(b.y*sc); o1[2]=f2bf(b.z*sc); o1[3]=f2bf(b.w*sc);
    o2[0]=f2bf(c.x*sc); o2[1]=f2bf(c.y*sc); o2[2]=f2bf(c.z*sc); o2[3]=f2bf(c.w*sc);
    *(u16x4*)(hr) = o0; *(u16x4*)(hr + 4) = o1; *(u16x4*)(hr + 8) = o2;
}

// ---- bf16 MFMA GEMM: A[M][K] bf16, Bt[N][K] bf16 -> C[M][N] ---------------
// 128x128 tile, BK=64, 4 waves, XCD-aware block swizzle.
// EPI: 0=store bf16(+bias)  1=qkv scatter (V transposed)  2=gate  3=val*gelu  4=x+=v
template <int EPI>
__global__ __launch_bounds__(256) void gemm_mfma(const unsigned short* __restrict__ A, int lda,
                                                 const unsigned short* __restrict__ Bt, int ldb,
                                                 unsigned short* __restrict__ Cb, int ldc, int K,
                                                 const float* __restrict__ bias,
                                                 float* __restrict__ Xf,
                                                 const unsigned short* __restrict__ Pb) {
    __shared__ unsigned short As[8192];   // [128 rows][64 k], 8-slot XOR swizzle
    __shared__ unsigned short Bs[8192];
    int tid = threadIdx.x;
    int wave = tid >> 6, lane = tid & 63;
    // XCD-aware bijective swizzle (all grids have nwg % 8 == 0)
    int gx = gridDim.x;
    int id = blockIdx.y * gx + blockIdx.x;
    int q = (gx * gridDim.y) >> 3;
    id = (id & 7) * q + (id >> 3);
    int row0 = (id / gx) * 128, col0 = (id % gx) * 128;
    int wm = wave >> 1, wn = wave & 1;
    f32x4 acc[4][4] = {};

    int srow = lane >> 3;                       // row within 8-row group
    int ksw = ((lane & 7) ^ srow) * 8;          // pre-swizzled source k offset
    int lrow = lane & 15;

    for (int k0 = 0; k0 < K; k0 += 64) {
#pragma unroll
        for (int it = 0; it < 4; ++it) {
            int g = it * 4 + wave;              // 16 groups of 8 rows
            int r = g * 8 + srow;
            gload16(A  + (size_t)(row0 + r) * lda + k0 + ksw, &As[g * 512]);
            gload16(Bt + (size_t)(col0 + r) * ldb + k0 + ksw, &Bs[g * 512]);
        }
        __syncthreads();
#pragma unroll
        for (int kk = 0; kk < 2; ++kk) {
            int phys = (kk * 4 + (lane >> 4)) ^ (lane & 7);
            s16x8 af[4], bf[4];
#pragma unroll
            for (int m = 0; m < 4; ++m)
                af[m] = *(const s16x8*)&As[(wm * 64 + m * 16 + lrow) * 64 + phys * 8];
#pragma unroll
            for (int n = 0; n < 4; ++n)
                bf[n] = *(const s16x8*)&Bs[(wn * 64 + n * 16 + lrow) * 64 + phys * 8];
#pragma unroll
            for (int m = 0; m < 4; ++m)
#pragma unroll
                for (int n = 0; n < 4; ++n)
                    acc[m][n] = __builtin_amdgcn_mfma_f32_16x16x32_bf16(af[m], bf[n], acc[m][n], 0, 0, 0);
        }
        __syncthreads();
    }

    int lquad = lane >> 4;
#pragma unroll
    for (int m = 0; m < 4; ++m) {
#pragma unroll
        for (int n = 0; n < 4; ++n) {
#pragma unroll
            for (int r = 0; r < 4; ++r) {
                int i = row0 + wm * 64 + m * 16 + lquad * 4 + r;
                int j = col0 + wn * 64 + n * 16 + lrow;
                float v = acc[m][n][r];
                if (bias) v += bias[j];
                if constexpr (EPI == 0) {
                    Cb[(size_t)i * ldc + j] = f2bf(v);
                } else if constexpr (EPI == 1) {
                    int which = j / 768;
                    int rem = j - which * 768;
                    int head = rem / 192;
                    int hd = rem - head * 192;
                    int b = i >> 8, s = i & 255;
                    if (which == 2) {   // V transposed: [bh][d][s]
                        Cb[2 * ARENA_K + (((size_t)(b * 4 + head)) * 192 + hd) * 256 + s] = f2bf(v);
                    } else {
                        Cb[(size_t)which * ARENA_K + (((size_t)(b * 4 + head)) * 256 + s) * 192 + hd] = f2bf(v);
                    }
                } else if constexpr (EPI == 2) {
                    float p = b2f(Pb[(size_t)i * 768 + j]);
                    Xf[(size_t)i * 768 + j] += p * sigmoidf_(v);
                } else if constexpr (EPI == 3) {
                    float g = b2f(Cb[(size_t)i * ldc + j]);
                    Cb[(size_t)i * ldc + j] = f2bf(v * geluf_(g));
                } else if constexpr (EPI == 4) {
                    Xf[(size_t)i * ldc + j] += v;
                }
            }
        }
    }
}

// in-place RoPE on bf16 [q|k] (131072 rows x 192)
__global__ __launch_bounds__(256) void rope_kernel(unsigned short* __restrict__ qk,
                                                   const float* __restrict__ cosb,
                                                   const float* __restrict__ sinb) {
    int gid = blockIdx.x * 256 + threadIdx.x;
    int row = gid / 24, q4 = gid - row * 24;
    int j0 = q4 * 4;
    int s = row & 255;
    unsigned short* p = qk + (size_t)row * 192;
    u16x4 t1 = *(u16x4*)(p + j0);
    u16x4 t2 = *(u16x4*)(p + 96 + j0);
    u16x4 o1, o2;
#pragma unroll
    for (int i = 0; i < 4; ++i) {
        float a = b2f(t1[i]), b = b2f(t2[i]);
        float c1 = cosb[s * 192 + j0 + i],      s1 = sinb[s * 192 + j0 + i];
        float c2 = cosb[s * 192 + 96 + j0 + i], s2 = sinb[s * 192 + 96 + j0 + i];
        o1[i] = f2bf(a * c1 - b * s1);
        o2[i] = f2bf(b * c2 + a * s2);
    }
    *(u16x4*)(p + j0) = o1;
    *(u16x4*)(p + 96 + j0) = o2;
}

// ---- MFMA attention: grid (2 halves, NH, B), 512 thr (8 waves x 16 qrows) -
__global__ __launch_bounds__(512) void attn_mfma_kernel(const unsigned short* __restrict__ qb_,
                                                        const unsigned short* __restrict__ kb_,
                                                        const unsigned short* __restrict__ vtb_,
                                                        unsigned short* __restrict__ attnb,
                                                        int glob) {
    __shared__ unsigned short Klds[256 * 200];
    __shared__ unsigned short Vlds[192 * 72];
    __shared__ unsigned short Plds[8 * 16 * 72];
    int b = blockIdx.z, hh = blockIdx.y;
    int tid = threadIdx.x;
    int wave = tid >> 6, lane = tid & 63;
    int q0 = blockIdx.x * 128 + wave * 16;
    size_t bh = (size_t)(b * 4 + hh);
    const unsigned short* qb  = qb_  + bh * 49152;
    const unsigned short* kb  = kb_  + bh * 49152;
    const unsigned short* vtb = vtb_ + bh * 49152;

    for (int c = tid; c < 6144; c += 512) {
        int r = c / 24, col = c - (c / 24) * 24;
        *(u16x8*)&Klds[r * 200 + col * 8] = *(const u16x8*)(kb + (size_t)r * 192 + col * 8);
    }
    __syncthreads();

    s16x8 qf[6];
#pragma unroll
    for (int kk = 0; kk < 6; ++kk)
        qf[kk] = *(const s16x8*)(qb + (size_t)(q0 + (lane & 15)) * 192 + kk * 32 + (lane >> 4) * 8);

    f32x4 sc[16];
#pragma unroll
    for (int n = 0; n < 16; ++n) sc[n] = (f32x4){0.f, 0.f, 0.f, 0.f};
#pragma unroll
    for (int kk = 0; kk < 6; ++kk) {
#pragma unroll
        for (int n = 0; n < 16; ++n) {
            s16x8 bf = *(const s16x8*)&Klds[(n * 16 + (lane & 15)) * 200 + kk * 32 + (lane >> 4) * 8];
            sc[n] = __builtin_amdgcn_mfma_f32_16x16x32_bf16(qf[kk], bf, sc[n], 0, 0, 0);
        }
    }

    int lq = (lane >> 4) * 4;
#pragma unroll
    for (int n = 0; n < 16; ++n) {
        int sk = n * 16 + (lane & 15);
        int yk = sk >> 4, xk = sk & 15;
#pragma unroll
        for (int r = 0; r < 4; ++r) {
            int sq = q0 + lq + r;
            int dy = (sq >> 4) - yk, dx = (sq & 15) - xk;
            bool keep = glob || (dy * dy + dx * dx) < 7;
            sc[n][r] = keep ? sc[n][r] * ATT_SCALE : -1e30f;
        }
    }
    float rmax[4], rsum[4];
#pragma unroll
    for (int r = 0; r < 4; ++r) {
        float m = sc[0][r];
#pragma unroll
        for (int n = 1; n < 16; ++n) m = fmaxf(m, sc[n][r]);
#pragma unroll
        for (int msk = 1; msk < 16; msk <<= 1) m = fmaxf(m, __shfl_xor(m, msk));
        rmax[r] = m;
    }
#pragma unroll
    for (int r = 0; r < 4; ++r) {
        float e = 0.f;
#pragma unroll
        for (int n = 0; n < 16; ++n) { float p = expf(sc[n][r] - rmax[r]); sc[n][r] = p; e += p; }
#pragma unroll
        for (int msk = 1; msk < 16; msk <<= 1) e += __shfl_xor(e, msk);
        rsum[r] = 1.0f / e;
    }

    f32x4 o[12];
#pragma unroll
    for (int n = 0; n < 12; ++n) o[n] = (f32x4){0.f, 0.f, 0.f, 0.f};
    unsigned short* Pw = &Plds[wave * 1152];
    for (int kt = 0; kt < 4; ++kt) {
#pragma unroll
        for (int nn = 0; nn < 4; ++nn) {
#pragma unroll
            for (int r = 0; r < 4; ++r)
                Pw[(lq + r) * 72 + nn * 16 + (lane & 15)] = f2bf(sc[kt * 4 + nn][r] * rsum[r]);
        }
        __syncthreads();
        for (int c = tid; c < 1536; c += 512) {
            int r = c >> 3, col = c & 7;
            *(u16x8*)&Vlds[r * 72 + col * 8] = *(const u16x8*)(vtb + (size_t)r * 256 + kt * 64 + col * 8);
        }
        __syncthreads();
        s16x8 af[2];
#pragma unroll
        for (int kk2 = 0; kk2 < 2; ++kk2)
            af[kk2] = *(const s16x8*)&Pw[(lane & 15) * 72 + kk2 * 32 + (lane >> 4) * 8];
#pragma unroll
        for (int n = 0; n < 12; ++n) {
#pragma unroll
            for (int kk2 = 0; kk2 < 2; ++kk2) {
                s16x8 bf = *(const s16x8*)&Vlds[(n * 16 + (lane & 15)) * 72 + kk2 * 32 + (lane >> 4) * 8];
                o[n] = __builtin_amdgcn_mfma_f32_16x16x32_bf16(af[kk2], bf, o[n], 0, 0, 0);
            }
        }
    }
#pragma unroll
    for (int n = 0; n < 12; ++n) {
        int d = n * 16 + (lane & 15);
#pragma unroll
        for (int r = 0; r < 4; ++r) {
            int sq = q0 + lq + r;
            attnb[((size_t)(b * 256 + sq)) * 768 + hh * 192 + d] = f2bf(o[n][r]);
        }
    }
}

__global__ __launch_bounds__(768) void scalef_kernel(const float* __restrict__ spins,
                                                     const float* __restrict__ sd1_w,
                                                     const float* __restrict__ sd1_b,
                                                     const float* __restrict__ sd2_w,
                                                     const float* __restrict__ sd2_b,
                                                     float* __restrict__ scalef) {
    int b = blockIdx.x, t = threadIdx.x;
    __shared__ float hid[768];
    __shared__ float sp[8];
    if (t < 8) sp[t] = spins[b * 8 + t];
    __syncthreads();
    float acc = sd1_b[t];
#pragma unroll
    for (int i = 0; i < 8; ++i) acc += sp[i] * sd1_w[i * 768 + t];
    hid[t] = acc * sigmoidf_(acc);
    __syncthreads();
    if (t < 12) {
        float o = sd2_b[t];
        for (int d = 0; d < 768; ++d) o += hid[d] * sd2_w[d * 12 + t];
        scalef[b * 12 + t] = expf(o);
    }
}

// head: wave-per-row, lane owns 12 contiguous d; also emits rowlam = x.lam_w
__global__ __launch_bounds__(256) void head_kernel(const unsigned short* __restrict__ xn,
                                                   const float* __restrict__ head_w,
                                                   const float* __restrict__ head_b,
                                                   const float* __restrict__ scalef,
                                                   const float* __restrict__ lam_w,
                                                   float* __restrict__ out,
                                                   float* __restrict__ rowlam) {
    __shared__ float hw[768][13];
    __shared__ float red[4][64][14];
    int t = threadIdx.x, wave = t >> 6, lane = t & 63;
    for (int i = t; i < 768 * 12; i += 256) hw[i / 12][i % 12] = head_w[i];
    for (int i = t; i < 768; i += 256) hw[i][12] = lam_w[i];
    __syncthreads();
    int row_base = blockIdx.x * 64;
    for (int rr = wave; rr < 64; rr += 4) {
        int row = row_base + rr;
        const unsigned short* xr = xn + (size_t)row * 768 + lane * 12;
        float xv[12];
        u16x4 v0 = *(const u16x4*)(xr);
        u16x4 v1 = *(const u16x4*)(xr + 4);
        u16x4 v2 = *(const u16x4*)(xr + 8);
#pragma unroll
        for (int j = 0; j < 4; ++j) { xv[j] = b2f(v0[j]); xv[4 + j] = b2f(v1[j]); xv[8 + j] = b2f(v2[j]); }
        float p[13] = {};
        int d0 = lane * 12;
#pragma unroll
        for (int dd = 0; dd < 12; ++dd) {
            float xvv = xv[dd];
#pragma unroll
            for (int o = 0; o < 12; ++o) p[o] += xvv * hw[d0 + dd][o];
            p[12] += xvv * hw[d0 + dd][12];
        }
#pragma unroll
        for (int o = 0; o < 13; ++o) red[wave][lane][o] = p[o];
        __syncthreads();
        if (lane < 13) {
            float s = 0.f;
            for (int i = 0; i < 64; ++i) s += red[wave][i][lane];
            if (lane < 12) {
                int b = row >> 8, sidx = row & 255;
                float v = (s + head_b[lane]) * scalef[b * 12 + lane];
                int c = lane >> 2, py = (lane >> 1) & 1, px = lane & 1;
                int gy = sidx >> 4, gxx = sidx & 15;
                out[(((size_t)b * 3 + c) * 32 + 2 * gy + py) * 32 + 2 * gxx + px] = v;
            } else {
                rowlam[row] = s;
            }
        }
        __syncthreads();
    }
}

__global__ __launch_bounds__(256) void lpred_kernel(const float* __restrict__ rowlam,
                                                    const float* __restrict__ lam_b,
                                                    float* __restrict__ out) {
    int b = blockIdx.x, t = threadIdx.x;
    __shared__ float red[256];
    red[t] = rowlam[b * 256 + t];
    __syncthreads();
    for (int s2 = 128; s2 > 0; s2 >>= 1) { if (t < s2) red[t] += red[t + s2]; __syncthreads(); }
    if (t == 0) out[196608 + b] = red[0] / 256.0f + lam_b[0];
}

// ---------------------------------------------------------------------------
extern "C" void kernel_launch(void* const* d_in, const int* in_sizes, int n_in,
                              void* d_out, int out_size, void* d_ws, size_t ws_size,
                              hipStream_t stream) {
    const float* z_t     = (const float*)d_in[0];
    const float* logsnr  = (const float*)d_in[1];
    const float* qkv_w   = (const float*)d_in[2];
    const float* out_w   = (const float*)d_in[3];
    const float* gate_w  = (const float*)d_in[4];
    const float* gate_b  = (const float*)d_in[5];
    const float* mlpg_w  = (const float*)d_in[6];
    const float* mlpg_b  = (const float*)d_in[7];
    const float* mlpo_w  = (const float*)d_in[8];
    const float* mlpo_b  = (const float*)d_in[9];
    const float* hh_vs   = (const float*)d_in[10];
    const float* patch_w = (const float*)d_in[11];
    const float* patch_b = (const float*)d_in[12];
    const float* head_w  = (const float*)d_in[13];
    const float* head_b  = (const float*)d_in[14];
    const float* sd1_w   = (const float*)d_in[15];
    const float* sd1_b   = (const float*)d_in[16];
    const float* sd2_w   = (const float*)d_in[17];
    const float* sd2_b   = (const float*)d_in[18];
    const float* lam_w   = (const float*)d_in[19];
    const float* lam_b   = (const float*)d_in[20];

    char* wsb = (char*)d_ws;
    float* spins  = (float*)(wsb + B_SPINS);
    float* scalef = (float*)(wsb + B_SCALEF);
    float* qt     = (float*)(wsb + B_QT);
    float* cosb   = (float*)(wsb + B_COS);
    float* sinb   = (float*)(wsb + B_SIN);
    float* Gm     = (float*)(wsb + B_G);
    float* Tm     = (float*)(wsb + B_T);
    float* Am     = (float*)(wsb + B_AWY);
    float* rowlam = (float*)(wsb + B_ROWLAM);
    float* x      = (float*)(wsb + B_X);
    unsigned short* h      = (unsigned short*)(wsb + B_H);
    unsigned short* proj   = (unsigned short*)(wsb + B_PROJ);
    unsigned short* weff_t = (unsigned short*)(wsb + B_WEFFT);
    unsigned short* outw_t = (unsigned short*)(wsb + B_OUTWT);
    unsigned short* gatew_t= (unsigned short*)(wsb + B_GATEWT);
    unsigned short* mlpg_t = (unsigned short*)(wsb + B_MLPGT);
    unsigned short* mlpo_t = (unsigned short*)(wsb + B_MLPOT);
    unsigned short* arena  = (unsigned short*)(wsb + B_ARENA);
    unsigned short* qbuf = arena;
    unsigned short* kbuf = arena + ARENA_K;
    unsigned short* vtbuf = arena + 2 * ARENA_K;
    unsigned short* attnb = arena + 3 * ARENA_K;
    unsigned short* hidden = arena;
    float* weff_f = (float*)(wsb + B_ARENA);
    float* out = (float*)d_out;

    // ---- setup ----
    spins_kernel<<<1, 64, 0, stream>>>(logsnr, spins);
    rope_table_kernel<<<256, 192, 0, stream>>>(cosb, sinb);
    hh_gram_kernel<<<8, 256, 0, stream>>>(hh_vs, Gm);
    hh_t_kernel<<<8, 128, 0, stream>>>(Gm, Tm);
    hh_a_kernel<<<8, 256, 0, stream>>>(Tm, hh_vs, Am);
    hh_p_kernel<<<8, 256, 0, stream>>>(hh_vs, Am, qt);
    hipMemcpyAsync(weff_f, qkv_w, (size_t)Ll * Dd * 3 * Dd * sizeof(float),
                   hipMemcpyDeviceToDevice, stream);
    fold_kernel<<<dim3(3, 12, 64), 256, 0, stream>>>(qkv_w, qt, weff_f);
    transpose_bf16_kernel<<<dim3(72, 24, 8), 256, 0, stream>>>(weff_f, weff_t, 768, 2304);
    transpose_bf16_kernel<<<dim3(24, 24, 8), 256, 0, stream>>>(out_w, outw_t, 768, 768);
    transpose_bf16_kernel<<<dim3(24, 24, 8), 256, 0, stream>>>(gate_w, gatew_t, 768, 768);
    transpose_bf16_kernel<<<dim3(192, 24, 8), 256, 0, stream>>>(mlpg_w, mlpg_t, 768, 6144);
    transpose_bf16_kernel<<<dim3(24, 96, 8), 256, 0, stream>>>(mlpo_w, mlpo_t, 3072, 768);
    patch_embed_kernel<<<M_TOK, 256, 0, stream>>>(z_t, spins, patch_w, patch_b, x);

    for (int l = 0; l < Ll; ++l) {
        int glob = ((l + 1) % 4 == 0) ? 1 : 0;
        rmsnorm_kernel<<<4096, 256, 0, stream>>>(x, h);
        gemm_mfma<1><<<dim3(18, 128), 256, 0, stream>>>(h, 768,
            weff_t + (size_t)l * 2304 * 768, 768, arena, 0, 768, nullptr, nullptr, nullptr);
        rope_kernel<<<12288, 256, 0, stream>>>(arena, cosb, sinb);
        attn_mfma_kernel<<<dim3(2, 4, 64), 512, 0, stream>>>(qbuf, kbuf, vtbuf, attnb, glob);
        gemm_mfma<0><<<dim3(6, 128), 256, 0, stream>>>(attnb, 768,
            outw_t + (size_t)l * 768 * 768, 768, proj, 768, 768, nullptr, nullptr, nullptr);
        gemm_mfma<2><<<dim3(6, 128), 256, 0, stream>>>(proj, 768,
            gatew_t + (size_t)l * 768 * 768, 768, nullptr, 768, 768,
            gate_b + (size_t)l * 768, x, proj);
        rmsnorm_kernel<<<4096, 256, 0, stream>>>(x, h);
        gemm_mfma<0><<<dim3(24, 128), 256, 0, stream>>>(h, 768,
            mlpg_t + (size_t)l * 6144 * 768, 768, hidden, 3072, 768,
            mlpg_b + (size_t)l * 6144, nullptr, nullptr);
        gemm_mfma<3><<<dim3(24, 128), 256, 0, stream>>>(h, 768,
            mlpg_t + (size_t)l * 6144 * 768 + (size_t)3072 * 768, 768, hidden, 3072, 768,
            mlpg_b + (size_t)l * 6144 + 3072, nullptr, nullptr);
        gemm_mfma<4><<<dim3(6, 128), 256, 0, stream>>>(hidden, 3072,
            mlpo_t + (size_t)l * 768 * 3072, 3072, nullptr, 768, 3072,
            mlpo_b + (size_t)l * 768, x, nullptr);
    }

    rmsnorm_kernel<<<4096, 256, 0, stream>>>(x, h);
    scalef_kernel<<<64, 768, 0, stream>>>(spins, sd1_w, sd1_b, sd2_w, sd2_b, scalef);
    head_kernel<<<256, 256, 0, stream>>>(h, head_w, head_b, scalef, lam_w, out, rowlam);
    lpred_kernel<<<64, 256, 0, stream>>>(rowlam, lam_b, out);
}

// Round 5
// 6410.233 us; speedup vs baseline: 1.3232x; 1.3232x over previous
//
#include <hip/hip_runtime.h>
#include <hip/hip_bf16.h>
#include <math.h>

// ---------------------------------------------------------------------------
// HybridGemmaDiT forward.  B=64, S=256 (16x16), D=768, L=8, NH=4, HD=192.
// R5: revert GEMM to proven BK=32 (R3) structure; fuse mlpg pair into one
//     gelu-fused GEMM (g never hits memory); keep R4 head/rmsnorm/lpred.
// ---------------------------------------------------------------------------

#define DEV static __device__ __forceinline__

typedef float    f32x4 __attribute__((ext_vector_type(4)));
typedef short    s16x8 __attribute__((ext_vector_type(8)));
typedef unsigned short u16x8 __attribute__((ext_vector_type(8)));
typedef unsigned short u16x4 __attribute__((ext_vector_type(4)));

constexpr int Bb = 64, Ss = 256, Dd = 768, Ll = 8, NHh = 4, HDd = 192;
constexpr int M_TOK = Bb * Ss;                 // 16384
constexpr float EPS_RMS = 1.1920929e-07f;
constexpr float ATT_SCALE = 0.07216878364870322f;  // 1/sqrt(192)
constexpr size_t ARENA_K = (size_t)Bb * NHh * Ss * HDd;   // 12,582,912 elems

// ---- workspace layout (BYTES) ---------------------------------------------
constexpr size_t B_SPINS  = 0;
constexpr size_t B_SCALEF = 2048;
constexpr size_t B_QT     = 5120;                        // 8*192*192 f32
constexpr size_t B_COS    = B_QT + 1179648;
constexpr size_t B_SIN    = B_COS + 196608;
constexpr size_t B_G      = B_SIN + 196608;              // 8*96*96 f32
constexpr size_t B_T      = B_G + 294912;
constexpr size_t B_AWY    = B_T + 294912;                // 8*96*192 f32
constexpr size_t B_ROWLAM = B_AWY + 589824;              // 16384 f32
constexpr size_t B_X      = B_ROWLAM + 65536;            // 16384*768 f32
constexpr size_t B_H      = B_X + 50331648;              // bf16
constexpr size_t B_PROJ   = B_H + 25165824;              // bf16
constexpr size_t B_WEFFT  = B_PROJ + 25165824;           // 8*2304*768 bf16
constexpr size_t B_OUTWT  = B_WEFFT + 28311552;
constexpr size_t B_GATEWT = B_OUTWT + 9437184;
constexpr size_t B_MLPGT  = B_GATEWT + 9437184;          // 8*6144*768 bf16
constexpr size_t B_MLPOT  = B_MLPGT + 75497472;          // 8*768*3072 bf16
constexpr size_t B_ARENA  = B_MLPOT + 37748736;          // q,k,v^T,attn bf16 | hidden | weff_f32

DEV float sigmoidf_(float x) { return 1.0f / (1.0f + expf(-x)); }
DEV float geluf_(float g)    { return 0.5f * g * (1.0f + erff(g * 0.7071067811865476f)); }
DEV unsigned short f2bf(float f) {
    union { float f; unsigned u; } a; a.f = f;
    unsigned u = a.u + 0x7fffu + ((a.u >> 16) & 1u);
    return (unsigned short)(u >> 16);
}
DEV float b2f(unsigned short u) {
    union { unsigned u; float f; } a; a.u = ((unsigned)u) << 16; return a.f;
}
DEV void gload16(const void* g, void* l) {
    __builtin_amdgcn_global_load_lds((const __attribute__((address_space(1))) void*)g,
                                     (__attribute__((address_space(3))) void*)l, 16, 0, 0);
}

// ---------------------------------------------------------------------------
__global__ void spins_kernel(const float* __restrict__ logsnr, float* __restrict__ spins) {
    int b = threadIdx.x;
    if (b < 64) {
        float v = logsnr[b];
#pragma unroll
        for (int j = 0; j < 4; ++j) {
            float ang = v * (float)(1 << j);
            spins[b * 8 + j]     = sinf(ang);
            spins[b * 8 + 4 + j] = cosf(ang);
        }
    }
}

__global__ void rope_table_kernel(float* __restrict__ cosb, float* __restrict__ sinb) {
    int s = blockIdx.x, j = threadIdx.x;
    int y = s >> 4, x = s & 15;
    int base = j % 96;
    float coord, invf;
    if (base < 48) { invf = expf(-(float)base * (2.0f / 96.0f) * 9.210340371976184f); coord = (float)y; }
    else { int i = base - 48; invf = expf(-(float)i * (2.0f / 96.0f) * 9.210340371976184f); coord = (float)x; }
    float f = coord * invf, sv, cv;
    sincosf(f, &sv, &cv);
    cosb[s * 192 + j] = cv;
    sinb[s * 192 + j] = sv;
}

// ---- WY householder: qt = P = I - Y T Y^T ---------------------------------
__global__ __launch_bounds__(256) void hh_gram_kernel(const float* __restrict__ hh_vs,
                                                      float* __restrict__ Gm) {
    __shared__ float Y[96][192];
    int l = blockIdx.x, t = threadIdx.x;
    const float4* src = (const float4*)(hh_vs + (size_t)l * 96 * 192);
    for (int i = t; i < 4608; i += 256) ((float4*)&Y[0][0])[i] = src[i];
    __syncthreads();
    for (int e = t; e < 9216; e += 256) {
        int i = e / 96, j = e - (e / 96) * 96;
        float acc = 0.f;
        for (int d = 0; d < 48; ++d) {
            float4 a = *(const float4*)&Y[i][d * 4];
            float4 b = *(const float4*)&Y[j][d * 4];
            acc += a.x * b.x + a.y * b.y + a.z * b.z + a.w * b.w;
        }
        Gm[(size_t)l * 9216 + e] = acc;
    }
}

__global__ __launch_bounds__(128) void hh_t_kernel(const float* __restrict__ Gm,
                                                   float* __restrict__ Tm) {
    __shared__ float G[96][96];
    __shared__ float T[96][100];
    int l = blockIdx.x, t = threadIdx.x;
    const float* Gl = Gm + (size_t)l * 9216;
    for (int i = t; i < 9216; i += 128) { G[i / 96][i % 96] = Gl[i]; }
    for (int i = t; i < 9600; i += 128) { T[i / 100][i % 100] = 0.f; }
    __syncthreads();
    if (t < 96) T[t][t] = 2.0f / (G[t][t] + 1e-8f);
    __syncthreads();
    for (int j = 1; j < 96; ++j) {
        if (t < j) {
            float cj = 2.0f / (G[j][j] + 1e-8f);
            float dot = 0.f;
            for (int p = t; p < j; ++p) dot += T[t][p] * G[p][j];
            T[t][j] = -cj * dot;
        }
        __syncthreads();
    }
    for (int i = t; i < 9216; i += 128) Tm[(size_t)l * 9216 + i] = T[i / 96][i % 96];
}

__global__ __launch_bounds__(256) void hh_a_kernel(const float* __restrict__ Tm,
                                                   const float* __restrict__ hh_vs,
                                                   float* __restrict__ Am) {
    __shared__ float T[96][100];
    __shared__ float Y[96][192];
    int l = blockIdx.x, t = threadIdx.x;
    const float* Tl = Tm + (size_t)l * 9216;
    const float4* src = (const float4*)(hh_vs + (size_t)l * 96 * 192);
    for (int i = t; i < 9216; i += 256) T[i / 96][i % 96] = Tl[i];
    for (int i = t; i < 4608; i += 256) ((float4*)&Y[0][0])[i] = src[i];
    __syncthreads();
    for (int idx = t; idx < 4608; idx += 256) {
        int i = idx / 48, e0 = (idx % 48) * 4;
        float4 acc = {0.f, 0.f, 0.f, 0.f};
        for (int j = i; j < 96; ++j) {
            float tv = T[i][j];
            float4 y = *(const float4*)&Y[j][e0];
            acc.x += tv * y.x; acc.y += tv * y.y; acc.z += tv * y.z; acc.w += tv * y.w;
        }
        *(float4*)(Am + (size_t)l * 96 * 192 + (size_t)i * 192 + e0) = acc;
    }
}

__global__ __launch_bounds__(256) void hh_p_kernel(const float* __restrict__ hh_vs,
                                                   const float* __restrict__ Am,
                                                   float* __restrict__ qt) {
    __shared__ float Y[96][192];
    __shared__ float A[96][192];
    int l = blockIdx.x, t = threadIdx.x;
    const float4* ys = (const float4*)(hh_vs + (size_t)l * 96 * 192);
    const float4* as = (const float4*)(Am + (size_t)l * 96 * 192);
    for (int i = t; i < 4608; i += 256) { ((float4*)&Y[0][0])[i] = ys[i]; ((float4*)&A[0][0])[i] = as[i]; }
    __syncthreads();
    for (int idx = t; idx < 9216; idx += 256) {
        int d = idx / 48, e0 = (idx % 48) * 4;
        float4 acc = {0.f, 0.f, 0.f, 0.f};
        for (int i = 0; i < 96; ++i) {
            float yv = Y[i][d];
            float4 a = *(const float4*)&A[i][e0];
            acc.x += yv * a.x; acc.y += yv * a.y; acc.z += yv * a.z; acc.w += yv * a.w;
        }
        acc.x = (d == e0 + 0 ? 1.f : 0.f) - acc.x;
        acc.y = (d == e0 + 1 ? 1.f : 0.f) - acc.y;
        acc.z = (d == e0 + 2 ? 1.f : 0.f) - acc.z;
        acc.w = (d == e0 + 3 ? 1.f : 0.f) - acc.w;
        *(float4*)(qt + (size_t)l * 192 * 192 + (size_t)d * 192 + e0) = acc;
    }
}

// W_eff q/k head-blocks <- qkv_w block @ Q^T (fp32).  grid (3, 12, 64).
__global__ __launch_bounds__(256) void fold_kernel(const float* __restrict__ qkv_w,
                                                   const float* __restrict__ qt,
                                                   float* __restrict__ weff) {
    int z = blockIdx.z;
    int l = z >> 3, which = (z >> 2) & 1, head = z & 3;
    const float* A  = qkv_w + (size_t)l * 768 * 2304 + (size_t)which * 768 + head * 192;
    const float* Bq = qt + (size_t)l * 192 * 192;
    float* C        = weff + (size_t)l * 768 * 2304 + (size_t)which * 768 + head * 192;
    int row0 = blockIdx.y * 64, col0 = blockIdx.x * 64;
    __shared__ float As[64][65];
    __shared__ float Bs[64][65];
    int tid = threadIdx.x, tx = tid & 15, ty = tid >> 4;
    float acc[4][4] = {};
    for (int k0 = 0; k0 < 192; k0 += 64) {
        for (int i = tid; i < 1024; i += 256) {
            int r = i >> 4, kq = i & 15;
            float4 va = *(const float4*)(A + (size_t)(row0 + r) * 2304 + k0 + kq * 4);
            As[kq * 4 + 0][r] = va.x; As[kq * 4 + 1][r] = va.y; As[kq * 4 + 2][r] = va.z; As[kq * 4 + 3][r] = va.w;
        }
        for (int i = tid; i < 1024; i += 256) {
            int r = i >> 4, nq = i & 15;
            float4 vb = *(const float4*)(Bq + (size_t)(k0 + r) * 192 + col0 + nq * 4);
            Bs[r][nq * 4 + 0] = vb.x; Bs[r][nq * 4 + 1] = vb.y; Bs[r][nq * 4 + 2] = vb.z; Bs[r][nq * 4 + 3] = vb.w;
        }
        __syncthreads();
        for (int k = 0; k < 64; ++k) {
            float a[4], bb[4];
#pragma unroll
            for (int m = 0; m < 4; ++m) a[m] = As[k][ty * 4 + m];
#pragma unroll
            for (int n = 0; n < 4; ++n) bb[n] = Bs[k][tx * 4 + n];
#pragma unroll
            for (int m = 0; m < 4; ++m)
#pragma unroll
                for (int n = 0; n < 4; ++n) acc[m][n] = fmaf(a[m], bb[n], acc[m][n]);
        }
        __syncthreads();
    }
#pragma unroll
    for (int m = 0; m < 4; ++m)
#pragma unroll
        for (int n = 0; n < 4; ++n)
            C[(size_t)(row0 + ty * 4 + m) * 2304 + col0 + tx * 4 + n] = acc[m][n];
}

// fp32 [K][N] -> bf16 [N][K]
__global__ __launch_bounds__(256) void transpose_bf16_kernel(const float* __restrict__ W,
                                                             unsigned short* __restrict__ Wt,
                                                             int K, int N) {
    __shared__ float t[32][33];
    size_t zoff = (size_t)blockIdx.z * K * N;
    const float* Wz = W + zoff;
    unsigned short* Wtz = Wt + zoff;
    int k0 = blockIdx.y * 32, n0 = blockIdx.x * 32;
    int tid = threadIdx.x;
    int tr = tid >> 3, tc = tid & 7;
    float4 v = *(const float4*)(Wz + (size_t)(k0 + tr) * N + n0 + tc * 4);
    t[tr][tc * 4 + 0] = v.x; t[tr][tc * 4 + 1] = v.y; t[tr][tc * 4 + 2] = v.z; t[tr][tc * 4 + 3] = v.w;
    __syncthreads();
    u16x4 o;
    o[0] = f2bf(t[tc * 4 + 0][tr]); o[1] = f2bf(t[tc * 4 + 1][tr]);
    o[2] = f2bf(t[tc * 4 + 2][tr]); o[3] = f2bf(t[tc * 4 + 3][tr]);
    *(u16x4*)(Wtz + (size_t)(n0 + tr) * K + k0 + tc * 4) = o;
}

__global__ __launch_bounds__(256) void patch_embed_kernel(const float* __restrict__ z_t,
                                                          const float* __restrict__ spins,
                                                          const float* __restrict__ patch_w,
                                                          const float* __restrict__ patch_b,
                                                          float* __restrict__ x) {
    int bs = blockIdx.x;
    int b = bs >> 8, s = bs & 255;
    int gy = s >> 4, gx = s & 15;
    __shared__ float in20[20];
    int t = threadIdx.x;
    if (t < 12) {
        int c = t >> 2, py = (t >> 1) & 1, px = t & 1;
        in20[t] = z_t[(((size_t)b * 3 + c) * 32 + (2 * gy + py)) * 32 + (2 * gx + px)];
    } else if (t < 20) {
        in20[t] = spins[b * 8 + (t - 12)];
    }
    __syncthreads();
    for (int d = t; d < 768; d += 256) {
        float acc = patch_b[d];
#pragma unroll
        for (int i = 0; i < 20; ++i) acc += in20[i] * patch_w[i * 768 + d];
        x[(size_t)bs * 768 + d] = acc;
    }
}

// wave-per-row rmsnorm: 4 rows/block, lane owns 12 contiguous d
__global__ __launch_bounds__(256) void rmsnorm_kernel(const float* __restrict__ x,
                                                      unsigned short* __restrict__ h) {
    int wave = threadIdx.x >> 6, lane = threadIdx.x & 63;
    int row = blockIdx.x * 4 + wave;
    const float* xr = x + (size_t)row * 768 + lane * 12;
    float4 a = *(const float4*)(xr);
    float4 b = *(const float4*)(xr + 4);
    float4 c = *(const float4*)(xr + 8);
    float ss = a.x*a.x + a.y*a.y + a.z*a.z + a.w*a.w
             + b.x*b.x + b.y*b.y + b.z*b.z + b.w*b.w
             + c.x*c.x + c.y*c.y + c.z*c.z + c.w*c.w;
#pragma unroll
    for (int msk = 1; msk < 64; msk <<= 1) ss += __shfl_xor(ss, msk);
    float sc = 1.0f / sqrtf(ss / 768.0f + EPS_RMS);
    unsigned short* hr = h + (size_t)row * 768 + lane * 12;
    u16x4 o0, o1, o2;
    o0[0]=f2bf(a.x*sc); o0[1]=f2bf(a.y*sc); o0[2]=f2bf(a.z*sc); o0[3]=f2bf(a.w*sc);
    o1[0]=f2bf(b.x*sc); o1[1]=f2bf(b.y*sc); o1[2]=f2bf(b.z*sc); o1[3]=f2bf(b.w*sc);
    o2[0]=f2bf(c.x*sc); o2[1]=f2bf(c.y*sc); o2[2]=f2bf(c.z*sc); o2[3]=f2bf(c.w*sc);
    *(u16x4*)(hr) = o0; *(u16x4*)(hr + 4) = o1; *(u16x4*)(hr + 8) = o2;
}

// ---- bf16 MFMA GEMM (R3-proven): 128x128, BK=32, 4 waves ------------------
// EPI: 0=store bf16(+bias)  1=qkv scatter (V transposed)  2=gate  4=x+=v
template <int EPI>
__global__ __launch_bounds__(256) void gemm_mfma(const unsigned short* __restrict__ A, int lda,
                                                 const unsigned short* __restrict__ Bt, int ldb,
                                                 unsigned short* __restrict__ Cb, int ldc, int K,
                                                 const float* __restrict__ bias,
                                                 float* __restrict__ Xf,
                                                 const unsigned short* __restrict__ Pb) {
    __shared__ unsigned short As[4096];
    __shared__ unsigned short Bs[4096];
    int tid = threadIdx.x;
    int wave = tid >> 6, lane = tid & 63;
    int row0 = blockIdx.y * 128, col0 = blockIdx.x * 128;
    int wm = wave >> 1, wn = wave & 1;
    f32x4 acc[4][4] = {};

    int srow = lane >> 2;
    int ksw = (((lane & 3) ^ (srow & 3)) * 8);
    int lrow = lane & 15;
    int csw = (((lane >> 4) ^ (lane & 3)) * 8);

    for (int k0 = 0; k0 < K; k0 += 32) {
#pragma unroll
        for (int it = 0; it < 2; ++it) {
            int chunk = it * 4 + wave;
            int r = chunk * 16 + srow;
            gload16(A  + (size_t)(row0 + r) * lda + k0 + ksw, &As[chunk * 512]);
            gload16(Bt + (size_t)(col0 + r) * ldb + k0 + ksw, &Bs[chunk * 512]);
        }
        __syncthreads();
        s16x8 af[4], bf[4];
#pragma unroll
        for (int m = 0; m < 4; ++m)
            af[m] = *(const s16x8*)&As[(wm * 64 + m * 16 + lrow) * 32 + csw];
#pragma unroll
        for (int n = 0; n < 4; ++n)
            bf[n] = *(const s16x8*)&Bs[(wn * 64 + n * 16 + lrow) * 32 + csw];
#pragma unroll
        for (int m = 0; m < 4; ++m)
#pragma unroll
            for (int n = 0; n < 4; ++n)
                acc[m][n] = __builtin_amdgcn_mfma_f32_16x16x32_bf16(af[m], bf[n], acc[m][n], 0, 0, 0);
        __syncthreads();
    }

    int lquad = lane >> 4;
#pragma unroll
    for (int m = 0; m < 4; ++m) {
#pragma unroll
        for (int n = 0; n < 4; ++n) {
#pragma unroll
            for (int r = 0; r < 4; ++r) {
                int i = row0 + wm * 64 + m * 16 + lquad * 4 + r;
                int j = col0 + wn * 64 + n * 16 + lrow;
                float v = acc[m][n][r];
                if (bias) v += bias[j];
                if constexpr (EPI == 0) {
                    Cb[(size_t)i * ldc + j] = f2bf(v);
                } else if constexpr (EPI == 1) {
                    int which = j / 768;
                    int rem = j - which * 768;
                    int head = rem / 192;
                    int hd = rem - head * 192;
                    int b = i >> 8, s = i & 255;
                    if (which == 2) {   // V transposed: [bh][d][s]
                        Cb[2 * ARENA_K + (((size_t)(b * 4 + head)) * 192 + hd) * 256 + s] = f2bf(v);
                    } else {
                        Cb[(size_t)which * ARENA_K + (((size_t)(b * 4 + head)) * 256 + s) * 192 + hd] = f2bf(v);
                    }
                } else if constexpr (EPI == 2) {
                    float p = b2f(Pb[(size_t)i * 768 + j]);
                    Xf[(size_t)i * 768 + j] += p * sigmoidf_(v);
                } else if constexpr (EPI == 4) {
                    Xf[(size_t)i * ldc + j] += v;
                }
            }
        }
    }
}

// ---- fused MLP-in GEMM: hidden = gelu(h@Wg+bg) * (h@Wv+bv) ----------------
// tile 128M x 64N (per half), BK=32, 4 waves (2x2), per-wave 4x2 frags x2.
__global__ __launch_bounds__(256) void gemm_mlp_fused(const unsigned short* __restrict__ A,
                                                      const unsigned short* __restrict__ Bt,
                                                      unsigned short* __restrict__ Hid,
                                                      const float* __restrict__ bias) {
    __shared__ unsigned short As[4096];   // 128 x 32
    __shared__ unsigned short Bs[4096];   // g: 64x32 | v: 64x32
    int tid = threadIdx.x;
    int wave = tid >> 6, lane = tid & 63;
    int row0 = blockIdx.y * 128, col0 = blockIdx.x * 64;
    int wm = wave >> 1, wn = wave & 1;
    f32x4 accg[4][2] = {};
    f32x4 accv[4][2] = {};

    int srow = lane >> 2;
    int ksw = (((lane & 3) ^ (srow & 3)) * 8);
    int lrow = lane & 15;
    int csw = (((lane >> 4) ^ (lane & 3)) * 8);

    const unsigned short* Bg = Bt + (size_t)col0 * 768;
    const unsigned short* Bv = Bt + (size_t)(3072 + col0) * 768;

    for (int k0 = 0; k0 < 768; k0 += 32) {
#pragma unroll
        for (int it = 0; it < 2; ++it) {
            int chunk = it * 4 + wave;
            int r = chunk * 16 + srow;
            gload16(A + (size_t)(row0 + r) * 768 + k0 + ksw, &As[chunk * 512]);
        }
        {
            int r = wave * 16 + srow;
            gload16(Bg + (size_t)r * 768 + k0 + ksw, &Bs[wave * 512]);
            gload16(Bv + (size_t)r * 768 + k0 + ksw, &Bs[2048 + wave * 512]);
        }
        __syncthreads();
        s16x8 af[4], bgf[2], bvf[2];
#pragma unroll
        for (int m = 0; m < 4; ++m)
            af[m] = *(const s16x8*)&As[(wm * 64 + m * 16 + lrow) * 32 + csw];
#pragma unroll
        for (int n = 0; n < 2; ++n) {
            bgf[n] = *(const s16x8*)&Bs[(wn * 32 + n * 16 + lrow) * 32 + csw];
            bvf[n] = *(const s16x8*)&Bs[2048 + (wn * 32 + n * 16 + lrow) * 32 + csw];
        }
#pragma unroll
        for (int m = 0; m < 4; ++m)
#pragma unroll
            for (int n = 0; n < 2; ++n) {
                accg[m][n] = __builtin_amdgcn_mfma_f32_16x16x32_bf16(af[m], bgf[n], accg[m][n], 0, 0, 0);
                accv[m][n] = __builtin_amdgcn_mfma_f32_16x16x32_bf16(af[m], bvf[n], accv[m][n], 0, 0, 0);
            }
        __syncthreads();
    }

    int lquad = lane >> 4;
#pragma unroll
    for (int m = 0; m < 4; ++m) {
#pragma unroll
        for (int n = 0; n < 2; ++n) {
#pragma unroll
            for (int r = 0; r < 4; ++r) {
                int i = row0 + wm * 64 + m * 16 + lquad * 4 + r;
                int j = col0 + wn * 32 + n * 16 + lrow;
                float g = accg[m][n][r] + bias[j];
                float v = accv[m][n][r] + bias[3072 + j];
                Hid[(size_t)i * 3072 + j] = f2bf(v * geluf_(g));
            }
        }
    }
}

// in-place RoPE on bf16 [q|k] (131072 rows x 192)
__global__ __launch_bounds__(256) void rope_kernel(unsigned short* __restrict__ qk,
                                                   const float* __restrict__ cosb,
                                                   const float* __restrict__ sinb) {
    int gid = blockIdx.x * 256 + threadIdx.x;
    int row = gid / 24, q4 = gid - row * 24;
    int j0 = q4 * 4;
    int s = row & 255;
    unsigned short* p = qk + (size_t)row * 192;
    u16x4 t1 = *(u16x4*)(p + j0);
    u16x4 t2 = *(u16x4*)(p + 96 + j0);
    u16x4 o1, o2;
#pragma unroll
    for (int i = 0; i < 4; ++i) {
        float a = b2f(t1[i]), b = b2f(t2[i]);
        float c1 = cosb[s * 192 + j0 + i],      s1 = sinb[s * 192 + j0 + i];
        float c2 = cosb[s * 192 + 96 + j0 + i], s2 = sinb[s * 192 + 96 + j0 + i];
        o1[i] = f2bf(a * c1 - b * s1);
        o2[i] = f2bf(b * c2 + a * s2);
    }
    *(u16x4*)(p + j0) = o1;
    *(u16x4*)(p + 96 + j0) = o2;
}

// ---- MFMA attention: grid (2 halves, NH, B), 512 thr (8 waves x 16 qrows) -
__global__ __launch_bounds__(512) void attn_mfma_kernel(const unsigned short* __restrict__ qb_,
                                                        const unsigned short* __restrict__ kb_,
                                                        const unsigned short* __restrict__ vtb_,
                                                        unsigned short* __restrict__ attnb,
                                                        int glob) {
    __shared__ unsigned short Klds[256 * 200];
    __shared__ unsigned short Vlds[192 * 72];
    __shared__ unsigned short Plds[8 * 16 * 72];
    int b = blockIdx.z, hh = blockIdx.y;
    int tid = threadIdx.x;
    int wave = tid >> 6, lane = tid & 63;
    int q0 = blockIdx.x * 128 + wave * 16;
    size_t bh = (size_t)(b * 4 + hh);
    const unsigned short* qb  = qb_  + bh * 49152;
    const unsigned short* kb  = kb_  + bh * 49152;
    const unsigned short* vtb = vtb_ + bh * 49152;

    for (int c = tid; c < 6144; c += 512) {
        int r = c / 24, col = c - (c / 24) * 24;
        *(u16x8*)&Klds[r * 200 + col * 8] = *(const u16x8*)(kb + (size_t)r * 192 + col * 8);
    }
    __syncthreads();

    s16x8 qf[6];
#pragma unroll
    for (int kk = 0; kk < 6; ++kk)
        qf[kk] = *(const s16x8*)(qb + (size_t)(q0 + (lane & 15)) * 192 + kk * 32 + (lane >> 4) * 8);

    f32x4 sc[16];
#pragma unroll
    for (int n = 0; n < 16; ++n) sc[n] = (f32x4){0.f, 0.f, 0.f, 0.f};
#pragma unroll
    for (int kk = 0; kk < 6; ++kk) {
#pragma unroll
        for (int n = 0; n < 16; ++n) {
            s16x8 bf = *(const s16x8*)&Klds[(n * 16 + (lane & 15)) * 200 + kk * 32 + (lane >> 4) * 8];
            sc[n] = __builtin_amdgcn_mfma_f32_16x16x32_bf16(qf[kk], bf, sc[n], 0, 0, 0);
        }
    }

    int lq = (lane >> 4) * 4;
#pragma unroll
    for (int n = 0; n < 16; ++n) {
        int sk = n * 16 + (lane & 15);
        int yk = sk >> 4, xk = sk & 15;
#pragma unroll
        for (int r = 0; r < 4; ++r) {
            int sq = q0 + lq + r;
            int dy = (sq >> 4) - yk, dx = (sq & 15) - xk;
            bool keep = glob || (dy * dy + dx * dx) < 7;
            sc[n][r] = keep ? sc[n][r] * ATT_SCALE : -1e30f;
        }
    }
    float rmax[4], rsum[4];
#pragma unroll
    for (int r = 0; r < 4; ++r) {
        float m = sc[0][r];
#pragma unroll
        for (int n = 1; n < 16; ++n) m = fmaxf(m, sc[n][r]);
#pragma unroll
        for (int msk = 1; msk < 16; msk <<= 1) m = fmaxf(m, __shfl_xor(m, msk));
        rmax[r] = m;
    }
#pragma unroll
    for (int r = 0; r < 4; ++r) {
        float e = 0.f;
#pragma unroll
        for (int n = 0; n < 16; ++n) { float p = expf(sc[n][r] - rmax[r]); sc[n][r] = p; e += p; }
#pragma unroll
        for (int msk = 1; msk < 16; msk <<= 1) e += __shfl_xor(e, msk);
        rsum[r] = 1.0f / e;
    }

    f32x4 o[12];
#pragma unroll
    for (int n = 0; n < 12; ++n) o[n] = (f32x4){0.f, 0.f, 0.f, 0.f};
    unsigned short* Pw = &Plds[wave * 1152];
    for (int kt = 0; kt < 4; ++kt) {
#pragma unroll
        for (int nn = 0; nn < 4; ++nn) {
#pragma unroll
            for (int r = 0; r < 4; ++r)
                Pw[(lq + r) * 72 + nn * 16 + (lane & 15)] = f2bf(sc[kt * 4 + nn][r] * rsum[r]);
        }
        __syncthreads();
        for (int c = tid; c < 1536; c += 512) {
            int r = c >> 3, col = c & 7;
            *(u16x8*)&Vlds[r * 72 + col * 8] = *(const u16x8*)(vtb + (size_t)r * 256 + kt * 64 + col * 8);
        }
        __syncthreads();
        s16x8 af[2];
#pragma unroll
        for (int kk2 = 0; kk2 < 2; ++kk2)
            af[kk2] = *(const s16x8*)&Pw[(lane & 15) * 72 + kk2 * 32 + (lane >> 4) * 8];
#pragma unroll
        for (int n = 0; n < 12; ++n) {
#pragma unroll
            for (int kk2 = 0; kk2 < 2; ++kk2) {
                s16x8 bf = *(const s16x8*)&Vlds[(n * 16 + (lane & 15)) * 72 + kk2 * 32 + (lane >> 4) * 8];
                o[n] = __builtin_amdgcn_mfma_f32_16x16x32_bf16(af[kk2], bf, o[n], 0, 0, 0);
            }
        }
    }
#pragma unroll
    for (int n = 0; n < 12; ++n) {
        int d = n * 16 + (lane & 15);
#pragma unroll
        for (int r = 0; r < 4; ++r) {
            int sq = q0 + lq + r;
            attnb[((size_t)(b * 256 + sq)) * 768 + hh * 192 + d] = f2bf(o[n][r]);
        }
    }
}

__global__ __launch_bounds__(768) void scalef_kernel(const float* __restrict__ spins,
                                                     const float* __restrict__ sd1_w,
                                                     const float* __restrict__ sd1_b,
                                                     const float* __restrict__ sd2_w,
                                                     const float* __restrict__ sd2_b,
                                                     float* __restrict__ scalef) {
    int b = blockIdx.x, t = threadIdx.x;
    __shared__ float hid[768];
    __shared__ float sp[8];
    if (t < 8) sp[t] = spins[b * 8 + t];
    __syncthreads();
    float acc = sd1_b[t];
#pragma unroll
    for (int i = 0; i < 8; ++i) acc += sp[i] * sd1_w[i * 768 + t];
    hid[t] = acc * sigmoidf_(acc);
    __syncthreads();
    if (t < 12) {
        float o = sd2_b[t];
        for (int d = 0; d < 768; ++d) o += hid[d] * sd2_w[d * 12 + t];
        scalef[b * 12 + t] = expf(o);
    }
}

// head: wave-per-row, lane owns 12 contiguous d; also emits rowlam = x.lam_w
__global__ __launch_bounds__(256) void head_kernel(const unsigned short* __restrict__ xn,
                                                   const float* __restrict__ head_w,
                                                   const float* __restrict__ head_b,
                                                   const float* __restrict__ scalef,
                                                   const float* __restrict__ lam_w,
                                                   float* __restrict__ out,
                                                   float* __restrict__ rowlam) {
    __shared__ float hw[768][13];
    __shared__ float red[4][64][14];
    int t = threadIdx.x, wave = t >> 6, lane = t & 63;
    for (int i = t; i < 768 * 12; i += 256) hw[i / 12][i % 12] = head_w[i];
    for (int i = t; i < 768; i += 256) hw[i][12] = lam_w[i];
    __syncthreads();
    int row_base = blockIdx.x * 64;
    for (int rr = wave; rr < 64; rr += 4) {
        int row = row_base + rr;
        const unsigned short* xr = xn + (size_t)row * 768 + lane * 12;
        float xv[12];
        u16x4 v0 = *(const u16x4*)(xr);
        u16x4 v1 = *(const u16x4*)(xr + 4);
        u16x4 v2 = *(const u16x4*)(xr + 8);
#pragma unroll
        for (int j = 0; j < 4; ++j) { xv[j] = b2f(v0[j]); xv[4 + j] = b2f(v1[j]); xv[8 + j] = b2f(v2[j]); }
        float p[13] = {};
        int d0 = lane * 12;
#pragma unroll
        for (int dd = 0; dd < 12; ++dd) {
            float xvv = xv[dd];
#pragma unroll
            for (int o = 0; o < 12; ++o) p[o] += xvv * hw[d0 + dd][o];
            p[12] += xvv * hw[d0 + dd][12];
        }
#pragma unroll
        for (int o = 0; o < 13; ++o) red[wave][lane][o] = p[o];
        __syncthreads();
        if (lane < 13) {
            float s = 0.f;
            for (int i = 0; i < 64; ++i) s += red[wave][i][lane];
            if (lane < 12) {
                int b = row >> 8, sidx = row & 255;
                float v = (s + head_b[lane]) * scalef[b * 12 + lane];
                int c = lane >> 2, py = (lane >> 1) & 1, px = lane & 1;
                int gy = sidx >> 4, gxx = sidx & 15;
                out[(((size_t)b * 3 + c) * 32 + 2 * gy + py) * 32 + 2 * gxx + px] = v;
            } else {
                rowlam[row] = s;
            }
        }
        __syncthreads();
    }
}

__global__ __launch_bounds__(256) void lpred_kernel(const float* __restrict__ rowlam,
                                                    const float* __restrict__ lam_b,
                                                    float* __restrict__ out) {
    int b = blockIdx.x, t = threadIdx.x;
    __shared__ float red[256];
    red[t] = rowlam[b * 256 + t];
    __syncthreads();
    for (int s2 = 128; s2 > 0; s2 >>= 1) { if (t < s2) red[t] += red[t + s2]; __syncthreads(); }
    if (t == 0) out[196608 + b] = red[0] / 256.0f + lam_b[0];
}

// ---------------------------------------------------------------------------
extern "C" void kernel_launch(void* const* d_in, const int* in_sizes, int n_in,
                              void* d_out, int out_size, void* d_ws, size_t ws_size,
                              hipStream_t stream) {
    const float* z_t     = (const float*)d_in[0];
    const float* logsnr  = (const float*)d_in[1];
    const float* qkv_w   = (const float*)d_in[2];
    const float* out_w   = (const float*)d_in[3];
    const float* gate_w  = (const float*)d_in[4];
    const float* gate_b  = (const float*)d_in[5];
    const float* mlpg_w  = (const float*)d_in[6];
    const float* mlpg_b  = (const float*)d_in[7];
    const float* mlpo_w  = (const float*)d_in[8];
    const float* mlpo_b  = (const float*)d_in[9];
    const float* hh_vs   = (const float*)d_in[10];
    const float* patch_w = (const float*)d_in[11];
    const float* patch_b = (const float*)d_in[12];
    const float* head_w  = (const float*)d_in[13];
    const float* head_b  = (const float*)d_in[14];
    const float* sd1_w   = (const float*)d_in[15];
    const float* sd1_b   = (const float*)d_in[16];
    const float* sd2_w   = (const float*)d_in[17];
    const float* sd2_b   = (const float*)d_in[18];
    const float* lam_w   = (const float*)d_in[19];
    const float* lam_b   = (const float*)d_in[20];

    char* wsb = (char*)d_ws;
    float* spins  = (float*)(wsb + B_SPINS);
    float* scalef = (float*)(wsb + B_SCALEF);
    float* qt     = (float*)(wsb + B_QT);
    float* cosb   = (float*)(wsb + B_COS);
    float* sinb   = (float*)(wsb + B_SIN);
    float* Gm     = (float*)(wsb + B_G);
    float* Tm     = (float*)(wsb + B_T);
    float* Am     = (float*)(wsb + B_AWY);
    float* rowlam = (float*)(wsb + B_ROWLAM);
    float* x      = (float*)(wsb + B_X);
    unsigned short* h      = (unsigned short*)(wsb + B_H);
    unsigned short* proj   = (unsigned short*)(wsb + B_PROJ);
    unsigned short* weff_t = (unsigned short*)(wsb + B_WEFFT);
    unsigned short* outw_t = (unsigned short*)(wsb + B_OUTWT);
    unsigned short* gatew_t= (unsigned short*)(wsb + B_GATEWT);
    unsigned short* mlpg_t = (unsigned short*)(wsb + B_MLPGT);
    unsigned short* mlpo_t = (unsigned short*)(wsb + B_MLPOT);
    unsigned short* arena  = (unsigned short*)(wsb + B_ARENA);
    unsigned short* qbuf = arena;
    unsigned short* kbuf = arena + ARENA_K;
    unsigned short* vtbuf = arena + 2 * ARENA_K;
    unsigned short* attnb = arena + 3 * ARENA_K;
    unsigned short* hidden = arena;
    float* weff_f = (float*)(wsb + B_ARENA);
    float* out = (float*)d_out;

    // ---- setup ----
    spins_kernel<<<1, 64, 0, stream>>>(logsnr, spins);
    rope_table_kernel<<<256, 192, 0, stream>>>(cosb, sinb);
    hh_gram_kernel<<<8, 256, 0, stream>>>(hh_vs, Gm);
    hh_t_kernel<<<8, 128, 0, stream>>>(Gm, Tm);
    hh_a_kernel<<<8, 256, 0, stream>>>(Tm, hh_vs, Am);
    hh_p_kernel<<<8, 256, 0, stream>>>(hh_vs, Am, qt);
    hipMemcpyAsync(weff_f, qkv_w, (size_t)Ll * Dd * 3 * Dd * sizeof(float),
                   hipMemcpyDeviceToDevice, stream);
    fold_kernel<<<dim3(3, 12, 64), 256, 0, stream>>>(qkv_w, qt, weff_f);
    transpose_bf16_kernel<<<dim3(72, 24, 8), 256, 0, stream>>>(weff_f, weff_t, 768, 2304);
    transpose_bf16_kernel<<<dim3(24, 24, 8), 256, 0, stream>>>(out_w, outw_t, 768, 768);
    transpose_bf16_kernel<<<dim3(24, 24, 8), 256, 0, stream>>>(gate_w, gatew_t, 768, 768);
    transpose_bf16_kernel<<<dim3(192, 24, 8), 256, 0, stream>>>(mlpg_w, mlpg_t, 768, 6144);
    transpose_bf16_kernel<<<dim3(24, 96, 8), 256, 0, stream>>>(mlpo_w, mlpo_t, 3072, 768);
    patch_embed_kernel<<<M_TOK, 256, 0, stream>>>(z_t, spins, patch_w, patch_b, x);

    for (int l = 0; l < Ll; ++l) {
        int glob = ((l + 1) % 4 == 0) ? 1 : 0;
        rmsnorm_kernel<<<4096, 256, 0, stream>>>(x, h);
        gemm_mfma<1><<<dim3(18, 128), 256, 0, stream>>>(h, 768,
            weff_t + (size_t)l * 2304 * 768, 768, arena, 0, 768, nullptr, nullptr, nullptr);
        rope_kernel<<<12288, 256, 0, stream>>>(arena, cosb, sinb);
        attn_mfma_kernel<<<dim3(2, 4, 64), 512, 0, stream>>>(qbuf, kbuf, vtbuf, attnb, glob);
        gemm_mfma<0><<<dim3(6, 128), 256, 0, stream>>>(attnb, 768,
            outw_t + (size_t)l * 768 * 768, 768, proj, 768, 768, nullptr, nullptr, nullptr);
        gemm_mfma<2><<<dim3(6, 128), 256, 0, stream>>>(proj, 768,
            gatew_t + (size_t)l * 768 * 768, 768, nullptr, 768, 768,
            gate_b + (size_t)l * 768, x, proj);
        rmsnorm_kernel<<<4096, 256, 0, stream>>>(x, h);
        gemm_mlp_fused<<<dim3(48, 128), 256, 0, stream>>>(h,
            mlpg_t + (size_t)l * 6144 * 768, hidden, mlpg_b + (size_t)l * 6144);
        gemm_mfma<4><<<dim3(6, 128), 256, 0, stream>>>(hidden, 3072,
            mlpo_t + (size_t)l * 768 * 3072, 3072, nullptr, 768, 3072,
            mlpo_b + (size_t)l * 768, x, nullptr);
    }

    rmsnorm_kernel<<<4096, 256, 0, stream>>>(x, h);
    scalef_kernel<<<64, 768, 0, stream>>>(spins, sd1_w, sd1_b, sd2_w, sd2_b, scalef);
    head_kernel<<<256, 256, 0, stream>>>(h, head_w, head_b, scalef, lam_w, out, rowlam);
    lpred_kernel<<<64, 256, 0, stream>>>(rowlam, lam_b, out);
}

// Round 6
// 6319.613 us; speedup vs baseline: 1.3422x; 1.0143x over previous
//
#include <hip/hip_runtime.h>
#include <hip/hip_bf16.h>
#include <math.h>

// ---------------------------------------------------------------------------
// HybridGemmaDiT forward.  B=64, S=256 (16x16), D=768, L=8, NH=4, HD=192.
// R6: conflict-free hh_t (transposed T recurrence); RoPE fused into attention
//     loads; fold writes bf16-transposed weights directly (no memcpy/fp32
//     round-trip).  GEMM core = R3-proven BK=32 m97 structure.
// ---------------------------------------------------------------------------

#define DEV static __device__ __forceinline__

typedef float    f32x4 __attribute__((ext_vector_type(4)));
typedef short    s16x8 __attribute__((ext_vector_type(8)));
typedef unsigned short u16x8 __attribute__((ext_vector_type(8)));
typedef unsigned short u16x4 __attribute__((ext_vector_type(4)));

constexpr int Bb = 64, Ss = 256, Dd = 768, Ll = 8, NHh = 4, HDd = 192;
constexpr int M_TOK = Bb * Ss;                 // 16384
constexpr float EPS_RMS = 1.1920929e-07f;
constexpr float ATT_SCALE = 0.07216878364870322f;  // 1/sqrt(192)
constexpr size_t ARENA_K = (size_t)Bb * NHh * Ss * HDd;   // 12,582,912 elems

// ---- workspace layout (BYTES) ---------------------------------------------
constexpr size_t B_SPINS  = 0;
constexpr size_t B_SCALEF = 2048;
constexpr size_t B_QT     = 5120;                        // 8*192*192 f32
constexpr size_t B_COS    = B_QT + 1179648;
constexpr size_t B_SIN    = B_COS + 196608;
constexpr size_t B_G      = B_SIN + 196608;              // 8*96*96 f32
constexpr size_t B_T      = B_G + 294912;
constexpr size_t B_AWY    = B_T + 294912;                // 8*96*192 f32
constexpr size_t B_ROWLAM = B_AWY + 589824;              // 16384 f32
constexpr size_t B_X      = B_ROWLAM + 65536;            // 16384*768 f32
constexpr size_t B_H      = B_X + 50331648;              // bf16
constexpr size_t B_PROJ   = B_H + 25165824;              // bf16
constexpr size_t B_WEFFT  = B_PROJ + 25165824;           // 8*2304*768 bf16
constexpr size_t B_OUTWT  = B_WEFFT + 28311552;
constexpr size_t B_GATEWT = B_OUTWT + 9437184;
constexpr size_t B_MLPGT  = B_GATEWT + 9437184;          // 8*6144*768 bf16
constexpr size_t B_MLPOT  = B_MLPGT + 75497472;          // 8*768*3072 bf16
constexpr size_t B_ARENA  = B_MLPOT + 37748736;          // q,k,v^T,attn bf16 | hidden

DEV float sigmoidf_(float x) { return 1.0f / (1.0f + expf(-x)); }
DEV float geluf_(float g)    { return 0.5f * g * (1.0f + erff(g * 0.7071067811865476f)); }
DEV unsigned short f2bf(float f) {
    union { float f; unsigned u; } a; a.f = f;
    unsigned u = a.u + 0x7fffu + ((a.u >> 16) & 1u);
    return (unsigned short)(u >> 16);
}
DEV float b2f(unsigned short u) {
    union { unsigned u; float f; } a; a.u = ((unsigned)u) << 16; return a.f;
}
DEV void gload16(const void* g, void* l) {
    __builtin_amdgcn_global_load_lds((const __attribute__((address_space(1))) void*)g,
                                     (__attribute__((address_space(3))) void*)l, 16, 0, 0);
}

// ---------------------------------------------------------------------------
__global__ void spins_kernel(const float* __restrict__ logsnr, float* __restrict__ spins) {
    int b = threadIdx.x;
    if (b < 64) {
        float v = logsnr[b];
#pragma unroll
        for (int j = 0; j < 4; ++j) {
            float ang = v * (float)(1 << j);
            spins[b * 8 + j]     = sinf(ang);
            spins[b * 8 + 4 + j] = cosf(ang);
        }
    }
}

__global__ void rope_table_kernel(float* __restrict__ cosb, float* __restrict__ sinb) {
    int s = blockIdx.x, j = threadIdx.x;
    int y = s >> 4, x = s & 15;
    int base = j % 96;
    float coord, invf;
    if (base < 48) { invf = expf(-(float)base * (2.0f / 96.0f) * 9.210340371976184f); coord = (float)y; }
    else { int i = base - 48; invf = expf(-(float)i * (2.0f / 96.0f) * 9.210340371976184f); coord = (float)x; }
    float f = coord * invf, sv, cv;
    sincosf(f, &sv, &cv);
    cosb[s * 192 + j] = cv;
    sinb[s * 192 + j] = sv;
}

// ---- WY householder: qt = Q^T = I - Y^T T Y -------------------------------
__global__ __launch_bounds__(256) void hh_gram_kernel(const float* __restrict__ hh_vs,
                                                      float* __restrict__ Gm) {
    __shared__ float Y[96][192];
    int l = blockIdx.x, t = threadIdx.x;
    const float4* src = (const float4*)(hh_vs + (size_t)l * 96 * 192);
    for (int i = t; i < 4608; i += 256) ((float4*)&Y[0][0])[i] = src[i];
    __syncthreads();
    for (int e = t; e < 9216; e += 256) {
        int i = e / 96, j = e - (e / 96) * 96;
        float acc = 0.f;
        for (int d = 0; d < 48; ++d) {
            float4 a = *(const float4*)&Y[i][d * 4];
            float4 b = *(const float4*)&Y[j][d * 4];
            acc += a.x * b.x + a.y * b.y + a.z * b.z + a.w * b.w;
        }
        Gm[(size_t)l * 9216 + e] = acc;
    }
}

// T recurrence, TRANSPOSED storage Tt[j][i] = T[i][j] (conflict-free reads)
__global__ __launch_bounds__(128) void hh_t_kernel(const float* __restrict__ Gm,
                                                   float* __restrict__ Tm) {
    __shared__ float G[96][96];
    __shared__ float Tt[96][96];
    int l = blockIdx.x, t = threadIdx.x;
    const float* Gl = Gm + (size_t)l * 9216;
    for (int i = t; i < 9216; i += 128) { ((float*)G)[i] = Gl[i]; ((float*)Tt)[i] = 0.f; }
    __syncthreads();
    if (t < 96) Tt[t][t] = 2.0f / (G[t][t] + 1e-8f);
    __syncthreads();
    for (int j = 1; j < 96; ++j) {
        if (t < j) {
            float cj = 2.0f / (G[j][j] + 1e-8f);
            float dot = 0.f;
            for (int p = t; p < j; ++p) dot += Tt[p][t] * G[p][j];   // Tt[p][t]: lane-consecutive
            Tt[j][t] = -cj * dot;
        }
        __syncthreads();
    }
    for (int i = t; i < 9216; i += 128) Tm[(size_t)l * 9216 + i] = ((float*)Tt)[i];
}

// A[i][e] = sum_{j>=i} T[i][j] Y[j][e] = sum_j Tt[j][i] Y[j][e]
__global__ __launch_bounds__(256) void hh_a_kernel(const float* __restrict__ Tm,
                                                   const float* __restrict__ hh_vs,
                                                   float* __restrict__ Am) {
    __shared__ float T[96][96];    // Tt layout [j][i]
    __shared__ float Y[96][192];
    int l = blockIdx.x, t = threadIdx.x;
    const float* Tl = Tm + (size_t)l * 9216;
    const float4* src = (const float4*)(hh_vs + (size_t)l * 96 * 192);
    for (int i = t; i < 9216; i += 256) ((float*)T)[i] = Tl[i];
    for (int i = t; i < 4608; i += 256) ((float4*)&Y[0][0])[i] = src[i];
    __syncthreads();
    for (int idx = t; idx < 4608; idx += 256) {
        int i = idx / 48, e0 = (idx % 48) * 4;
        float4 acc = {0.f, 0.f, 0.f, 0.f};
        for (int j = i; j < 96; ++j) {
            float tv = T[j][i];
            float4 y = *(const float4*)&Y[j][e0];
            acc.x += tv * y.x; acc.y += tv * y.y; acc.z += tv * y.z; acc.w += tv * y.w;
        }
        *(float4*)(Am + (size_t)l * 96 * 192 + (size_t)i * 192 + e0) = acc;
    }
}

__global__ __launch_bounds__(256) void hh_p_kernel(const float* __restrict__ hh_vs,
                                                   const float* __restrict__ Am,
                                                   float* __restrict__ qt) {
    __shared__ float Y[96][192];
    __shared__ float A[96][192];
    int l = blockIdx.x, t = threadIdx.x;
    const float4* ys = (const float4*)(hh_vs + (size_t)l * 96 * 192);
    const float4* as = (const float4*)(Am + (size_t)l * 96 * 192);
    for (int i = t; i < 4608; i += 256) { ((float4*)&Y[0][0])[i] = ys[i]; ((float4*)&A[0][0])[i] = as[i]; }
    __syncthreads();
    for (int idx = t; idx < 9216; idx += 256) {
        int d = idx / 48, e0 = (idx % 48) * 4;
        float4 acc = {0.f, 0.f, 0.f, 0.f};
        for (int i = 0; i < 96; ++i) {
            float yv = Y[i][d];
            float4 a = *(const float4*)&A[i][e0];
            acc.x += yv * a.x; acc.y += yv * a.y; acc.z += yv * a.z; acc.w += yv * a.w;
        }
        acc.x = (d == e0 + 0 ? 1.f : 0.f) - acc.x;
        acc.y = (d == e0 + 1 ? 1.f : 0.f) - acc.y;
        acc.z = (d == e0 + 2 ? 1.f : 0.f) - acc.z;
        acc.w = (d == e0 + 3 ? 1.f : 0.f) - acc.w;
        *(float4*)(qt + (size_t)l * 192 * 192 + (size_t)d * 192 + e0) = acc;
    }
}

// fold + transpose + bf16 in one: weff_t[n][k] = sum_d qkv_w[k][d] qt[d][n]
// grid (3 n-tiles, 12 k-tiles, 64 = l*8+which*4+head)
__global__ __launch_bounds__(256) void fold_bf16t(const float* __restrict__ qkv_w,
                                                  const float* __restrict__ qt,
                                                  unsigned short* __restrict__ weff_t) {
    int z = blockIdx.z;
    int l = z >> 3, which = (z >> 2) & 1, head = z & 3;
    const float* A  = qkv_w + (size_t)l * 768 * 2304 + (size_t)which * 768 + head * 192;
    const float* Bq = qt + (size_t)l * 192 * 192;
    unsigned short* C = weff_t + (size_t)l * 2304 * 768 + ((size_t)which * 768 + head * 192) * 768;
    int row0 = blockIdx.y * 64, col0 = blockIdx.x * 64;   // row0: k, col0: n
    __shared__ float As[64][65];
    __shared__ float Bs[64][65];
    int tid = threadIdx.x, tx = tid & 15, ty = tid >> 4;
    float acc[4][4] = {};
    for (int k0 = 0; k0 < 192; k0 += 64) {
        for (int i = tid; i < 1024; i += 256) {
            int r = i >> 4, kq = i & 15;
            float4 va = *(const float4*)(A + (size_t)(row0 + r) * 2304 + k0 + kq * 4);
            As[kq * 4 + 0][r] = va.x; As[kq * 4 + 1][r] = va.y; As[kq * 4 + 2][r] = va.z; As[kq * 4 + 3][r] = va.w;
        }
        for (int i = tid; i < 1024; i += 256) {
            int r = i >> 4, nq = i & 15;
            float4 vb = *(const float4*)(Bq + (size_t)(k0 + r) * 192 + col0 + nq * 4);
            Bs[r][nq * 4 + 0] = vb.x; Bs[r][nq * 4 + 1] = vb.y; Bs[r][nq * 4 + 2] = vb.z; Bs[r][nq * 4 + 3] = vb.w;
        }
        __syncthreads();
        for (int k = 0; k < 64; ++k) {
            float a[4], bb[4];
#pragma unroll
            for (int m = 0; m < 4; ++m) a[m] = As[k][ty * 4 + m];
#pragma unroll
            for (int n = 0; n < 4; ++n) bb[n] = Bs[k][tx * 4 + n];
#pragma unroll
            for (int m = 0; m < 4; ++m)
#pragma unroll
                for (int n = 0; n < 4; ++n) acc[m][n] = fmaf(a[m], bb[n], acc[m][n]);
        }
        __syncthreads();
    }
    // transpose through LDS, write bf16 [n][k] coalesced-ish
    float (*Tr)[65] = (float(*)[65])As;
#pragma unroll
    for (int m = 0; m < 4; ++m)
#pragma unroll
        for (int n = 0; n < 4; ++n) Tr[tx * 4 + n][ty * 4 + m] = acc[m][n];
    __syncthreads();
    int nl = tid >> 2, kc = (tid & 3) * 16;
#pragma unroll
    for (int q4 = 0; q4 < 4; ++q4) {
        u16x4 o;
#pragma unroll
        for (int ii = 0; ii < 4; ++ii) o[ii] = f2bf(Tr[nl][kc + q4 * 4 + ii]);
        *(u16x4*)(C + (size_t)(col0 + nl) * 768 + row0 + kc + q4 * 4) = o;
    }
}

// strided fp32 [K][N] -> bf16 [N][K]
__global__ __launch_bounds__(256) void transpose_bf16_kernel(const float* __restrict__ W,
                                                             int ldw, size_t zsrc,
                                                             unsigned short* __restrict__ Wt,
                                                             int ldwt, size_t zdst) {
    __shared__ float t[32][33];
    const float* Wz = W + (size_t)blockIdx.z * zsrc;
    unsigned short* Wtz = Wt + (size_t)blockIdx.z * zdst;
    int k0 = blockIdx.y * 32, n0 = blockIdx.x * 32;
    int tid = threadIdx.x;
    int tr = tid >> 3, tc = tid & 7;
    float4 v = *(const float4*)(Wz + (size_t)(k0 + tr) * ldw + n0 + tc * 4);
    t[tr][tc * 4 + 0] = v.x; t[tr][tc * 4 + 1] = v.y; t[tr][tc * 4 + 2] = v.z; t[tr][tc * 4 + 3] = v.w;
    __syncthreads();
    u16x4 o;
    o[0] = f2bf(t[tc * 4 + 0][tr]); o[1] = f2bf(t[tc * 4 + 1][tr]);
    o[2] = f2bf(t[tc * 4 + 2][tr]); o[3] = f2bf(t[tc * 4 + 3][tr]);
    *(u16x4*)(Wtz + (size_t)(n0 + tr) * ldwt + k0 + tc * 4) = o;
}

__global__ __launch_bounds__(256) void patch_embed_kernel(const float* __restrict__ z_t,
                                                          const float* __restrict__ spins,
                                                          const float* __restrict__ patch_w,
                                                          const float* __restrict__ patch_b,
                                                          float* __restrict__ x) {
    int bs = blockIdx.x;
    int b = bs >> 8, s = bs & 255;
    int gy = s >> 4, gx = s & 15;
    __shared__ float in20[20];
    int t = threadIdx.x;
    if (t < 12) {
        int c = t >> 2, py = (t >> 1) & 1, px = t & 1;
        in20[t] = z_t[(((size_t)b * 3 + c) * 32 + (2 * gy + py)) * 32 + (2 * gx + px)];
    } else if (t < 20) {
        in20[t] = spins[b * 8 + (t - 12)];
    }
    __syncthreads();
    for (int d = t; d < 768; d += 256) {
        float acc = patch_b[d];
#pragma unroll
        for (int i = 0; i < 20; ++i) acc += in20[i] * patch_w[i * 768 + d];
        x[(size_t)bs * 768 + d] = acc;
    }
}

// wave-per-row rmsnorm: 4 rows/block, lane owns 12 contiguous d
__global__ __launch_bounds__(256) void rmsnorm_kernel(const float* __restrict__ x,
                                                      unsigned short* __restrict__ h) {
    int wave = threadIdx.x >> 6, lane = threadIdx.x & 63;
    int row = blockIdx.x * 4 + wave;
    const float* xr = x + (size_t)row * 768 + lane * 12;
    float4 a = *(const float4*)(xr);
    float4 b = *(const float4*)(xr + 4);
    float4 c = *(const float4*)(xr + 8);
    float ss = a.x*a.x + a.y*a.y + a.z*a.z + a.w*a.w
             + b.x*b.x + b.y*b.y + b.z*b.z + b.w*b.w
             + c.x*c.x + c.y*c.y + c.z*c.z + c.w*c.w;
#pragma unroll
    for (int msk = 1; msk < 64; msk <<= 1) ss += __shfl_xor(ss, msk);
    float sc = 1.0f / sqrtf(ss / 768.0f + EPS_RMS);
    unsigned short* hr = h + (size_t)row * 768 + lane * 12;
    u16x4 o0, o1, o2;
    o0[0]=f2bf(a.x*sc); o0[1]=f2bf(a.y*sc); o0[2]=f2bf(a.z*sc); o0[3]=f2bf(a.w*sc);
    o1[0]=f2bf(b.x*sc); o1[1]=f2bf(b.y*sc); o1[2]=f2bf(b.z*sc); o1[3]=f2bf(b.w*sc);
    o2[0]=f2bf(c.x*sc); o2[1]=f2bf(c.y*sc); o2[2]=f2bf(c.z*sc); o2[3]=f2bf(c.w*sc);
    *(u16x4*)(hr) = o0; *(u16x4*)(hr + 4) = o1; *(u16x4*)(hr + 8) = o2;
}

// ---- bf16 MFMA GEMM (R3-proven): 128x128, BK=32, 4 waves ------------------
// EPI: 0=store bf16(+bias)  1=qkv scatter (V transposed)  2=gate  4=x+=v
template <int EPI>
__global__ __launch_bounds__(256) void gemm_mfma(const unsigned short* __restrict__ A, int lda,
                                                 const unsigned short* __restrict__ Bt, int ldb,
                                                 unsigned short* __restrict__ Cb, int ldc, int K,
                                                 const float* __restrict__ bias,
                                                 float* __restrict__ Xf,
                                                 const unsigned short* __restrict__ Pb) {
    __shared__ unsigned short As[4096];
    __shared__ unsigned short Bs[4096];
    int tid = threadIdx.x;
    int wave = tid >> 6, lane = tid & 63;
    int row0 = blockIdx.y * 128, col0 = blockIdx.x * 128;
    int wm = wave >> 1, wn = wave & 1;
    f32x4 acc[4][4] = {};

    int srow = lane >> 2;
    int ksw = (((lane & 3) ^ (srow & 3)) * 8);
    int lrow = lane & 15;
    int csw = (((lane >> 4) ^ (lane & 3)) * 8);

    for (int k0 = 0; k0 < K; k0 += 32) {
#pragma unroll
        for (int it = 0; it < 2; ++it) {
            int chunk = it * 4 + wave;
            int r = chunk * 16 + srow;
            gload16(A  + (size_t)(row0 + r) * lda + k0 + ksw, &As[chunk * 512]);
            gload16(Bt + (size_t)(col0 + r) * ldb + k0 + ksw, &Bs[chunk * 512]);
        }
        __syncthreads();
        s16x8 af[4], bf[4];
#pragma unroll
        for (int m = 0; m < 4; ++m)
            af[m] = *(const s16x8*)&As[(wm * 64 + m * 16 + lrow) * 32 + csw];
#pragma unroll
        for (int n = 0; n < 4; ++n)
            bf[n] = *(const s16x8*)&Bs[(wn * 64 + n * 16 + lrow) * 32 + csw];
#pragma unroll
        for (int m = 0; m < 4; ++m)
#pragma unroll
            for (int n = 0; n < 4; ++n)
                acc[m][n] = __builtin_amdgcn_mfma_f32_16x16x32_bf16(af[m], bf[n], acc[m][n], 0, 0, 0);
        __syncthreads();
    }

    int lquad = lane >> 4;
#pragma unroll
    for (int m = 0; m < 4; ++m) {
#pragma unroll
        for (int n = 0; n < 4; ++n) {
#pragma unroll
            for (int r = 0; r < 4; ++r) {
                int i = row0 + wm * 64 + m * 16 + lquad * 4 + r;
                int j = col0 + wn * 64 + n * 16 + lrow;
                float v = acc[m][n][r];
                if (bias) v += bias[j];
                if constexpr (EPI == 0) {
                    Cb[(size_t)i * ldc + j] = f2bf(v);
                } else if constexpr (EPI == 1) {
                    int which = j / 768;
                    int rem = j - which * 768;
                    int head = rem / 192;
                    int hd = rem - head * 192;
                    int b = i >> 8, s = i & 255;
                    if (which == 2) {   // V transposed: [bh][d][s]
                        Cb[2 * ARENA_K + (((size_t)(b * 4 + head)) * 192 + hd) * 256 + s] = f2bf(v);
                    } else {
                        Cb[(size_t)which * ARENA_K + (((size_t)(b * 4 + head)) * 256 + s) * 192 + hd] = f2bf(v);
                    }
                } else if constexpr (EPI == 2) {
                    float p = b2f(Pb[(size_t)i * 768 + j]);
                    Xf[(size_t)i * 768 + j] += p * sigmoidf_(v);
                } else if constexpr (EPI == 4) {
                    Xf[(size_t)i * ldc + j] += v;
                }
            }
        }
    }
}

// ---- fused MLP-in GEMM: hidden = gelu(h@Wg+bg) * (h@Wv+bv) ----------------
__global__ __launch_bounds__(256) void gemm_mlp_fused(const unsigned short* __restrict__ A,
                                                      const unsigned short* __restrict__ Bt,
                                                      unsigned short* __restrict__ Hid,
                                                      const float* __restrict__ bias) {
    __shared__ unsigned short As[4096];
    __shared__ unsigned short Bs[4096];
    int tid = threadIdx.x;
    int wave = tid >> 6, lane = tid & 63;
    int row0 = blockIdx.y * 128, col0 = blockIdx.x * 64;
    int wm = wave >> 1, wn = wave & 1;
    f32x4 accg[4][2] = {};
    f32x4 accv[4][2] = {};

    int srow = lane >> 2;
    int ksw = (((lane & 3) ^ (srow & 3)) * 8);
    int lrow = lane & 15;
    int csw = (((lane >> 4) ^ (lane & 3)) * 8);

    const unsigned short* Bg = Bt + (size_t)col0 * 768;
    const unsigned short* Bv = Bt + (size_t)(3072 + col0) * 768;

    for (int k0 = 0; k0 < 768; k0 += 32) {
#pragma unroll
        for (int it = 0; it < 2; ++it) {
            int chunk = it * 4 + wave;
            int r = chunk * 16 + srow;
            gload16(A + (size_t)(row0 + r) * 768 + k0 + ksw, &As[chunk * 512]);
        }
        {
            int r = wave * 16 + srow;
            gload16(Bg + (size_t)r * 768 + k0 + ksw, &Bs[wave * 512]);
            gload16(Bv + (size_t)r * 768 + k0 + ksw, &Bs[2048 + wave * 512]);
        }
        __syncthreads();
        s16x8 af[4], bgf[2], bvf[2];
#pragma unroll
        for (int m = 0; m < 4; ++m)
            af[m] = *(const s16x8*)&As[(wm * 64 + m * 16 + lrow) * 32 + csw];
#pragma unroll
        for (int n = 0; n < 2; ++n) {
            bgf[n] = *(const s16x8*)&Bs[(wn * 32 + n * 16 + lrow) * 32 + csw];
            bvf[n] = *(const s16x8*)&Bs[2048 + (wn * 32 + n * 16 + lrow) * 32 + csw];
        }
#pragma unroll
        for (int m = 0; m < 4; ++m)
#pragma unroll
            for (int n = 0; n < 2; ++n) {
                accg[m][n] = __builtin_amdgcn_mfma_f32_16x16x32_bf16(af[m], bgf[n], accg[m][n], 0, 0, 0);
                accv[m][n] = __builtin_amdgcn_mfma_f32_16x16x32_bf16(af[m], bvf[n], accv[m][n], 0, 0, 0);
            }
        __syncthreads();
    }

    int lquad = lane >> 4;
#pragma unroll
    for (int m = 0; m < 4; ++m) {
#pragma unroll
        for (int n = 0; n < 2; ++n) {
#pragma unroll
            for (int r = 0; r < 4; ++r) {
                int i = row0 + wm * 64 + m * 16 + lquad * 4 + r;
                int j = col0 + wn * 32 + n * 16 + lrow;
                float g = accg[m][n][r] + bias[j];
                float v = accv[m][n][r] + bias[3072 + j];
                Hid[(size_t)i * 3072 + j] = f2bf(v * geluf_(g));
            }
        }
    }
}

// ---- MFMA attention with fused RoPE: grid (2, NH, B), 512 thr -------------
__global__ __launch_bounds__(512) void attn_mfma_kernel(const unsigned short* __restrict__ qb_,
                                                        const unsigned short* __restrict__ kb_,
                                                        const unsigned short* __restrict__ vtb_,
                                                        unsigned short* __restrict__ attnb,
                                                        const float* __restrict__ cosb,
                                                        const float* __restrict__ sinb,
                                                        int glob) {
    __shared__ unsigned short Klds[256 * 200];
    __shared__ unsigned short Vlds[192 * 72];
    __shared__ unsigned short Plds[8 * 16 * 72];
    int b = blockIdx.z, hh = blockIdx.y;
    int tid = threadIdx.x;
    int wave = tid >> 6, lane = tid & 63;
    int q0 = blockIdx.x * 128 + wave * 16;
    size_t bh = (size_t)(b * 4 + hh);
    const unsigned short* qb  = qb_  + bh * 49152;
    const unsigned short* kb  = kb_  + bh * 49152;
    const unsigned short* vtb = vtb_ + bh * 49152;

    // stage K with RoPE applied (rot(k)[j] = k[j]*cos[j] -/+ k[j+-96]*sin[j])
    for (int c = tid; c < 6144; c += 512) {
        int r = c / 24, col = c - (c / 24) * 24;
        int j0 = col * 8;
        int jp = j0 < 96 ? j0 + 96 : j0 - 96;
        float sgn = j0 < 96 ? -1.f : 1.f;
        u16x8 a = *(const u16x8*)(kb + (size_t)r * 192 + j0);
        u16x8 p = *(const u16x8*)(kb + (size_t)r * 192 + jp);
        const float* cr = cosb + r * 192 + j0;
        const float* sr = sinb + r * 192 + j0;
        u16x8 o;
#pragma unroll
        for (int i = 0; i < 8; ++i)
            o[i] = f2bf(b2f(a[i]) * cr[i] + sgn * b2f(p[i]) * sr[i]);
        *(u16x8*)&Klds[r * 200 + j0] = o;
    }
    __syncthreads();

    // Q fragments with RoPE
    s16x8 qf[6];
    {
        int sq = q0 + (lane & 15);
        const unsigned short* qrow = qb + (size_t)sq * 192;
        const float* cr = cosb + sq * 192;
        const float* sr = sinb + sq * 192;
#pragma unroll
        for (int kk = 0; kk < 6; ++kk) {
            int ck = kk * 32 + (lane >> 4) * 8;
            int cp = ck < 96 ? ck + 96 : ck - 96;
            float sgn = ck < 96 ? -1.f : 1.f;
            u16x8 a = *(const u16x8*)(qrow + ck);
            u16x8 p = *(const u16x8*)(qrow + cp);
            s16x8 o;
#pragma unroll
            for (int i = 0; i < 8; ++i)
                o[i] = (short)f2bf(b2f(a[i]) * cr[ck + i] + sgn * b2f(p[i]) * sr[ck + i]);
            qf[kk] = o;
        }
    }

    f32x4 sc[16];
#pragma unroll
    for (int n = 0; n < 16; ++n) sc[n] = (f32x4){0.f, 0.f, 0.f, 0.f};
#pragma unroll
    for (int kk = 0; kk < 6; ++kk) {
#pragma unroll
        for (int n = 0; n < 16; ++n) {
            s16x8 bf = *(const s16x8*)&Klds[(n * 16 + (lane & 15)) * 200 + kk * 32 + (lane >> 4) * 8];
            sc[n] = __builtin_amdgcn_mfma_f32_16x16x32_bf16(qf[kk], bf, sc[n], 0, 0, 0);
        }
    }

    int lq = (lane >> 4) * 4;
#pragma unroll
    for (int n = 0; n < 16; ++n) {
        int sk = n * 16 + (lane & 15);
        int yk = sk >> 4, xk = sk & 15;
#pragma unroll
        for (int r = 0; r < 4; ++r) {
            int sq = q0 + lq + r;
            int dy = (sq >> 4) - yk, dx = (sq & 15) - xk;
            bool keep = glob || (dy * dy + dx * dx) < 7;
            sc[n][r] = keep ? sc[n][r] * ATT_SCALE : -1e30f;
        }
    }
    float rmax[4], rsum[4];
#pragma unroll
    for (int r = 0; r < 4; ++r) {
        float m = sc[0][r];
#pragma unroll
        for (int n = 1; n < 16; ++n) m = fmaxf(m, sc[n][r]);
#pragma unroll
        for (int msk = 1; msk < 16; msk <<= 1) m = fmaxf(m, __shfl_xor(m, msk));
        rmax[r] = m;
    }
#pragma unroll
    for (int r = 0; r < 4; ++r) {
        float e = 0.f;
#pragma unroll
        for (int n = 0; n < 16; ++n) { float p = expf(sc[n][r] - rmax[r]); sc[n][r] = p; e += p; }
#pragma unroll
        for (int msk = 1; msk < 16; msk <<= 1) e += __shfl_xor(e, msk);
        rsum[r] = 1.0f / e;
    }

    f32x4 o[12];
#pragma unroll
    for (int n = 0; n < 12; ++n) o[n] = (f32x4){0.f, 0.f, 0.f, 0.f};
    unsigned short* Pw = &Plds[wave * 1152];
    for (int kt = 0; kt < 4; ++kt) {
#pragma unroll
        for (int nn = 0; nn < 4; ++nn) {
#pragma unroll
            for (int r = 0; r < 4; ++r)
                Pw[(lq + r) * 72 + nn * 16 + (lane & 15)] = f2bf(sc[kt * 4 + nn][r] * rsum[r]);
        }
        __syncthreads();
        for (int c = tid; c < 1536; c += 512) {
            int r = c >> 3, col = c & 7;
            *(u16x8*)&Vlds[r * 72 + col * 8] = *(const u16x8*)(vtb + (size_t)r * 256 + kt * 64 + col * 8);
        }
        __syncthreads();
        s16x8 af[2];
#pragma unroll
        for (int kk2 = 0; kk2 < 2; ++kk2)
            af[kk2] = *(const s16x8*)&Pw[(lane & 15) * 72 + kk2 * 32 + (lane >> 4) * 8];
#pragma unroll
        for (int n = 0; n < 12; ++n) {
#pragma unroll
            for (int kk2 = 0; kk2 < 2; ++kk2) {
                s16x8 bf = *(const s16x8*)&Vlds[(n * 16 + (lane & 15)) * 72 + kk2 * 32 + (lane >> 4) * 8];
                o[n] = __builtin_amdgcn_mfma_f32_16x16x32_bf16(af[kk2], bf, o[n], 0, 0, 0);
            }
        }
    }
#pragma unroll
    for (int n = 0; n < 12; ++n) {
        int d = n * 16 + (lane & 15);
#pragma unroll
        for (int r = 0; r < 4; ++r) {
            int sq = q0 + lq + r;
            attnb[((size_t)(b * 256 + sq)) * 768 + hh * 192 + d] = f2bf(o[n][r]);
        }
    }
}

__global__ __launch_bounds__(768) void scalef_kernel(const float* __restrict__ spins,
                                                     const float* __restrict__ sd1_w,
                                                     const float* __restrict__ sd1_b,
                                                     const float* __restrict__ sd2_w,
                                                     const float* __restrict__ sd2_b,
                                                     float* __restrict__ scalef) {
    int b = blockIdx.x, t = threadIdx.x;
    __shared__ float hid[768];
    __shared__ float sp[8];
    if (t < 8) sp[t] = spins[b * 8 + t];
    __syncthreads();
    float acc = sd1_b[t];
#pragma unroll
    for (int i = 0; i < 8; ++i) acc += sp[i] * sd1_w[i * 768 + t];
    hid[t] = acc * sigmoidf_(acc);
    __syncthreads();
    if (t < 12) {
        float o = sd2_b[t];
        for (int d = 0; d < 768; ++d) o += hid[d] * sd2_w[d * 12 + t];
        scalef[b * 12 + t] = expf(o);
    }
}

// head: wave-per-row, lane owns 12 contiguous d; also emits rowlam = x.lam_w
__global__ __launch_bounds__(256) void head_kernel(const unsigned short* __restrict__ xn,
                                                   const float* __restrict__ head_w,
                                                   const float* __restrict__ head_b,
                                                   const float* __restrict__ scalef,
                                                   const float* __restrict__ lam_w,
                                                   float* __restrict__ out,
                                                   float* __restrict__ rowlam) {
    __shared__ float hw[768][13];
    __shared__ float red[4][64][14];
    int t = threadIdx.x, wave = t >> 6, lane = t & 63;
    for (int i = t; i < 768 * 12; i += 256) hw[i / 12][i % 12] = head_w[i];
    for (int i = t; i < 768; i += 256) hw[i][12] = lam_w[i];
    __syncthreads();
    int row_base = blockIdx.x * 64;
    for (int rr = wave; rr < 64; rr += 4) {
        int row = row_base + rr;
        const unsigned short* xr = xn + (size_t)row * 768 + lane * 12;
        float xv[12];
        u16x4 v0 = *(const u16x4*)(xr);
        u16x4 v1 = *(const u16x4*)(xr + 4);
        u16x4 v2 = *(const u16x4*)(xr + 8);
#pragma unroll
        for (int j = 0; j < 4; ++j) { xv[j] = b2f(v0[j]); xv[4 + j] = b2f(v1[j]); xv[8 + j] = b2f(v2[j]); }
        float p[13] = {};
        int d0 = lane * 12;
#pragma unroll
        for (int dd = 0; dd < 12; ++dd) {
            float xvv = xv[dd];
#pragma unroll
            for (int o = 0; o < 12; ++o) p[o] += xvv * hw[d0 + dd][o];
            p[12] += xvv * hw[d0 + dd][12];
        }
#pragma unroll
        for (int o = 0; o < 13; ++o) red[wave][lane][o] = p[o];
        __syncthreads();
        if (lane < 13) {
            float s = 0.f;
            for (int i = 0; i < 64; ++i) s += red[wave][i][lane];
            if (lane < 12) {
                int b = row >> 8, sidx = row & 255;
                float v = (s + head_b[lane]) * scalef[b * 12 + lane];
                int c = lane >> 2, py = (lane >> 1) & 1, px = lane & 1;
                int gy = sidx >> 4, gxx = sidx & 15;
                out[(((size_t)b * 3 + c) * 32 + 2 * gy + py) * 32 + 2 * gxx + px] = v;
            } else {
                rowlam[row] = s;
            }
        }
        __syncthreads();
    }
}

__global__ __launch_bounds__(256) void lpred_kernel(const float* __restrict__ rowlam,
                                                    const float* __restrict__ lam_b,
                                                    float* __restrict__ out) {
    int b = blockIdx.x, t = threadIdx.x;
    __shared__ float red[256];
    red[t] = rowlam[b * 256 + t];
    __syncthreads();
    for (int s2 = 128; s2 > 0; s2 >>= 1) { if (t < s2) red[t] += red[t + s2]; __syncthreads(); }
    if (t == 0) out[196608 + b] = red[0] / 256.0f + lam_b[0];
}

// ---------------------------------------------------------------------------
extern "C" void kernel_launch(void* const* d_in, const int* in_sizes, int n_in,
                              void* d_out, int out_size, void* d_ws, size_t ws_size,
                              hipStream_t stream) {
    const float* z_t     = (const float*)d_in[0];
    const float* logsnr  = (const float*)d_in[1];
    const float* qkv_w   = (const float*)d_in[2];
    const float* out_w   = (const float*)d_in[3];
    const float* gate_w  = (const float*)d_in[4];
    const float* gate_b  = (const float*)d_in[5];
    const float* mlpg_w  = (const float*)d_in[6];
    const float* mlpg_b  = (const float*)d_in[7];
    const float* mlpo_w  = (const float*)d_in[8];
    const float* mlpo_b  = (const float*)d_in[9];
    const float* hh_vs   = (const float*)d_in[10];
    const float* patch_w = (const float*)d_in[11];
    const float* patch_b = (const float*)d_in[12];
    const float* head_w  = (const float*)d_in[13];
    const float* head_b  = (const float*)d_in[14];
    const float* sd1_w   = (const float*)d_in[15];
    const float* sd1_b   = (const float*)d_in[16];
    const float* sd2_w   = (const float*)d_in[17];
    const float* sd2_b   = (const float*)d_in[18];
    const float* lam_w   = (const float*)d_in[19];
    const float* lam_b   = (const float*)d_in[20];

    char* wsb = (char*)d_ws;
    float* spins  = (float*)(wsb + B_SPINS);
    float* scalef = (float*)(wsb + B_SCALEF);
    float* qt     = (float*)(wsb + B_QT);
    float* cosb   = (float*)(wsb + B_COS);
    float* sinb   = (float*)(wsb + B_SIN);
    float* Gm     = (float*)(wsb + B_G);
    float* Tm     = (float*)(wsb + B_T);
    float* Am     = (float*)(wsb + B_AWY);
    float* rowlam = (float*)(wsb + B_ROWLAM);
    float* x      = (float*)(wsb + B_X);
    unsigned short* h      = (unsigned short*)(wsb + B_H);
    unsigned short* proj   = (unsigned short*)(wsb + B_PROJ);
    unsigned short* weff_t = (unsigned short*)(wsb + B_WEFFT);
    unsigned short* outw_t = (unsigned short*)(wsb + B_OUTWT);
    unsigned short* gatew_t= (unsigned short*)(wsb + B_GATEWT);
    unsigned short* mlpg_t = (unsigned short*)(wsb + B_MLPGT);
    unsigned short* mlpo_t = (unsigned short*)(wsb + B_MLPOT);
    unsigned short* arena  = (unsigned short*)(wsb + B_ARENA);
    unsigned short* qbuf = arena;
    unsigned short* kbuf = arena + ARENA_K;
    unsigned short* vtbuf = arena + 2 * ARENA_K;
    unsigned short* attnb = arena + 3 * ARENA_K;
    unsigned short* hidden = arena;
    float* out = (float*)d_out;

    // ---- setup ----
    spins_kernel<<<1, 64, 0, stream>>>(logsnr, spins);
    rope_table_kernel<<<256, 192, 0, stream>>>(cosb, sinb);
    hh_gram_kernel<<<8, 256, 0, stream>>>(hh_vs, Gm);
    hh_t_kernel<<<8, 128, 0, stream>>>(Gm, Tm);
    hh_a_kernel<<<8, 256, 0, stream>>>(Tm, hh_vs, Am);
    hh_p_kernel<<<8, 256, 0, stream>>>(hh_vs, Am, qt);
    fold_bf16t<<<dim3(3, 12, 64), 256, 0, stream>>>(qkv_w, qt, weff_t);
    transpose_bf16_kernel<<<dim3(24, 24, 8), 256, 0, stream>>>(qkv_w + 1536, 2304,
        (size_t)768 * 2304, weff_t + (size_t)1536 * 768, 768, (size_t)2304 * 768);
    transpose_bf16_kernel<<<dim3(24, 24, 8), 256, 0, stream>>>(out_w, 768,
        (size_t)768 * 768, outw_t, 768, (size_t)768 * 768);
    transpose_bf16_kernel<<<dim3(24, 24, 8), 256, 0, stream>>>(gate_w, 768,
        (size_t)768 * 768, gatew_t, 768, (size_t)768 * 768);
    transpose_bf16_kernel<<<dim3(192, 24, 8), 256, 0, stream>>>(mlpg_w, 6144,
        (size_t)768 * 6144, mlpg_t, 768, (size_t)6144 * 768);
    transpose_bf16_kernel<<<dim3(24, 96, 8), 256, 0, stream>>>(mlpo_w, 768,
        (size_t)3072 * 768, mlpo_t, 3072, (size_t)768 * 3072);
    patch_embed_kernel<<<M_TOK, 256, 0, stream>>>(z_t, spins, patch_w, patch_b, x);

    for (int l = 0; l < Ll; ++l) {
        int glob = ((l + 1) % 4 == 0) ? 1 : 0;
        rmsnorm_kernel<<<4096, 256, 0, stream>>>(x, h);
        gemm_mfma<1><<<dim3(18, 128), 256, 0, stream>>>(h, 768,
            weff_t + (size_t)l * 2304 * 768, 768, arena, 0, 768, nullptr, nullptr, nullptr);
        attn_mfma_kernel<<<dim3(2, 4, 64), 512, 0, stream>>>(qbuf, kbuf, vtbuf, attnb,
            cosb, sinb, glob);
        gemm_mfma<0><<<dim3(6, 128), 256, 0, stream>>>(attnb, 768,
            outw_t + (size_t)l * 768 * 768, 768, proj, 768, 768, nullptr, nullptr, nullptr);
        gemm_mfma<2><<<dim3(6, 128), 256, 0, stream>>>(proj, 768,
            gatew_t + (size_t)l * 768 * 768, 768, nullptr, 768, 768,
            gate_b + (size_t)l * 768, x, proj);
        rmsnorm_kernel<<<4096, 256, 0, stream>>>(x, h);
        gemm_mlp_fused<<<dim3(48, 128), 256, 0, stream>>>(h,
            mlpg_t + (size_t)l * 6144 * 768, hidden, mlpg_b + (size_t)l * 6144);
        gemm_mfma<4><<<dim3(6, 128), 256, 0, stream>>>(hidden, 3072,
            mlpo_t + (size_t)l * 768 * 3072, 3072, nullptr, 768, 3072,
            mlpo_b + (size_t)l * 768, x, nullptr);
    }

    rmsnorm_kernel<<<4096, 256, 0, stream>>>(x, h);
    scalef_kernel<<<64, 768, 0, stream>>>(spins, sd1_w, sd1_b, sd2_w, sd2_b, scalef);
    head_kernel<<<256, 256, 0, stream>>>(h, head_w, head_b, scalef, lam_w, out, rowlam);
    lpred_kernel<<<64, 256, 0, stream>>>(rowlam, lam_b, out);
}

// Round 7
// 6004.883 us; speedup vs baseline: 1.4126x; 1.0524x over previous
//
#include <hip/hip_runtime.h>
#include <hip/hip_bf16.h>
#include <math.h>

// ---------------------------------------------------------------------------
// HybridGemmaDiT forward.  B=64, S=256 (16x16), D=768, L=8, NH=4, HD=192.
// R7: hh_t recurrence with uniform-p loop (G broadcast + Tt consecutive ->
//     zero bank conflicts); XCD-aware bijective block swizzle on the MFMA
//     GEMMs (isolated T1 re-test on the proven BK=32 core).
// ---------------------------------------------------------------------------

#define DEV static __device__ __forceinline__

typedef float    f32x4 __attribute__((ext_vector_type(4)));
typedef short    s16x8 __attribute__((ext_vector_type(8)));
typedef unsigned short u16x8 __attribute__((ext_vector_type(8)));
typedef unsigned short u16x4 __attribute__((ext_vector_type(4)));

constexpr int Bb = 64, Ss = 256, Dd = 768, Ll = 8, NHh = 4, HDd = 192;
constexpr int M_TOK = Bb * Ss;                 // 16384
constexpr float EPS_RMS = 1.1920929e-07f;
constexpr float ATT_SCALE = 0.07216878364870322f;  // 1/sqrt(192)
constexpr size_t ARENA_K = (size_t)Bb * NHh * Ss * HDd;   // 12,582,912 elems

// ---- workspace layout (BYTES) ---------------------------------------------
constexpr size_t B_SPINS  = 0;
constexpr size_t B_SCALEF = 2048;
constexpr size_t B_QT     = 5120;                        // 8*192*192 f32
constexpr size_t B_COS    = B_QT + 1179648;
constexpr size_t B_SIN    = B_COS + 196608;
constexpr size_t B_G      = B_SIN + 196608;              // 8*96*96 f32
constexpr size_t B_T      = B_G + 294912;
constexpr size_t B_AWY    = B_T + 294912;                // 8*96*192 f32
constexpr size_t B_ROWLAM = B_AWY + 589824;              // 16384 f32
constexpr size_t B_X      = B_ROWLAM + 65536;            // 16384*768 f32
constexpr size_t B_H      = B_X + 50331648;              // bf16
constexpr size_t B_PROJ   = B_H + 25165824;              // bf16
constexpr size_t B_WEFFT  = B_PROJ + 25165824;           // 8*2304*768 bf16
constexpr size_t B_OUTWT  = B_WEFFT + 28311552;
constexpr size_t B_GATEWT = B_OUTWT + 9437184;
constexpr size_t B_MLPGT  = B_GATEWT + 9437184;          // 8*6144*768 bf16
constexpr size_t B_MLPOT  = B_MLPGT + 75497472;          // 8*768*3072 bf16
constexpr size_t B_ARENA  = B_MLPOT + 37748736;          // q,k,v^T,attn bf16 | hidden

DEV float sigmoidf_(float x) { return 1.0f / (1.0f + expf(-x)); }
DEV float geluf_(float g)    { return 0.5f * g * (1.0f + erff(g * 0.7071067811865476f)); }
DEV unsigned short f2bf(float f) {
    union { float f; unsigned u; } a; a.f = f;
    unsigned u = a.u + 0x7fffu + ((a.u >> 16) & 1u);
    return (unsigned short)(u >> 16);
}
DEV float b2f(unsigned short u) {
    union { unsigned u; float f; } a; a.u = ((unsigned)u) << 16; return a.f;
}
DEV void gload16(const void* g, void* l) {
    __builtin_amdgcn_global_load_lds((const __attribute__((address_space(1))) void*)g,
                                     (__attribute__((address_space(3))) void*)l, 16, 0, 0);
}

// ---------------------------------------------------------------------------
__global__ void spins_kernel(const float* __restrict__ logsnr, float* __restrict__ spins) {
    int b = threadIdx.x;
    if (b < 64) {
        float v = logsnr[b];
#pragma unroll
        for (int j = 0; j < 4; ++j) {
            float ang = v * (float)(1 << j);
            spins[b * 8 + j]     = sinf(ang);
            spins[b * 8 + 4 + j] = cosf(ang);
        }
    }
}

__global__ void rope_table_kernel(float* __restrict__ cosb, float* __restrict__ sinb) {
    int s = blockIdx.x, j = threadIdx.x;
    int y = s >> 4, x = s & 15;
    int base = j % 96;
    float coord, invf;
    if (base < 48) { invf = expf(-(float)base * (2.0f / 96.0f) * 9.210340371976184f); coord = (float)y; }
    else { int i = base - 48; invf = expf(-(float)i * (2.0f / 96.0f) * 9.210340371976184f); coord = (float)x; }
    float f = coord * invf, sv, cv;
    sincosf(f, &sv, &cv);
    cosb[s * 192 + j] = cv;
    sinb[s * 192 + j] = sv;
}

// ---- WY householder: qt = Q^T = I - Y^T T Y -------------------------------
__global__ __launch_bounds__(256) void hh_gram_kernel(const float* __restrict__ hh_vs,
                                                      float* __restrict__ Gm) {
    __shared__ float Y[96][192];
    int l = blockIdx.x, t = threadIdx.x;
    const float4* src = (const float4*)(hh_vs + (size_t)l * 96 * 192);
    for (int i = t; i < 4608; i += 256) ((float4*)&Y[0][0])[i] = src[i];
    __syncthreads();
    for (int e = t; e < 9216; e += 256) {
        int i = e / 96, j = e - (e / 96) * 96;
        float acc = 0.f;
        for (int d = 0; d < 48; ++d) {
            float4 a = *(const float4*)&Y[i][d * 4];
            float4 b = *(const float4*)&Y[j][d * 4];
            acc += a.x * b.x + a.y * b.y + a.z * b.z + a.w * b.w;
        }
        Gm[(size_t)l * 9216 + e] = acc;
    }
}

// T recurrence, uniform-p loop: G[p][j] broadcast, Tt[p][t] lane-consecutive.
// Tt[j][i] = T[i][j]; upper-right of Tt stays 0 so p<t terms self-cancel.
__global__ __launch_bounds__(128) void hh_t_kernel(const float* __restrict__ Gm,
                                                   float* __restrict__ Tm) {
    __shared__ float G[96][96];
    __shared__ float Tt[96][96];
    int l = blockIdx.x, t = threadIdx.x;
    const float* Gl = Gm + (size_t)l * 9216;
    for (int i = t; i < 9216; i += 128) { ((float*)G)[i] = Gl[i]; ((float*)Tt)[i] = 0.f; }
    __syncthreads();
    if (t < 96) Tt[t][t] = 2.0f / (G[t][t] + 1e-8f);
    __syncthreads();
    for (int j = 1; j < 96; ++j) {
        if (t < 96) {
            float cj = 2.0f / (G[j][j] + 1e-8f);
            float dot = 0.f;
            for (int p = 0; p < j; ++p) dot += Tt[p][t] * G[p][j];  // consecutive * broadcast
            if (t < j) Tt[j][t] = -cj * dot;
        }
        __syncthreads();
    }
    for (int i = t; i < 9216; i += 128) Tm[(size_t)l * 9216 + i] = ((float*)Tt)[i];
}

// A[i][e] = sum_{j>=i} T[i][j] Y[j][e] = sum_j Tt[j][i] Y[j][e]
__global__ __launch_bounds__(256) void hh_a_kernel(const float* __restrict__ Tm,
                                                   const float* __restrict__ hh_vs,
                                                   float* __restrict__ Am) {
    __shared__ float T[96][96];    // Tt layout [j][i]
    __shared__ float Y[96][192];
    int l = blockIdx.x, t = threadIdx.x;
    const float* Tl = Tm + (size_t)l * 9216;
    const float4* src = (const float4*)(hh_vs + (size_t)l * 96 * 192);
    for (int i = t; i < 9216; i += 256) ((float*)T)[i] = Tl[i];
    for (int i = t; i < 4608; i += 256) ((float4*)&Y[0][0])[i] = src[i];
    __syncthreads();
    for (int idx = t; idx < 4608; idx += 256) {
        int i = idx / 48, e0 = (idx % 48) * 4;
        float4 acc = {0.f, 0.f, 0.f, 0.f};
        for (int j = i; j < 96; ++j) {
            float tv = T[j][i];
            float4 y = *(const float4*)&Y[j][e0];
            acc.x += tv * y.x; acc.y += tv * y.y; acc.z += tv * y.z; acc.w += tv * y.w;
        }
        *(float4*)(Am + (size_t)l * 96 * 192 + (size_t)i * 192 + e0) = acc;
    }
}

__global__ __launch_bounds__(256) void hh_p_kernel(const float* __restrict__ hh_vs,
                                                   const float* __restrict__ Am,
                                                   float* __restrict__ qt) {
    __shared__ float Y[96][192];
    __shared__ float A[96][192];
    int l = blockIdx.x, t = threadIdx.x;
    const float4* ys = (const float4*)(hh_vs + (size_t)l * 96 * 192);
    const float4* as = (const float4*)(Am + (size_t)l * 96 * 192);
    for (int i = t; i < 4608; i += 256) { ((float4*)&Y[0][0])[i] = ys[i]; ((float4*)&A[0][0])[i] = as[i]; }
    __syncthreads();
    for (int idx = t; idx < 9216; idx += 256) {
        int d = idx / 48, e0 = (idx % 48) * 4;
        float4 acc = {0.f, 0.f, 0.f, 0.f};
        for (int i = 0; i < 96; ++i) {
            float yv = Y[i][d];
            float4 a = *(const float4*)&A[i][e0];
            acc.x += yv * a.x; acc.y += yv * a.y; acc.z += yv * a.z; acc.w += yv * a.w;
        }
        acc.x = (d == e0 + 0 ? 1.f : 0.f) - acc.x;
        acc.y = (d == e0 + 1 ? 1.f : 0.f) - acc.y;
        acc.z = (d == e0 + 2 ? 1.f : 0.f) - acc.z;
        acc.w = (d == e0 + 3 ? 1.f : 0.f) - acc.w;
        *(float4*)(qt + (size_t)l * 192 * 192 + (size_t)d * 192 + e0) = acc;
    }
}

// fold + transpose + bf16 in one: weff_t[n][k] = sum_d qkv_w[k][d] qt[d][n]
__global__ __launch_bounds__(256) void fold_bf16t(const float* __restrict__ qkv_w,
                                                  const float* __restrict__ qt,
                                                  unsigned short* __restrict__ weff_t) {
    int z = blockIdx.z;
    int l = z >> 3, which = (z >> 2) & 1, head = z & 3;
    const float* A  = qkv_w + (size_t)l * 768 * 2304 + (size_t)which * 768 + head * 192;
    const float* Bq = qt + (size_t)l * 192 * 192;
    unsigned short* C = weff_t + (size_t)l * 2304 * 768 + ((size_t)which * 768 + head * 192) * 768;
    int row0 = blockIdx.y * 64, col0 = blockIdx.x * 64;   // row0: k, col0: n
    __shared__ float As[64][65];
    __shared__ float Bs[64][65];
    int tid = threadIdx.x, tx = tid & 15, ty = tid >> 4;
    float acc[4][4] = {};
    for (int k0 = 0; k0 < 192; k0 += 64) {
        for (int i = tid; i < 1024; i += 256) {
            int r = i >> 4, kq = i & 15;
            float4 va = *(const float4*)(A + (size_t)(row0 + r) * 2304 + k0 + kq * 4);
            As[kq * 4 + 0][r] = va.x; As[kq * 4 + 1][r] = va.y; As[kq * 4 + 2][r] = va.z; As[kq * 4 + 3][r] = va.w;
        }
        for (int i = tid; i < 1024; i += 256) {
            int r = i >> 4, nq = i & 15;
            float4 vb = *(const float4*)(Bq + (size_t)(k0 + r) * 192 + col0 + nq * 4);
            Bs[r][nq * 4 + 0] = vb.x; Bs[r][nq * 4 + 1] = vb.y; Bs[r][nq * 4 + 2] = vb.z; Bs[r][nq * 4 + 3] = vb.w;
        }
        __syncthreads();
        for (int k = 0; k < 64; ++k) {
            float a[4], bb[4];
#pragma unroll
            for (int m = 0; m < 4; ++m) a[m] = As[k][ty * 4 + m];
#pragma unroll
            for (int n = 0; n < 4; ++n) bb[n] = Bs[k][tx * 4 + n];
#pragma unroll
            for (int m = 0; m < 4; ++m)
#pragma unroll
                for (int n = 0; n < 4; ++n) acc[m][n] = fmaf(a[m], bb[n], acc[m][n]);
        }
        __syncthreads();
    }
    float (*Tr)[65] = (float(*)[65])As;
#pragma unroll
    for (int m = 0; m < 4; ++m)
#pragma unroll
        for (int n = 0; n < 4; ++n) Tr[tx * 4 + n][ty * 4 + m] = acc[m][n];
    __syncthreads();
    int nl = tid >> 2, kc = (tid & 3) * 16;
#pragma unroll
    for (int q4 = 0; q4 < 4; ++q4) {
        u16x4 o;
#pragma unroll
        for (int ii = 0; ii < 4; ++ii) o[ii] = f2bf(Tr[nl][kc + q4 * 4 + ii]);
        *(u16x4*)(C + (size_t)(col0 + nl) * 768 + row0 + kc + q4 * 4) = o;
    }
}

// strided fp32 [K][N] -> bf16 [N][K]
__global__ __launch_bounds__(256) void transpose_bf16_kernel(const float* __restrict__ W,
                                                             int ldw, size_t zsrc,
                                                             unsigned short* __restrict__ Wt,
                                                             int ldwt, size_t zdst) {
    __shared__ float t[32][33];
    const float* Wz = W + (size_t)blockIdx.z * zsrc;
    unsigned short* Wtz = Wt + (size_t)blockIdx.z * zdst;
    int k0 = blockIdx.y * 32, n0 = blockIdx.x * 32;
    int tid = threadIdx.x;
    int tr = tid >> 3, tc = tid & 7;
    float4 v = *(const float4*)(Wz + (size_t)(k0 + tr) * ldw + n0 + tc * 4);
    t[tr][tc * 4 + 0] = v.x; t[tr][tc * 4 + 1] = v.y; t[tr][tc * 4 + 2] = v.z; t[tr][tc * 4 + 3] = v.w;
    __syncthreads();
    u16x4 o;
    o[0] = f2bf(t[tc * 4 + 0][tr]); o[1] = f2bf(t[tc * 4 + 1][tr]);
    o[2] = f2bf(t[tc * 4 + 2][tr]); o[3] = f2bf(t[tc * 4 + 3][tr]);
    *(u16x4*)(Wtz + (size_t)(n0 + tr) * ldwt + k0 + tc * 4) = o;
}

__global__ __launch_bounds__(256) void patch_embed_kernel(const float* __restrict__ z_t,
                                                          const float* __restrict__ spins,
                                                          const float* __restrict__ patch_w,
                                                          const float* __restrict__ patch_b,
                                                          float* __restrict__ x) {
    int bs = blockIdx.x;
    int b = bs >> 8, s = bs & 255;
    int gy = s >> 4, gx = s & 15;
    __shared__ float in20[20];
    int t = threadIdx.x;
    if (t < 12) {
        int c = t >> 2, py = (t >> 1) & 1, px = t & 1;
        in20[t] = z_t[(((size_t)b * 3 + c) * 32 + (2 * gy + py)) * 32 + (2 * gx + px)];
    } else if (t < 20) {
        in20[t] = spins[b * 8 + (t - 12)];
    }
    __syncthreads();
    for (int d = t; d < 768; d += 256) {
        float acc = patch_b[d];
#pragma unroll
        for (int i = 0; i < 20; ++i) acc += in20[i] * patch_w[i * 768 + d];
        x[(size_t)bs * 768 + d] = acc;
    }
}

// wave-per-row rmsnorm: 4 rows/block, lane owns 12 contiguous d
__global__ __launch_bounds__(256) void rmsnorm_kernel(const float* __restrict__ x,
                                                      unsigned short* __restrict__ h) {
    int wave = threadIdx.x >> 6, lane = threadIdx.x & 63;
    int row = blockIdx.x * 4 + wave;
    const float* xr = x + (size_t)row * 768 + lane * 12;
    float4 a = *(const float4*)(xr);
    float4 b = *(const float4*)(xr + 4);
    float4 c = *(const float4*)(xr + 8);
    float ss = a.x*a.x + a.y*a.y + a.z*a.z + a.w*a.w
             + b.x*b.x + b.y*b.y + b.z*b.z + b.w*b.w
             + c.x*c.x + c.y*c.y + c.z*c.z + c.w*c.w;
#pragma unroll
    for (int msk = 1; msk < 64; msk <<= 1) ss += __shfl_xor(ss, msk);
    float sc = 1.0f / sqrtf(ss / 768.0f + EPS_RMS);
    unsigned short* hr = h + (size_t)row * 768 + lane * 12;
    u16x4 o0, o1, o2;
    o0[0]=f2bf(a.x*sc); o0[1]=f2bf(a.y*sc); o0[2]=f2bf(a.z*sc); o0[3]=f2bf(a.w*sc);
    o1[0]=f2bf(b.x*sc); o1[1]=f2bf(b.y*sc); o1[2]=f2bf(b.z*sc); o1[3]=f2bf(b.w*sc);
    o2[0]=f2bf(c.x*sc); o2[1]=f2bf(c.y*sc); o2[2]=f2bf(c.z*sc); o2[3]=f2bf(c.w*sc);
    *(u16x4*)(hr) = o0; *(u16x4*)(hr + 4) = o1; *(u16x4*)(hr + 8) = o2;
}

// XCD-aware bijective block swizzle (requires nwg % 8 == 0)
DEV void xcd_swizzle(int gx, int gy, int& bx, int& by) {
    int nwg = gx * gy;
    int id = by * gx + bx;
    int q = nwg >> 3;
    id = (id & 7) * q + (id >> 3);
    by = id / gx; bx = id % gx;
}

// ---- bf16 MFMA GEMM (R3-proven): 128x128, BK=32, 4 waves, XCD swizzle -----
// EPI: 0=store bf16(+bias)  1=qkv scatter (V transposed)  2=gate  4=x+=v
template <int EPI>
__global__ __launch_bounds__(256) void gemm_mfma(const unsigned short* __restrict__ A, int lda,
                                                 const unsigned short* __restrict__ Bt, int ldb,
                                                 unsigned short* __restrict__ Cb, int ldc, int K,
                                                 const float* __restrict__ bias,
                                                 float* __restrict__ Xf,
                                                 const unsigned short* __restrict__ Pb) {
    __shared__ unsigned short As[4096];
    __shared__ unsigned short Bs[4096];
    int tid = threadIdx.x;
    int wave = tid >> 6, lane = tid & 63;
    int bx = blockIdx.x, by = blockIdx.y;
    xcd_swizzle(gridDim.x, gridDim.y, bx, by);
    int row0 = by * 128, col0 = bx * 128;
    int wm = wave >> 1, wn = wave & 1;
    f32x4 acc[4][4] = {};

    int srow = lane >> 2;
    int ksw = (((lane & 3) ^ (srow & 3)) * 8);
    int lrow = lane & 15;
    int csw = (((lane >> 4) ^ (lane & 3)) * 8);

    for (int k0 = 0; k0 < K; k0 += 32) {
#pragma unroll
        for (int it = 0; it < 2; ++it) {
            int chunk = it * 4 + wave;
            int r = chunk * 16 + srow;
            gload16(A  + (size_t)(row0 + r) * lda + k0 + ksw, &As[chunk * 512]);
            gload16(Bt + (size_t)(col0 + r) * ldb + k0 + ksw, &Bs[chunk * 512]);
        }
        __syncthreads();
        s16x8 af[4], bf[4];
#pragma unroll
        for (int m = 0; m < 4; ++m)
            af[m] = *(const s16x8*)&As[(wm * 64 + m * 16 + lrow) * 32 + csw];
#pragma unroll
        for (int n = 0; n < 4; ++n)
            bf[n] = *(const s16x8*)&Bs[(wn * 64 + n * 16 + lrow) * 32 + csw];
#pragma unroll
        for (int m = 0; m < 4; ++m)
#pragma unroll
            for (int n = 0; n < 4; ++n)
                acc[m][n] = __builtin_amdgcn_mfma_f32_16x16x32_bf16(af[m], bf[n], acc[m][n], 0, 0, 0);
        __syncthreads();
    }

    int lquad = lane >> 4;
#pragma unroll
    for (int m = 0; m < 4; ++m) {
#pragma unroll
        for (int n = 0; n < 4; ++n) {
#pragma unroll
            for (int r = 0; r < 4; ++r) {
                int i = row0 + wm * 64 + m * 16 + lquad * 4 + r;
                int j = col0 + wn * 64 + n * 16 + lrow;
                float v = acc[m][n][r];
                if (bias) v += bias[j];
                if constexpr (EPI == 0) {
                    Cb[(size_t)i * ldc + j] = f2bf(v);
                } else if constexpr (EPI == 1) {
                    int which = j / 768;
                    int rem = j - which * 768;
                    int head = rem / 192;
                    int hd = rem - head * 192;
                    int b = i >> 8, s = i & 255;
                    if (which == 2) {   // V transposed: [bh][d][s]
                        Cb[2 * ARENA_K + (((size_t)(b * 4 + head)) * 192 + hd) * 256 + s] = f2bf(v);
                    } else {
                        Cb[(size_t)which * ARENA_K + (((size_t)(b * 4 + head)) * 256 + s) * 192 + hd] = f2bf(v);
                    }
                } else if constexpr (EPI == 2) {
                    float p = b2f(Pb[(size_t)i * 768 + j]);
                    Xf[(size_t)i * 768 + j] += p * sigmoidf_(v);
                } else if constexpr (EPI == 4) {
                    Xf[(size_t)i * ldc + j] += v;
                }
            }
        }
    }
}

// ---- fused MLP-in GEMM: hidden = gelu(h@Wg+bg) * (h@Wv+bv) ----------------
__global__ __launch_bounds__(256) void gemm_mlp_fused(const unsigned short* __restrict__ A,
                                                      const unsigned short* __restrict__ Bt,
                                                      unsigned short* __restrict__ Hid,
                                                      const float* __restrict__ bias) {
    __shared__ unsigned short As[4096];
    __shared__ unsigned short Bs[4096];
    int tid = threadIdx.x;
    int wave = tid >> 6, lane = tid & 63;
    int bx = blockIdx.x, by = blockIdx.y;
    xcd_swizzle(gridDim.x, gridDim.y, bx, by);
    int row0 = by * 128, col0 = bx * 64;
    int wm = wave >> 1, wn = wave & 1;
    f32x4 accg[4][2] = {};
    f32x4 accv[4][2] = {};

    int srow = lane >> 2;
    int ksw = (((lane & 3) ^ (srow & 3)) * 8);
    int lrow = lane & 15;
    int csw = (((lane >> 4) ^ (lane & 3)) * 8);

    const unsigned short* Bg = Bt + (size_t)col0 * 768;
    const unsigned short* Bv = Bt + (size_t)(3072 + col0) * 768;

    for (int k0 = 0; k0 < 768; k0 += 32) {
#pragma unroll
        for (int it = 0; it < 2; ++it) {
            int chunk = it * 4 + wave;
            int r = chunk * 16 + srow;
            gload16(A + (size_t)(row0 + r) * 768 + k0 + ksw, &As[chunk * 512]);
        }
        {
            int r = wave * 16 + srow;
            gload16(Bg + (size_t)r * 768 + k0 + ksw, &Bs[wave * 512]);
            gload16(Bv + (size_t)r * 768 + k0 + ksw, &Bs[2048 + wave * 512]);
        }
        __syncthreads();
        s16x8 af[4], bgf[2], bvf[2];
#pragma unroll
        for (int m = 0; m < 4; ++m)
            af[m] = *(const s16x8*)&As[(wm * 64 + m * 16 + lrow) * 32 + csw];
#pragma unroll
        for (int n = 0; n < 2; ++n) {
            bgf[n] = *(const s16x8*)&Bs[(wn * 32 + n * 16 + lrow) * 32 + csw];
            bvf[n] = *(const s16x8*)&Bs[2048 + (wn * 32 + n * 16 + lrow) * 32 + csw];
        }
#pragma unroll
        for (int m = 0; m < 4; ++m)
#pragma unroll
            for (int n = 0; n < 2; ++n) {
                accg[m][n] = __builtin_amdgcn_mfma_f32_16x16x32_bf16(af[m], bgf[n], accg[m][n], 0, 0, 0);
                accv[m][n] = __builtin_amdgcn_mfma_f32_16x16x32_bf16(af[m], bvf[n], accv[m][n], 0, 0, 0);
            }
        __syncthreads();
    }

    int lquad = lane >> 4;
#pragma unroll
    for (int m = 0; m < 4; ++m) {
#pragma unroll
        for (int n = 0; n < 2; ++n) {
#pragma unroll
            for (int r = 0; r < 4; ++r) {
                int i = row0 + wm * 64 + m * 16 + lquad * 4 + r;
                int j = col0 + wn * 32 + n * 16 + lrow;
                float g = accg[m][n][r] + bias[j];
                float v = accv[m][n][r] + bias[3072 + j];
                Hid[(size_t)i * 3072 + j] = f2bf(v * geluf_(g));
            }
        }
    }
}

// ---- MFMA attention with fused RoPE: grid (2, NH, B), 512 thr -------------
__global__ __launch_bounds__(512) void attn_mfma_kernel(const unsigned short* __restrict__ qb_,
                                                        const unsigned short* __restrict__ kb_,
                                                        const unsigned short* __restrict__ vtb_,
                                                        unsigned short* __restrict__ attnb,
                                                        const float* __restrict__ cosb,
                                                        const float* __restrict__ sinb,
                                                        int glob) {
    __shared__ unsigned short Klds[256 * 200];
    __shared__ unsigned short Vlds[192 * 72];
    __shared__ unsigned short Plds[8 * 16 * 72];
    int b = blockIdx.z, hh = blockIdx.y;
    int tid = threadIdx.x;
    int wave = tid >> 6, lane = tid & 63;
    int q0 = blockIdx.x * 128 + wave * 16;
    size_t bh = (size_t)(b * 4 + hh);
    const unsigned short* qb  = qb_  + bh * 49152;
    const unsigned short* kb  = kb_  + bh * 49152;
    const unsigned short* vtb = vtb_ + bh * 49152;

    // stage K with RoPE applied
    for (int c = tid; c < 6144; c += 512) {
        int r = c / 24, col = c - (c / 24) * 24;
        int j0 = col * 8;
        int jp = j0 < 96 ? j0 + 96 : j0 - 96;
        float sgn = j0 < 96 ? -1.f : 1.f;
        u16x8 a = *(const u16x8*)(kb + (size_t)r * 192 + j0);
        u16x8 p = *(const u16x8*)(kb + (size_t)r * 192 + jp);
        const float* cr = cosb + r * 192 + j0;
        const float* sr = sinb + r * 192 + j0;
        u16x8 o;
#pragma unroll
        for (int i = 0; i < 8; ++i)
            o[i] = f2bf(b2f(a[i]) * cr[i] + sgn * b2f(p[i]) * sr[i]);
        *(u16x8*)&Klds[r * 200 + j0] = o;
    }
    __syncthreads();

    // Q fragments with RoPE
    s16x8 qf[6];
    {
        int sq = q0 + (lane & 15);
        const unsigned short* qrow = qb + (size_t)sq * 192;
        const float* cr = cosb + sq * 192;
        const float* sr = sinb + sq * 192;
#pragma unroll
        for (int kk = 0; kk < 6; ++kk) {
            int ck = kk * 32 + (lane >> 4) * 8;
            int cp = ck < 96 ? ck + 96 : ck - 96;
            float sgn = ck < 96 ? -1.f : 1.f;
            u16x8 a = *(const u16x8*)(qrow + ck);
            u16x8 p = *(const u16x8*)(qrow + cp);
            s16x8 o;
#pragma unroll
            for (int i = 0; i < 8; ++i)
                o[i] = (short)f2bf(b2f(a[i]) * cr[ck + i] + sgn * b2f(p[i]) * sr[ck + i]);
            qf[kk] = o;
        }
    }

    f32x4 sc[16];
#pragma unroll
    for (int n = 0; n < 16; ++n) sc[n] = (f32x4){0.f, 0.f, 0.f, 0.f};
#pragma unroll
    for (int kk = 0; kk < 6; ++kk) {
#pragma unroll
        for (int n = 0; n < 16; ++n) {
            s16x8 bf = *(const s16x8*)&Klds[(n * 16 + (lane & 15)) * 200 + kk * 32 + (lane >> 4) * 8];
            sc[n] = __builtin_amdgcn_mfma_f32_16x16x32_bf16(qf[kk], bf, sc[n], 0, 0, 0);
        }
    }

    int lq = (lane >> 4) * 4;
#pragma unroll
    for (int n = 0; n < 16; ++n) {
        int sk = n * 16 + (lane & 15);
        int yk = sk >> 4, xk = sk & 15;
#pragma unroll
        for (int r = 0; r < 4; ++r) {
            int sq = q0 + lq + r;
            int dy = (sq >> 4) - yk, dx = (sq & 15) - xk;
            bool keep = glob || (dy * dy + dx * dx) < 7;
            sc[n][r] = keep ? sc[n][r] * ATT_SCALE : -1e30f;
        }
    }
    float rmax[4], rsum[4];
#pragma unroll
    for (int r = 0; r < 4; ++r) {
        float m = sc[0][r];
#pragma unroll
        for (int n = 1; n < 16; ++n) m = fmaxf(m, sc[n][r]);
#pragma unroll
        for (int msk = 1; msk < 16; msk <<= 1) m = fmaxf(m, __shfl_xor(m, msk));
        rmax[r] = m;
    }
#pragma unroll
    for (int r = 0; r < 4; ++r) {
        float e = 0.f;
#pragma unroll
        for (int n = 0; n < 16; ++n) { float p = expf(sc[n][r] - rmax[r]); sc[n][r] = p; e += p; }
#pragma unroll
        for (int msk = 1; msk < 16; msk <<= 1) e += __shfl_xor(e, msk);
        rsum[r] = 1.0f / e;
    }

    f32x4 o[12];
#pragma unroll
    for (int n = 0; n < 12; ++n) o[n] = (f32x4){0.f, 0.f, 0.f, 0.f};
    unsigned short* Pw = &Plds[wave * 1152];
    for (int kt = 0; kt < 4; ++kt) {
#pragma unroll
        for (int nn = 0; nn < 4; ++nn) {
#pragma unroll
            for (int r = 0; r < 4; ++r)
                Pw[(lq + r) * 72 + nn * 16 + (lane & 15)] = f2bf(sc[kt * 4 + nn][r] * rsum[r]);
        }
        __syncthreads();
        for (int c = tid; c < 1536; c += 512) {
            int r = c >> 3, col = c & 7;
            *(u16x8*)&Vlds[r * 72 + col * 8] = *(const u16x8*)(vtb + (size_t)r * 256 + kt * 64 + col * 8);
        }
        __syncthreads();
        s16x8 af[2];
#pragma unroll
        for (int kk2 = 0; kk2 < 2; ++kk2)
            af[kk2] = *(const s16x8*)&Pw[(lane & 15) * 72 + kk2 * 32 + (lane >> 4) * 8];
#pragma unroll
        for (int n = 0; n < 12; ++n) {
#pragma unroll
            for (int kk2 = 0; kk2 < 2; ++kk2) {
                s16x8 bf = *(const s16x8*)&Vlds[(n * 16 + (lane & 15)) * 72 + kk2 * 32 + (lane >> 4) * 8];
                o[n] = __builtin_amdgcn_mfma_f32_16x16x32_bf16(af[kk2], bf, o[n], 0, 0, 0);
            }
        }
    }
#pragma unroll
    for (int n = 0; n < 12; ++n) {
        int d = n * 16 + (lane & 15);
#pragma unroll
        for (int r = 0; r < 4; ++r) {
            int sq = q0 + lq + r;
            attnb[((size_t)(b * 256 + sq)) * 768 + hh * 192 + d] = f2bf(o[n][r]);
        }
    }
}

__global__ __launch_bounds__(768) void scalef_kernel(const float* __restrict__ spins,
                                                     const float* __restrict__ sd1_w,
                                                     const float* __restrict__ sd1_b,
                                                     const float* __restrict__ sd2_w,
                                                     const float* __restrict__ sd2_b,
                                                     float* __restrict__ scalef) {
    int b = blockIdx.x, t = threadIdx.x;
    __shared__ float hid[768];
    __shared__ float sp[8];
    if (t < 8) sp[t] = spins[b * 8 + t];
    __syncthreads();
    float acc = sd1_b[t];
#pragma unroll
    for (int i = 0; i < 8; ++i) acc += sp[i] * sd1_w[i * 768 + t];
    hid[t] = acc * sigmoidf_(acc);
    __syncthreads();
    if (t < 12) {
        float o = sd2_b[t];
        for (int d = 0; d < 768; ++d) o += hid[d] * sd2_w[d * 12 + t];
        scalef[b * 12 + t] = expf(o);
    }
}

// head: wave-per-row, lane owns 12 contiguous d; also emits rowlam = x.lam_w
__global__ __launch_bounds__(256) void head_kernel(const unsigned short* __restrict__ xn,
                                                   const float* __restrict__ head_w,
                                                   const float* __restrict__ head_b,
                                                   const float* __restrict__ scalef,
                                                   const float* __restrict__ lam_w,
                                                   float* __restrict__ out,
                                                   float* __restrict__ rowlam) {
    __shared__ float hw[768][13];
    __shared__ float red[4][64][14];
    int t = threadIdx.x, wave = t >> 6, lane = t & 63;
    for (int i = t; i < 768 * 12; i += 256) hw[i / 12][i % 12] = head_w[i];
    for (int i = t; i < 768; i += 256) hw[i][12] = lam_w[i];
    __syncthreads();
    int row_base = blockIdx.x * 64;
    for (int rr = wave; rr < 64; rr += 4) {
        int row = row_base + rr;
        const unsigned short* xr = xn + (size_t)row * 768 + lane * 12;
        float xv[12];
        u16x4 v0 = *(const u16x4*)(xr);
        u16x4 v1 = *(const u16x4*)(xr + 4);
        u16x4 v2 = *(const u16x4*)(xr + 8);
#pragma unroll
        for (int j = 0; j < 4; ++j) { xv[j] = b2f(v0[j]); xv[4 + j] = b2f(v1[j]); xv[8 + j] = b2f(v2[j]); }
        float p[13] = {};
        int d0 = lane * 12;
#pragma unroll
        for (int dd = 0; dd < 12; ++dd) {
            float xvv = xv[dd];
#pragma unroll
            for (int o = 0; o < 12; ++o) p[o] += xvv * hw[d0 + dd][o];
            p[12] += xvv * hw[d0 + dd][12];
        }
#pragma unroll
        for (int o = 0; o < 13; ++o) red[wave][lane][o] = p[o];
        __syncthreads();
        if (lane < 13) {
            float s = 0.f;
            for (int i = 0; i < 64; ++i) s += red[wave][i][lane];
            if (lane < 12) {
                int b = row >> 8, sidx = row & 255;
                float v = (s + head_b[lane]) * scalef[b * 12 + lane];
                int c = lane >> 2, py = (lane >> 1) & 1, px = lane & 1;
                int gy = sidx >> 4, gxx = sidx & 15;
                out[(((size_t)b * 3 + c) * 32 + 2 * gy + py) * 32 + 2 * gxx + px] = v;
            } else {
                rowlam[row] = s;
            }
        }
        __syncthreads();
    }
}

__global__ __launch_bounds__(256) void lpred_kernel(const float* __restrict__ rowlam,
                                                    const float* __restrict__ lam_b,
                                                    float* __restrict__ out) {
    int b = blockIdx.x, t = threadIdx.x;
    __shared__ float red[256];
    red[t] = rowlam[b * 256 + t];
    __syncthreads();
    for (int s2 = 128; s2 > 0; s2 >>= 1) { if (t < s2) red[t] += red[t + s2]; __syncthreads(); }
    if (t == 0) out[196608 + b] = red[0] / 256.0f + lam_b[0];
}

// ---------------------------------------------------------------------------
extern "C" void kernel_launch(void* const* d_in, const int* in_sizes, int n_in,
                              void* d_out, int out_size, void* d_ws, size_t ws_size,
                              hipStream_t stream) {
    const float* z_t     = (const float*)d_in[0];
    const float* logsnr  = (const float*)d_in[1];
    const float* qkv_w   = (const float*)d_in[2];
    const float* out_w   = (const float*)d_in[3];
    const float* gate_w  = (const float*)d_in[4];
    const float* gate_b  = (const float*)d_in[5];
    const float* mlpg_w  = (const float*)d_in[6];
    const float* mlpg_b  = (const float*)d_in[7];
    const float* mlpo_w  = (const float*)d_in[8];
    const float* mlpo_b  = (const float*)d_in[9];
    const float* hh_vs   = (const float*)d_in[10];
    const float* patch_w = (const float*)d_in[11];
    const float* patch_b = (const float*)d_in[12];
    const float* head_w  = (const float*)d_in[13];
    const float* head_b  = (const float*)d_in[14];
    const float* sd1_w   = (const float*)d_in[15];
    const float* sd1_b   = (const float*)d_in[16];
    const float* sd2_w   = (const float*)d_in[17];
    const float* sd2_b   = (const float*)d_in[18];
    const float* lam_w   = (const float*)d_in[19];
    const float* lam_b   = (const float*)d_in[20];

    char* wsb = (char*)d_ws;
    float* spins  = (float*)(wsb + B_SPINS);
    float* scalef = (float*)(wsb + B_SCALEF);
    float* qt     = (float*)(wsb + B_QT);
    float* cosb   = (float*)(wsb + B_COS);
    float* sinb   = (float*)(wsb + B_SIN);
    float* Gm     = (float*)(wsb + B_G);
    float* Tm     = (float*)(wsb + B_T);
    float* Am     = (float*)(wsb + B_AWY);
    float* rowlam = (float*)(wsb + B_ROWLAM);
    float* x      = (float*)(wsb + B_X);
    unsigned short* h      = (unsigned short*)(wsb + B_H);
    unsigned short* proj   = (unsigned short*)(wsb + B_PROJ);
    unsigned short* weff_t = (unsigned short*)(wsb + B_WEFFT);
    unsigned short* outw_t = (unsigned short*)(wsb + B_OUTWT);
    unsigned short* gatew_t= (unsigned short*)(wsb + B_GATEWT);
    unsigned short* mlpg_t = (unsigned short*)(wsb + B_MLPGT);
    unsigned short* mlpo_t = (unsigned short*)(wsb + B_MLPOT);
    unsigned short* arena  = (unsigned short*)(wsb + B_ARENA);
    unsigned short* qbuf = arena;
    unsigned short* kbuf = arena + ARENA_K;
    unsigned short* vtbuf = arena + 2 * ARENA_K;
    unsigned short* attnb = arena + 3 * ARENA_K;
    unsigned short* hidden = arena;
    float* out = (float*)d_out;

    // ---- setup ----
    spins_kernel<<<1, 64, 0, stream>>>(logsnr, spins);
    rope_table_kernel<<<256, 192, 0, stream>>>(cosb, sinb);
    hh_gram_kernel<<<8, 256, 0, stream>>>(hh_vs, Gm);
    hh_t_kernel<<<8, 128, 0, stream>>>(Gm, Tm);
    hh_a_kernel<<<8, 256, 0, stream>>>(Tm, hh_vs, Am);
    hh_p_kernel<<<8, 256, 0, stream>>>(hh_vs, Am, qt);
    fold_bf16t<<<dim3(3, 12, 64), 256, 0, stream>>>(qkv_w, qt, weff_t);
    transpose_bf16_kernel<<<dim3(24, 24, 8), 256, 0, stream>>>(qkv_w + 1536, 2304,
        (size_t)768 * 2304, weff_t + (size_t)1536 * 768, 768, (size_t)2304 * 768);
    transpose_bf16_kernel<<<dim3(24, 24, 8), 256, 0, stream>>>(out_w, 768,
        (size_t)768 * 768, outw_t, 768, (size_t)768 * 768);
    transpose_bf16_kernel<<<dim3(24, 24, 8), 256, 0, stream>>>(gate_w, 768,
        (size_t)768 * 768, gatew_t, 768, (size_t)768 * 768);
    transpose_bf16_kernel<<<dim3(192, 24, 8), 256, 0, stream>>>(mlpg_w, 6144,
        (size_t)768 * 6144, mlpg_t, 768, (size_t)6144 * 768);
    transpose_bf16_kernel<<<dim3(24, 96, 8), 256, 0, stream>>>(mlpo_w, 768,
        (size_t)3072 * 768, mlpo_t, 3072, (size_t)768 * 3072);
    patch_embed_kernel<<<M_TOK, 256, 0, stream>>>(z_t, spins, patch_w, patch_b, x);

    for (int l = 0; l < Ll; ++l) {
        int glob = ((l + 1) % 4 == 0) ? 1 : 0;
        rmsnorm_kernel<<<4096, 256, 0, stream>>>(x, h);
        gemm_mfma<1><<<dim3(18, 128), 256, 0, stream>>>(h, 768,
            weff_t + (size_t)l * 2304 * 768, 768, arena, 0, 768, nullptr, nullptr, nullptr);
        attn_mfma_kernel<<<dim3(2, 4, 64), 512, 0, stream>>>(qbuf, kbuf, vtbuf, attnb,
            cosb, sinb, glob);
        gemm_mfma<0><<<dim3(6, 128), 256, 0, stream>>>(attnb, 768,
            outw_t + (size_t)l * 768 * 768, 768, proj, 768, 768, nullptr, nullptr, nullptr);
        gemm_mfma<2><<<dim3(6, 128), 256, 0, stream>>>(proj, 768,
            gatew_t + (size_t)l * 768 * 768, 768, nullptr, 768, 768,
            gate_b + (size_t)l * 768, x, proj);
        rmsnorm_kernel<<<4096, 256, 0, stream>>>(x, h);
        gemm_mlp_fused<<<dim3(48, 128), 256, 0, stream>>>(h,
            mlpg_t + (size_t)l * 6144 * 768, hidden, mlpg_b + (size_t)l * 6144);
        gemm_mfma<4><<<dim3(6, 128), 256, 0, stream>>>(hidden, 3072,
            mlpo_t + (size_t)l * 768 * 3072, 3072, nullptr, 768, 3072,
            mlpo_b + (size_t)l * 768, x, nullptr);
    }

    rmsnorm_kernel<<<4096, 256, 0, stream>>>(x, h);
    scalef_kernel<<<64, 768, 0, stream>>>(spins, sd1_w, sd1_b, sd2_w, sd2_b, scalef);
    head_kernel<<<256, 256, 0, stream>>>(h, head_w, head_b, scalef, lam_w, out, rowlam);
    lpred_kernel<<<64, 256, 0, stream>>>(rowlam, lam_b, out);
}

// Round 8
// 5917.635 us; speedup vs baseline: 1.4334x; 1.0147x over previous
//
#include <hip/hip_runtime.h>
#include <hip/hip_bf16.h>
#include <math.h>

// ---------------------------------------------------------------------------
// HybridGemmaDiT forward.  B=64, S=256 (16x16), D=768, L=8, NH=4, HD=192.
// R8: 2D-chunked XCD swizzle (CY=16 rows x CX cols sub-chunks sized to the
//     4MB per-XCD L2) on all GEMMs -- fixes the 9x B-matrix L2 thrash seen
//     in R7 (FETCH 322MB vs 35MB compulsory on mlp_fused).
// ---------------------------------------------------------------------------

#define DEV static __device__ __forceinline__

typedef float    f32x4 __attribute__((ext_vector_type(4)));
typedef short    s16x8 __attribute__((ext_vector_type(8)));
typedef unsigned short u16x8 __attribute__((ext_vector_type(8)));
typedef unsigned short u16x4 __attribute__((ext_vector_type(4)));

constexpr int Bb = 64, Ss = 256, Dd = 768, Ll = 8, NHh = 4, HDd = 192;
constexpr int M_TOK = Bb * Ss;                 // 16384
constexpr float EPS_RMS = 1.1920929e-07f;
constexpr float ATT_SCALE = 0.07216878364870322f;  // 1/sqrt(192)
constexpr size_t ARENA_K = (size_t)Bb * NHh * Ss * HDd;   // 12,582,912 elems

// ---- workspace layout (BYTES) ---------------------------------------------
constexpr size_t B_SPINS  = 0;
constexpr size_t B_SCALEF = 2048;
constexpr size_t B_QT     = 5120;                        // 8*192*192 f32
constexpr size_t B_COS    = B_QT + 1179648;
constexpr size_t B_SIN    = B_COS + 196608;
constexpr size_t B_G      = B_SIN + 196608;              // 8*96*96 f32
constexpr size_t B_T      = B_G + 294912;
constexpr size_t B_AWY    = B_T + 294912;                // 8*96*192 f32
constexpr size_t B_ROWLAM = B_AWY + 589824;              // 16384 f32
constexpr size_t B_X      = B_ROWLAM + 65536;            // 16384*768 f32
constexpr size_t B_H      = B_X + 50331648;              // bf16
constexpr size_t B_PROJ   = B_H + 25165824;              // bf16
constexpr size_t B_WEFFT  = B_PROJ + 25165824;           // 8*2304*768 bf16
constexpr size_t B_OUTWT  = B_WEFFT + 28311552;
constexpr size_t B_GATEWT = B_OUTWT + 9437184;
constexpr size_t B_MLPGT  = B_GATEWT + 9437184;          // 8*6144*768 bf16
constexpr size_t B_MLPOT  = B_MLPGT + 75497472;          // 8*768*3072 bf16
constexpr size_t B_ARENA  = B_MLPOT + 37748736;          // q,k,v^T,attn bf16 | hidden

DEV float sigmoidf_(float x) { return 1.0f / (1.0f + expf(-x)); }
DEV float geluf_(float g)    { return 0.5f * g * (1.0f + erff(g * 0.7071067811865476f)); }
DEV unsigned short f2bf(float f) {
    union { float f; unsigned u; } a; a.f = f;
    unsigned u = a.u + 0x7fffu + ((a.u >> 16) & 1u);
    return (unsigned short)(u >> 16);
}
DEV float b2f(unsigned short u) {
    union { unsigned u; float f; } a; a.u = ((unsigned)u) << 16; return a.f;
}
DEV void gload16(const void* g, void* l) {
    __builtin_amdgcn_global_load_lds((const __attribute__((address_space(1))) void*)g,
                                     (__attribute__((address_space(3))) void*)l, 16, 0, 0);
}

// 2D-chunked XCD-aware swizzle: XCD c = id%8 owns by-range [c*CY, (c+1)*CY);
// within an XCD, blocks walk sub-chunks of (CY rows x CX cols) so the L2
// working set = CY*A_panel + CX*B_panel stays under 4MB.  Bijective when
// gy%8==0 and gx%CX==0.
DEV void xcd_chunk(int gx, int gy, int CX, int& bx, int& by) {
    int id = by * gx + bx;
    int c = id & 7;
    int s = id >> 3;
    int CY = gy >> 3;
    int subsz = CY * CX;
    int bxc = s / subsz;
    int r = s - bxc * subsz;
    int byl = r / CX;
    by = c * CY + byl;
    bx = bxc * CX + (r - byl * CX);
}

// ---------------------------------------------------------------------------
__global__ void spins_kernel(const float* __restrict__ logsnr, float* __restrict__ spins) {
    int b = threadIdx.x;
    if (b < 64) {
        float v = logsnr[b];
#pragma unroll
        for (int j = 0; j < 4; ++j) {
            float ang = v * (float)(1 << j);
            spins[b * 8 + j]     = sinf(ang);
            spins[b * 8 + 4 + j] = cosf(ang);
        }
    }
}

__global__ void rope_table_kernel(float* __restrict__ cosb, float* __restrict__ sinb) {
    int s = blockIdx.x, j = threadIdx.x;
    int y = s >> 4, x = s & 15;
    int base = j % 96;
    float coord, invf;
    if (base < 48) { invf = expf(-(float)base * (2.0f / 96.0f) * 9.210340371976184f); coord = (float)y; }
    else { int i = base - 48; invf = expf(-(float)i * (2.0f / 96.0f) * 9.210340371976184f); coord = (float)x; }
    float f = coord * invf, sv, cv;
    sincosf(f, &sv, &cv);
    cosb[s * 192 + j] = cv;
    sinb[s * 192 + j] = sv;
}

// ---- WY householder: qt = Q^T = I - Y^T T Y -------------------------------
__global__ __launch_bounds__(256) void hh_gram_kernel(const float* __restrict__ hh_vs,
                                                      float* __restrict__ Gm) {
    __shared__ float Y[96][192];
    int l = blockIdx.x, t = threadIdx.x;
    const float4* src = (const float4*)(hh_vs + (size_t)l * 96 * 192);
    for (int i = t; i < 4608; i += 256) ((float4*)&Y[0][0])[i] = src[i];
    __syncthreads();
    for (int e = t; e < 9216; e += 256) {
        int i = e / 96, j = e - (e / 96) * 96;
        float acc = 0.f;
        for (int d = 0; d < 48; ++d) {
            float4 a = *(const float4*)&Y[i][d * 4];
            float4 b = *(const float4*)&Y[j][d * 4];
            acc += a.x * b.x + a.y * b.y + a.z * b.z + a.w * b.w;
        }
        Gm[(size_t)l * 9216 + e] = acc;
    }
}

// T recurrence, uniform-p loop: G[p][j] broadcast, Tt[p][t] lane-consecutive.
__global__ __launch_bounds__(128) void hh_t_kernel(const float* __restrict__ Gm,
                                                   float* __restrict__ Tm) {
    __shared__ float G[96][96];
    __shared__ float Tt[96][96];
    int l = blockIdx.x, t = threadIdx.x;
    const float* Gl = Gm + (size_t)l * 9216;
    for (int i = t; i < 9216; i += 128) { ((float*)G)[i] = Gl[i]; ((float*)Tt)[i] = 0.f; }
    __syncthreads();
    if (t < 96) Tt[t][t] = 2.0f / (G[t][t] + 1e-8f);
    __syncthreads();
    for (int j = 1; j < 96; ++j) {
        if (t < 96) {
            float cj = 2.0f / (G[j][j] + 1e-8f);
            float dot = 0.f;
            for (int p = 0; p < j; ++p) dot += Tt[p][t] * G[p][j];
            if (t < j) Tt[j][t] = -cj * dot;
        }
        __syncthreads();
    }
    for (int i = t; i < 9216; i += 128) Tm[(size_t)l * 9216 + i] = ((float*)Tt)[i];
}

// A[i][e] = sum_j Tt[j][i] Y[j][e]
__global__ __launch_bounds__(256) void hh_a_kernel(const float* __restrict__ Tm,
                                                   const float* __restrict__ hh_vs,
                                                   float* __restrict__ Am) {
    __shared__ float T[96][96];
    __shared__ float Y[96][192];
    int l = blockIdx.x, t = threadIdx.x;
    const float* Tl = Tm + (size_t)l * 9216;
    const float4* src = (const float4*)(hh_vs + (size_t)l * 96 * 192);
    for (int i = t; i < 9216; i += 256) ((float*)T)[i] = Tl[i];
    for (int i = t; i < 4608; i += 256) ((float4*)&Y[0][0])[i] = src[i];
    __syncthreads();
    for (int idx = t; idx < 4608; idx += 256) {
        int i = idx / 48, e0 = (idx % 48) * 4;
        float4 acc = {0.f, 0.f, 0.f, 0.f};
        for (int j = i; j < 96; ++j) {
            float tv = T[j][i];
            float4 y = *(const float4*)&Y[j][e0];
            acc.x += tv * y.x; acc.y += tv * y.y; acc.z += tv * y.z; acc.w += tv * y.w;
        }
        *(float4*)(Am + (size_t)l * 96 * 192 + (size_t)i * 192 + e0) = acc;
    }
}

__global__ __launch_bounds__(256) void hh_p_kernel(const float* __restrict__ hh_vs,
                                                   const float* __restrict__ Am,
                                                   float* __restrict__ qt) {
    __shared__ float Y[96][192];
    __shared__ float A[96][192];
    int l = blockIdx.x, t = threadIdx.x;
    const float4* ys = (const float4*)(hh_vs + (size_t)l * 96 * 192);
    const float4* as = (const float4*)(Am + (size_t)l * 96 * 192);
    for (int i = t; i < 4608; i += 256) { ((float4*)&Y[0][0])[i] = ys[i]; ((float4*)&A[0][0])[i] = as[i]; }
    __syncthreads();
    for (int idx = t; idx < 9216; idx += 256) {
        int d = idx / 48, e0 = (idx % 48) * 4;
        float4 acc = {0.f, 0.f, 0.f, 0.f};
        for (int i = 0; i < 96; ++i) {
            float yv = Y[i][d];
            float4 a = *(const float4*)&A[i][e0];
            acc.x += yv * a.x; acc.y += yv * a.y; acc.z += yv * a.z; acc.w += yv * a.w;
        }
        acc.x = (d == e0 + 0 ? 1.f : 0.f) - acc.x;
        acc.y = (d == e0 + 1 ? 1.f : 0.f) - acc.y;
        acc.z = (d == e0 + 2 ? 1.f : 0.f) - acc.z;
        acc.w = (d == e0 + 3 ? 1.f : 0.f) - acc.w;
        *(float4*)(qt + (size_t)l * 192 * 192 + (size_t)d * 192 + e0) = acc;
    }
}

// fold + transpose + bf16 in one: weff_t[n][k] = sum_d qkv_w[k][d] qt[d][n]
__global__ __launch_bounds__(256) void fold_bf16t(const float* __restrict__ qkv_w,
                                                  const float* __restrict__ qt,
                                                  unsigned short* __restrict__ weff_t) {
    int z = blockIdx.z;
    int l = z >> 3, which = (z >> 2) & 1, head = z & 3;
    const float* A  = qkv_w + (size_t)l * 768 * 2304 + (size_t)which * 768 + head * 192;
    const float* Bq = qt + (size_t)l * 192 * 192;
    unsigned short* C = weff_t + (size_t)l * 2304 * 768 + ((size_t)which * 768 + head * 192) * 768;
    int row0 = blockIdx.y * 64, col0 = blockIdx.x * 64;   // row0: k, col0: n
    __shared__ float As[64][65];
    __shared__ float Bs[64][65];
    int tid = threadIdx.x, tx = tid & 15, ty = tid >> 4;
    float acc[4][4] = {};
    for (int k0 = 0; k0 < 192; k0 += 64) {
        for (int i = tid; i < 1024; i += 256) {
            int r = i >> 4, kq = i & 15;
            float4 va = *(const float4*)(A + (size_t)(row0 + r) * 2304 + k0 + kq * 4);
            As[kq * 4 + 0][r] = va.x; As[kq * 4 + 1][r] = va.y; As[kq * 4 + 2][r] = va.z; As[kq * 4 + 3][r] = va.w;
        }
        for (int i = tid; i < 1024; i += 256) {
            int r = i >> 4, nq = i & 15;
            float4 vb = *(const float4*)(Bq + (size_t)(k0 + r) * 192 + col0 + nq * 4);
            Bs[r][nq * 4 + 0] = vb.x; Bs[r][nq * 4 + 1] = vb.y; Bs[r][nq * 4 + 2] = vb.z; Bs[r][nq * 4 + 3] = vb.w;
        }
        __syncthreads();
        for (int k = 0; k < 64; ++k) {
            float a[4], bb[4];
#pragma unroll
            for (int m = 0; m < 4; ++m) a[m] = As[k][ty * 4 + m];
#pragma unroll
            for (int n = 0; n < 4; ++n) bb[n] = Bs[k][tx * 4 + n];
#pragma unroll
            for (int m = 0; m < 4; ++m)
#pragma unroll
                for (int n = 0; n < 4; ++n) acc[m][n] = fmaf(a[m], bb[n], acc[m][n]);
        }
        __syncthreads();
    }
    float (*Tr)[65] = (float(*)[65])As;
#pragma unroll
    for (int m = 0; m < 4; ++m)
#pragma unroll
        for (int n = 0; n < 4; ++n) Tr[tx * 4 + n][ty * 4 + m] = acc[m][n];
    __syncthreads();
    int nl = tid >> 2, kc = (tid & 3) * 16;
#pragma unroll
    for (int q4 = 0; q4 < 4; ++q4) {
        u16x4 o;
#pragma unroll
        for (int ii = 0; ii < 4; ++ii) o[ii] = f2bf(Tr[nl][kc + q4 * 4 + ii]);
        *(u16x4*)(C + (size_t)(col0 + nl) * 768 + row0 + kc + q4 * 4) = o;
    }
}

// strided fp32 [K][N] -> bf16 [N][K]
__global__ __launch_bounds__(256) void transpose_bf16_kernel(const float* __restrict__ W,
                                                             int ldw, size_t zsrc,
                                                             unsigned short* __restrict__ Wt,
                                                             int ldwt, size_t zdst) {
    __shared__ float t[32][33];
    const float* Wz = W + (size_t)blockIdx.z * zsrc;
    unsigned short* Wtz = Wt + (size_t)blockIdx.z * zdst;
    int k0 = blockIdx.y * 32, n0 = blockIdx.x * 32;
    int tid = threadIdx.x;
    int tr = tid >> 3, tc = tid & 7;
    float4 v = *(const float4*)(Wz + (size_t)(k0 + tr) * ldw + n0 + tc * 4);
    t[tr][tc * 4 + 0] = v.x; t[tr][tc * 4 + 1] = v.y; t[tr][tc * 4 + 2] = v.z; t[tr][tc * 4 + 3] = v.w;
    __syncthreads();
    u16x4 o;
    o[0] = f2bf(t[tc * 4 + 0][tr]); o[1] = f2bf(t[tc * 4 + 1][tr]);
    o[2] = f2bf(t[tc * 4 + 2][tr]); o[3] = f2bf(t[tc * 4 + 3][tr]);
    *(u16x4*)(Wtz + (size_t)(n0 + tr) * ldwt + k0 + tc * 4) = o;
}

__global__ __launch_bounds__(256) void patch_embed_kernel(const float* __restrict__ z_t,
                                                          const float* __restrict__ spins,
                                                          const float* __restrict__ patch_w,
                                                          const float* __restrict__ patch_b,
                                                          float* __restrict__ x) {
    int bs = blockIdx.x;
    int b = bs >> 8, s = bs & 255;
    int gy = s >> 4, gx = s & 15;
    __shared__ float in20[20];
    int t = threadIdx.x;
    if (t < 12) {
        int c = t >> 2, py = (t >> 1) & 1, px = t & 1;
        in20[t] = z_t[(((size_t)b * 3 + c) * 32 + (2 * gy + py)) * 32 + (2 * gx + px)];
    } else if (t < 20) {
        in20[t] = spins[b * 8 + (t - 12)];
    }
    __syncthreads();
    for (int d = t; d < 768; d += 256) {
        float acc = patch_b[d];
#pragma unroll
        for (int i = 0; i < 20; ++i) acc += in20[i] * patch_w[i * 768 + d];
        x[(size_t)bs * 768 + d] = acc;
    }
}

// wave-per-row rmsnorm: 4 rows/block, lane owns 12 contiguous d
__global__ __launch_bounds__(256) void rmsnorm_kernel(const float* __restrict__ x,
                                                      unsigned short* __restrict__ h) {
    int wave = threadIdx.x >> 6, lane = threadIdx.x & 63;
    int row = blockIdx.x * 4 + wave;
    const float* xr = x + (size_t)row * 768 + lane * 12;
    float4 a = *(const float4*)(xr);
    float4 b = *(const float4*)(xr + 4);
    float4 c = *(const float4*)(xr + 8);
    float ss = a.x*a.x + a.y*a.y + a.z*a.z + a.w*a.w
             + b.x*b.x + b.y*b.y + b.z*b.z + b.w*b.w
             + c.x*c.x + c.y*c.y + c.z*c.z + c.w*c.w;
#pragma unroll
    for (int msk = 1; msk < 64; msk <<= 1) ss += __shfl_xor(ss, msk);
    float sc = 1.0f / sqrtf(ss / 768.0f + EPS_RMS);
    unsigned short* hr = h + (size_t)row * 768 + lane * 12;
    u16x4 o0, o1, o2;
    o0[0]=f2bf(a.x*sc); o0[1]=f2bf(a.y*sc); o0[2]=f2bf(a.z*sc); o0[3]=f2bf(a.w*sc);
    o1[0]=f2bf(b.x*sc); o1[1]=f2bf(b.y*sc); o1[2]=f2bf(b.z*sc); o1[3]=f2bf(b.w*sc);
    o2[0]=f2bf(c.x*sc); o2[1]=f2bf(c.y*sc); o2[2]=f2bf(c.z*sc); o2[3]=f2bf(c.w*sc);
    *(u16x4*)(hr) = o0; *(u16x4*)(hr + 4) = o1; *(u16x4*)(hr + 8) = o2;
}

// ---- bf16 MFMA GEMM: 128x128, BK=32, 4 waves, chunked XCD swizzle ---------
// EPI: 0=store bf16(+bias)  1=qkv scatter (V transposed)  2=gate  4=x+=v
template <int EPI>
__global__ __launch_bounds__(256) void gemm_mfma(const unsigned short* __restrict__ A, int lda,
                                                 const unsigned short* __restrict__ Bt, int ldb,
                                                 unsigned short* __restrict__ Cb, int ldc, int K,
                                                 const float* __restrict__ bias,
                                                 float* __restrict__ Xf,
                                                 const unsigned short* __restrict__ Pb,
                                                 int CX) {
    __shared__ unsigned short As[4096];
    __shared__ unsigned short Bs[4096];
    int tid = threadIdx.x;
    int wave = tid >> 6, lane = tid & 63;
    int bx = blockIdx.x, by = blockIdx.y;
    xcd_chunk(gridDim.x, gridDim.y, CX, bx, by);
    int row0 = by * 128, col0 = bx * 128;
    int wm = wave >> 1, wn = wave & 1;
    f32x4 acc[4][4] = {};

    int srow = lane >> 2;
    int ksw = (((lane & 3) ^ (srow & 3)) * 8);
    int lrow = lane & 15;
    int csw = (((lane >> 4) ^ (lane & 3)) * 8);

    for (int k0 = 0; k0 < K; k0 += 32) {
#pragma unroll
        for (int it = 0; it < 2; ++it) {
            int chunk = it * 4 + wave;
            int r = chunk * 16 + srow;
            gload16(A  + (size_t)(row0 + r) * lda + k0 + ksw, &As[chunk * 512]);
            gload16(Bt + (size_t)(col0 + r) * ldb + k0 + ksw, &Bs[chunk * 512]);
        }
        __syncthreads();
        s16x8 af[4], bf[4];
#pragma unroll
        for (int m = 0; m < 4; ++m)
            af[m] = *(const s16x8*)&As[(wm * 64 + m * 16 + lrow) * 32 + csw];
#pragma unroll
        for (int n = 0; n < 4; ++n)
            bf[n] = *(const s16x8*)&Bs[(wn * 64 + n * 16 + lrow) * 32 + csw];
#pragma unroll
        for (int m = 0; m < 4; ++m)
#pragma unroll
            for (int n = 0; n < 4; ++n)
                acc[m][n] = __builtin_amdgcn_mfma_f32_16x16x32_bf16(af[m], bf[n], acc[m][n], 0, 0, 0);
        __syncthreads();
    }

    int lquad = lane >> 4;
#pragma unroll
    for (int m = 0; m < 4; ++m) {
#pragma unroll
        for (int n = 0; n < 4; ++n) {
#pragma unroll
            for (int r = 0; r < 4; ++r) {
                int i = row0 + wm * 64 + m * 16 + lquad * 4 + r;
                int j = col0 + wn * 64 + n * 16 + lrow;
                float v = acc[m][n][r];
                if (bias) v += bias[j];
                if constexpr (EPI == 0) {
                    Cb[(size_t)i * ldc + j] = f2bf(v);
                } else if constexpr (EPI == 1) {
                    int which = j / 768;
                    int rem = j - which * 768;
                    int head = rem / 192;
                    int hd = rem - head * 192;
                    int b = i >> 8, s = i & 255;
                    if (which == 2) {   // V transposed: [bh][d][s]
                        Cb[2 * ARENA_K + (((size_t)(b * 4 + head)) * 192 + hd) * 256 + s] = f2bf(v);
                    } else {
                        Cb[(size_t)which * ARENA_K + (((size_t)(b * 4 + head)) * 256 + s) * 192 + hd] = f2bf(v);
                    }
                } else if constexpr (EPI == 2) {
                    float p = b2f(Pb[(size_t)i * 768 + j]);
                    Xf[(size_t)i * 768 + j] += p * sigmoidf_(v);
                } else if constexpr (EPI == 4) {
                    Xf[(size_t)i * ldc + j] += v;
                }
            }
        }
    }
}

// ---- fused MLP-in GEMM: hidden = gelu(h@Wg+bg) * (h@Wv+bv) ----------------
__global__ __launch_bounds__(256) void gemm_mlp_fused(const unsigned short* __restrict__ A,
                                                      const unsigned short* __restrict__ Bt,
                                                      unsigned short* __restrict__ Hid,
                                                      const float* __restrict__ bias,
                                                      int CX) {
    __shared__ unsigned short As[4096];
    __shared__ unsigned short Bs[4096];
    int tid = threadIdx.x;
    int wave = tid >> 6, lane = tid & 63;
    int bx = blockIdx.x, by = blockIdx.y;
    xcd_chunk(gridDim.x, gridDim.y, CX, bx, by);
    int row0 = by * 128, col0 = bx * 64;
    int wm = wave >> 1, wn = wave & 1;
    f32x4 accg[4][2] = {};
    f32x4 accv[4][2] = {};

    int srow = lane >> 2;
    int ksw = (((lane & 3) ^ (srow & 3)) * 8);
    int lrow = lane & 15;
    int csw = (((lane >> 4) ^ (lane & 3)) * 8);

    const unsigned short* Bg = Bt + (size_t)col0 * 768;
    const unsigned short* Bv = Bt + (size_t)(3072 + col0) * 768;

    for (int k0 = 0; k0 < 768; k0 += 32) {
#pragma unroll
        for (int it = 0; it < 2; ++it) {
            int chunk = it * 4 + wave;
            int r = chunk * 16 + srow;
            gload16(A + (size_t)(row0 + r) * 768 + k0 + ksw, &As[chunk * 512]);
        }
        {
            int r = wave * 16 + srow;
            gload16(Bg + (size_t)r * 768 + k0 + ksw, &Bs[wave * 512]);
            gload16(Bv + (size_t)r * 768 + k0 + ksw, &Bs[2048 + wave * 512]);
        }
        __syncthreads();
        s16x8 af[4], bgf[2], bvf[2];
#pragma unroll
        for (int m = 0; m < 4; ++m)
            af[m] = *(const s16x8*)&As[(wm * 64 + m * 16 + lrow) * 32 + csw];
#pragma unroll
        for (int n = 0; n < 2; ++n) {
            bgf[n] = *(const s16x8*)&Bs[(wn * 32 + n * 16 + lrow) * 32 + csw];
            bvf[n] = *(const s16x8*)&Bs[2048 + (wn * 32 + n * 16 + lrow) * 32 + csw];
        }
#pragma unroll
        for (int m = 0; m < 4; ++m)
#pragma unroll
            for (int n = 0; n < 2; ++n) {
                accg[m][n] = __builtin_amdgcn_mfma_f32_16x16x32_bf16(af[m], bgf[n], accg[m][n], 0, 0, 0);
                accv[m][n] = __builtin_amdgcn_mfma_f32_16x16x32_bf16(af[m], bvf[n], accv[m][n], 0, 0, 0);
            }
        __syncthreads();
    }

    int lquad = lane >> 4;
#pragma unroll
    for (int m = 0; m < 4; ++m) {
#pragma unroll
        for (int n = 0; n < 2; ++n) {
#pragma unroll
            for (int r = 0; r < 4; ++r) {
                int i = row0 + wm * 64 + m * 16 + lquad * 4 + r;
                int j = col0 + wn * 32 + n * 16 + lrow;
                float g = accg[m][n][r] + bias[j];
                float v = accv[m][n][r] + bias[3072 + j];
                Hid[(size_t)i * 3072 + j] = f2bf(v * geluf_(g));
            }
        }
    }
}

// ---- MFMA attention with fused RoPE: grid (2, NH, B), 512 thr -------------
__global__ __launch_bounds__(512) void attn_mfma_kernel(const unsigned short* __restrict__ qb_,
                                                        const unsigned short* __restrict__ kb_,
                                                        const unsigned short* __restrict__ vtb_,
                                                        unsigned short* __restrict__ attnb,
                                                        const float* __restrict__ cosb,
                                                        const float* __restrict__ sinb,
                                                        int glob) {
    __shared__ unsigned short Klds[256 * 200];
    __shared__ unsigned short Vlds[192 * 72];
    __shared__ unsigned short Plds[8 * 16 * 72];
    int b = blockIdx.z, hh = blockIdx.y;
    int tid = threadIdx.x;
    int wave = tid >> 6, lane = tid & 63;
    int q0 = blockIdx.x * 128 + wave * 16;
    size_t bh = (size_t)(b * 4 + hh);
    const unsigned short* qb  = qb_  + bh * 49152;
    const unsigned short* kb  = kb_  + bh * 49152;
    const unsigned short* vtb = vtb_ + bh * 49152;

    // stage K with RoPE applied
    for (int c = tid; c < 6144; c += 512) {
        int r = c / 24, col = c - (c / 24) * 24;
        int j0 = col * 8;
        int jp = j0 < 96 ? j0 + 96 : j0 - 96;
        float sgn = j0 < 96 ? -1.f : 1.f;
        u16x8 a = *(const u16x8*)(kb + (size_t)r * 192 + j0);
        u16x8 p = *(const u16x8*)(kb + (size_t)r * 192 + jp);
        const float* cr = cosb + r * 192 + j0;
        const float* sr = sinb + r * 192 + j0;
        u16x8 o;
#pragma unroll
        for (int i = 0; i < 8; ++i)
            o[i] = f2bf(b2f(a[i]) * cr[i] + sgn * b2f(p[i]) * sr[i]);
        *(u16x8*)&Klds[r * 200 + j0] = o;
    }
    __syncthreads();

    // Q fragments with RoPE
    s16x8 qf[6];
    {
        int sq = q0 + (lane & 15);
        const unsigned short* qrow = qb + (size_t)sq * 192;
        const float* cr = cosb + sq * 192;
        const float* sr = sinb + sq * 192;
#pragma unroll
        for (int kk = 0; kk < 6; ++kk) {
            int ck = kk * 32 + (lane >> 4) * 8;
            int cp = ck < 96 ? ck + 96 : ck - 96;
            float sgn = ck < 96 ? -1.f : 1.f;
            u16x8 a = *(const u16x8*)(qrow + ck);
            u16x8 p = *(const u16x8*)(qrow + cp);
            s16x8 o;
#pragma unroll
            for (int i = 0; i < 8; ++i)
                o[i] = (short)f2bf(b2f(a[i]) * cr[ck + i] + sgn * b2f(p[i]) * sr[ck + i]);
            qf[kk] = o;
        }
    }

    f32x4 sc[16];
#pragma unroll
    for (int n = 0; n < 16; ++n) sc[n] = (f32x4){0.f, 0.f, 0.f, 0.f};
#pragma unroll
    for (int kk = 0; kk < 6; ++kk) {
#pragma unroll
        for (int n = 0; n < 16; ++n) {
            s16x8 bf = *(const s16x8*)&Klds[(n * 16 + (lane & 15)) * 200 + kk * 32 + (lane >> 4) * 8];
            sc[n] = __builtin_amdgcn_mfma_f32_16x16x32_bf16(qf[kk], bf, sc[n], 0, 0, 0);
        }
    }

    int lq = (lane >> 4) * 4;
#pragma unroll
    for (int n = 0; n < 16; ++n) {
        int sk = n * 16 + (lane & 15);
        int yk = sk >> 4, xk = sk & 15;
#pragma unroll
        for (int r = 0; r < 4; ++r) {
            int sq = q0 + lq + r;
            int dy = (sq >> 4) - yk, dx = (sq & 15) - xk;
            bool keep = glob || (dy * dy + dx * dx) < 7;
            sc[n][r] = keep ? sc[n][r] * ATT_SCALE : -1e30f;
        }
    }
    float rmax[4], rsum[4];
#pragma unroll
    for (int r = 0; r < 4; ++r) {
        float m = sc[0][r];
#pragma unroll
        for (int n = 1; n < 16; ++n) m = fmaxf(m, sc[n][r]);
#pragma unroll
        for (int msk = 1; msk < 16; msk <<= 1) m = fmaxf(m, __shfl_xor(m, msk));
        rmax[r] = m;
    }
#pragma unroll
    for (int r = 0; r < 4; ++r) {
        float e = 0.f;
#pragma unroll
        for (int n = 0; n < 16; ++n) { float p = expf(sc[n][r] - rmax[r]); sc[n][r] = p; e += p; }
#pragma unroll
        for (int msk = 1; msk < 16; msk <<= 1) e += __shfl_xor(e, msk);
        rsum[r] = 1.0f / e;
    }

    f32x4 o[12];
#pragma unroll
    for (int n = 0; n < 12; ++n) o[n] = (f32x4){0.f, 0.f, 0.f, 0.f};
    unsigned short* Pw = &Plds[wave * 1152];
    for (int kt = 0; kt < 4; ++kt) {
#pragma unroll
        for (int nn = 0; nn < 4; ++nn) {
#pragma unroll
            for (int r = 0; r < 4; ++r)
                Pw[(lq + r) * 72 + nn * 16 + (lane & 15)] = f2bf(sc[kt * 4 + nn][r] * rsum[r]);
        }
        __syncthreads();
        for (int c = tid; c < 1536; c += 512) {
            int r = c >> 3, col = c & 7;
            *(u16x8*)&Vlds[r * 72 + col * 8] = *(const u16x8*)(vtb + (size_t)r * 256 + kt * 64 + col * 8);
        }
        __syncthreads();
        s16x8 af[2];
#pragma unroll
        for (int kk2 = 0; kk2 < 2; ++kk2)
            af[kk2] = *(const s16x8*)&Pw[(lane & 15) * 72 + kk2 * 32 + (lane >> 4) * 8];
#pragma unroll
        for (int n = 0; n < 12; ++n) {
#pragma unroll
            for (int kk2 = 0; kk2 < 2; ++kk2) {
                s16x8 bf = *(const s16x8*)&Vlds[(n * 16 + (lane & 15)) * 72 + kk2 * 32 + (lane >> 4) * 8];
                o[n] = __builtin_amdgcn_mfma_f32_16x16x32_bf16(af[kk2], bf, o[n], 0, 0, 0);
            }
        }
    }
#pragma unroll
    for (int n = 0; n < 12; ++n) {
        int d = n * 16 + (lane & 15);
#pragma unroll
        for (int r = 0; r < 4; ++r) {
            int sq = q0 + lq + r;
            attnb[((size_t)(b * 256 + sq)) * 768 + hh * 192 + d] = f2bf(o[n][r]);
        }
    }
}

__global__ __launch_bounds__(768) void scalef_kernel(const float* __restrict__ spins,
                                                     const float* __restrict__ sd1_w,
                                                     const float* __restrict__ sd1_b,
                                                     const float* __restrict__ sd2_w,
                                                     const float* __restrict__ sd2_b,
                                                     float* __restrict__ scalef) {
    int b = blockIdx.x, t = threadIdx.x;
    __shared__ float hid[768];
    __shared__ float sp[8];
    if (t < 8) sp[t] = spins[b * 8 + t];
    __syncthreads();
    float acc = sd1_b[t];
#pragma unroll
    for (int i = 0; i < 8; ++i) acc += sp[i] * sd1_w[i * 768 + t];
    hid[t] = acc * sigmoidf_(acc);
    __syncthreads();
    if (t < 12) {
        float o = sd2_b[t];
        for (int d = 0; d < 768; ++d) o += hid[d] * sd2_w[d * 12 + t];
        scalef[b * 12 + t] = expf(o);
    }
}

// head: wave-per-row, lane owns 12 contiguous d; also emits rowlam = x.lam_w
__global__ __launch_bounds__(256) void head_kernel(const unsigned short* __restrict__ xn,
                                                   const float* __restrict__ head_w,
                                                   const float* __restrict__ head_b,
                                                   const float* __restrict__ scalef,
                                                   const float* __restrict__ lam_w,
                                                   float* __restrict__ out,
                                                   float* __restrict__ rowlam) {
    __shared__ float hw[768][13];
    __shared__ float red[4][64][14];
    int t = threadIdx.x, wave = t >> 6, lane = t & 63;
    for (int i = t; i < 768 * 12; i += 256) hw[i / 12][i % 12] = head_w[i];
    for (int i = t; i < 768; i += 256) hw[i][12] = lam_w[i];
    __syncthreads();
    int row_base = blockIdx.x * 64;
    for (int rr = wave; rr < 64; rr += 4) {
        int row = row_base + rr;
        const unsigned short* xr = xn + (size_t)row * 768 + lane * 12;
        float xv[12];
        u16x4 v0 = *(const u16x4*)(xr);
        u16x4 v1 = *(const u16x4*)(xr + 4);
        u16x4 v2 = *(const u16x4*)(xr + 8);
#pragma unroll
        for (int j = 0; j < 4; ++j) { xv[j] = b2f(v0[j]); xv[4 + j] = b2f(v1[j]); xv[8 + j] = b2f(v2[j]); }
        float p[13] = {};
        int d0 = lane * 12;
#pragma unroll
        for (int dd = 0; dd < 12; ++dd) {
            float xvv = xv[dd];
#pragma unroll
            for (int o = 0; o < 12; ++o) p[o] += xvv * hw[d0 + dd][o];
            p[12] += xvv * hw[d0 + dd][12];
        }
#pragma unroll
        for (int o = 0; o < 13; ++o) red[wave][lane][o] = p[o];
        __syncthreads();
        if (lane < 13) {
            float s = 0.f;
            for (int i = 0; i < 64; ++i) s += red[wave][i][lane];
            if (lane < 12) {
                int b = row >> 8, sidx = row & 255;
                float v = (s + head_b[lane]) * scalef[b * 12 + lane];
                int c = lane >> 2, py = (lane >> 1) & 1, px = lane & 1;
                int gy = sidx >> 4, gxx = sidx & 15;
                out[(((size_t)b * 3 + c) * 32 + 2 * gy + py) * 32 + 2 * gxx + px] = v;
            } else {
                rowlam[row] = s;
            }
        }
        __syncthreads();
    }
}

__global__ __launch_bounds__(256) void lpred_kernel(const float* __restrict__ rowlam,
                                                    const float* __restrict__ lam_b,
                                                    float* __restrict__ out) {
    int b = blockIdx.x, t = threadIdx.x;
    __shared__ float red[256];
    red[t] = rowlam[b * 256 + t];
    __syncthreads();
    for (int s2 = 128; s2 > 0; s2 >>= 1) { if (t < s2) red[t] += red[t + s2]; __syncthreads(); }
    if (t == 0) out[196608 + b] = red[0] / 256.0f + lam_b[0];
}

// ---------------------------------------------------------------------------
extern "C" void kernel_launch(void* const* d_in, const int* in_sizes, int n_in,
                              void* d_out, int out_size, void* d_ws, size_t ws_size,
                              hipStream_t stream) {
    const float* z_t     = (const float*)d_in[0];
    const float* logsnr  = (const float*)d_in[1];
    const float* qkv_w   = (const float*)d_in[2];
    const float* out_w   = (const float*)d_in[3];
    const float* gate_w  = (const float*)d_in[4];
    const float* gate_b  = (const float*)d_in[5];
    const float* mlpg_w  = (const float*)d_in[6];
    const float* mlpg_b  = (const float*)d_in[7];
    const float* mlpo_w  = (const float*)d_in[8];
    const float* mlpo_b  = (const float*)d_in[9];
    const float* hh_vs   = (const float*)d_in[10];
    const float* patch_w = (const float*)d_in[11];
    const float* patch_b = (const float*)d_in[12];
    const float* head_w  = (const float*)d_in[13];
    const float* head_b  = (const float*)d_in[14];
    const float* sd1_w   = (const float*)d_in[15];
    const float* sd1_b   = (const float*)d_in[16];
    const float* sd2_w   = (const float*)d_in[17];
    const float* sd2_b   = (const float*)d_in[18];
    const float* lam_w   = (const float*)d_in[19];
    const float* lam_b   = (const float*)d_in[20];

    char* wsb = (char*)d_ws;
    float* spins  = (float*)(wsb + B_SPINS);
    float* scalef = (float*)(wsb + B_SCALEF);
    float* qt     = (float*)(wsb + B_QT);
    float* cosb   = (float*)(wsb + B_COS);
    float* sinb   = (float*)(wsb + B_SIN);
    float* Gm     = (float*)(wsb + B_G);
    float* Tm     = (float*)(wsb + B_T);
    float* Am     = (float*)(wsb + B_AWY);
    float* rowlam = (float*)(wsb + B_ROWLAM);
    float* x      = (float*)(wsb + B_X);
    unsigned short* h      = (unsigned short*)(wsb + B_H);
    unsigned short* proj   = (unsigned short*)(wsb + B_PROJ);
    unsigned short* weff_t = (unsigned short*)(wsb + B_WEFFT);
    unsigned short* outw_t = (unsigned short*)(wsb + B_OUTWT);
    unsigned short* gatew_t= (unsigned short*)(wsb + B_GATEWT);
    unsigned short* mlpg_t = (unsigned short*)(wsb + B_MLPGT);
    unsigned short* mlpo_t = (unsigned short*)(wsb + B_MLPOT);
    unsigned short* arena  = (unsigned short*)(wsb + B_ARENA);
    unsigned short* qbuf = arena;
    unsigned short* kbuf = arena + ARENA_K;
    unsigned short* vtbuf = arena + 2 * ARENA_K;
    unsigned short* attnb = arena + 3 * ARENA_K;
    unsigned short* hidden = arena;
    float* out = (float*)d_out;

    // ---- setup ----
    spins_kernel<<<1, 64, 0, stream>>>(logsnr, spins);
    rope_table_kernel<<<256, 192, 0, stream>>>(cosb, sinb);
    hh_gram_kernel<<<8, 256, 0, stream>>>(hh_vs, Gm);
    hh_t_kernel<<<8, 128, 0, stream>>>(Gm, Tm);
    hh_a_kernel<<<8, 256, 0, stream>>>(Tm, hh_vs, Am);
    hh_p_kernel<<<8, 256, 0, stream>>>(hh_vs, Am, qt);
    fold_bf16t<<<dim3(3, 12, 64), 256, 0, stream>>>(qkv_w, qt, weff_t);
    transpose_bf16_kernel<<<dim3(24, 24, 8), 256, 0, stream>>>(qkv_w + 1536, 2304,
        (size_t)768 * 2304, weff_t + (size_t)1536 * 768, 768, (size_t)2304 * 768);
    transpose_bf16_kernel<<<dim3(24, 24, 8), 256, 0, stream>>>(out_w, 768,
        (size_t)768 * 768, outw_t, 768, (size_t)768 * 768);
    transpose_bf16_kernel<<<dim3(24, 24, 8), 256, 0, stream>>>(gate_w, 768,
        (size_t)768 * 768, gatew_t, 768, (size_t)768 * 768);
    transpose_bf16_kernel<<<dim3(192, 24, 8), 256, 0, stream>>>(mlpg_w, 6144,
        (size_t)768 * 6144, mlpg_t, 768, (size_t)6144 * 768);
    transpose_bf16_kernel<<<dim3(24, 96, 8), 256, 0, stream>>>(mlpo_w, 768,
        (size_t)3072 * 768, mlpo_t, 3072, (size_t)768 * 3072);
    patch_embed_kernel<<<M_TOK, 256, 0, stream>>>(z_t, spins, patch_w, patch_b, x);

    for (int l = 0; l < Ll; ++l) {
        int glob = ((l + 1) % 4 == 0) ? 1 : 0;
        rmsnorm_kernel<<<4096, 256, 0, stream>>>(x, h);
        gemm_mfma<1><<<dim3(18, 128), 256, 0, stream>>>(h, 768,
            weff_t + (size_t)l * 2304 * 768, 768, arena, 0, 768, nullptr, nullptr, nullptr, 3);
        attn_mfma_kernel<<<dim3(2, 4, 64), 512, 0, stream>>>(qbuf, kbuf, vtbuf, attnb,
            cosb, sinb, glob);
        gemm_mfma<0><<<dim3(6, 128), 256, 0, stream>>>(attnb, 768,
            outw_t + (size_t)l * 768 * 768, 768, proj, 768, 768, nullptr, nullptr, nullptr, 3);
        gemm_mfma<2><<<dim3(6, 128), 256, 0, stream>>>(proj, 768,
            gatew_t + (size_t)l * 768 * 768, 768, nullptr, 768, 768,
            gate_b + (size_t)l * 768, x, proj, 3);
        rmsnorm_kernel<<<4096, 256, 0, stream>>>(x, h);
        gemm_mlp_fused<<<dim3(48, 128), 256, 0, stream>>>(h,
            mlpg_t + (size_t)l * 6144 * 768, hidden, mlpg_b + (size_t)l * 6144, 4);
        gemm_mfma<4><<<dim3(6, 128), 256, 0, stream>>>(hidden, 3072,
            mlpo_t + (size_t)l * 768 * 3072, 3072, nullptr, 768, 3072,
            mlpo_b + (size_t)l * 768, x, nullptr, 6);
    }

    rmsnorm_kernel<<<4096, 256, 0, stream>>>(x, h);
    scalef_kernel<<<64, 768, 0, stream>>>(spins, sd1_w, sd1_b, sd2_w, sd2_b, scalef);
    head_kernel<<<256, 256, 0, stream>>>(h, head_w, head_b, scalef, lam_w, out, rowlam);
    lpred_kernel<<<64, 256, 0, stream>>>(rowlam, lam_b, out);
}